// Round 12
// baseline (197.659 us; speedup 1.0000x reference)
//
#include <hip/hip_runtime.h>
#include <math.h>

#define EMBED 1024
#define NH    16
#define DH    64
#define BATCH 2
#define SEQ   2048
#define MTOT  4096
#define BHTOT 32

typedef float f32x4  __attribute__((ext_vector_type(4)));
typedef float f32x16 __attribute__((ext_vector_type(16)));
typedef short s16x8  __attribute__((ext_vector_type(8)));
typedef short s16x4  __attribute__((ext_vector_type(4)));
typedef unsigned u32x2 __attribute__((ext_vector_type(2)));
typedef unsigned u32x4 __attribute__((ext_vector_type(4)));

#define AS1 __attribute__((address_space(1)))
#define AS3 __attribute__((address_space(3)))

__device__ __forceinline__ unsigned short bf16_rne(float f) {
    unsigned u = __builtin_bit_cast(unsigned, f);
    return (unsigned short)((u + 0x7FFFu + ((u >> 16) & 1u)) >> 16);
}
__device__ __forceinline__ float bf16_f(unsigned short h) {
    unsigned u = ((unsigned)h) << 16;
    return __builtin_bit_cast(float, u);
}
__device__ __forceinline__ void split2(float v, unsigned short& hi, unsigned short& lo) {
    hi = bf16_rne(v);
    lo = bf16_rne(v - bf16_f(hi));
}
__device__ __forceinline__ void gload16(const void* g, void* l) {
    __builtin_amdgcn_global_load_lds((const AS1 void*)g, (AS3 void*)l, 16, 0, 0);
}
__device__ __forceinline__ unsigned cvt_pk_bf16(float lo, float hi) {
    unsigned r;
    asm volatile("v_cvt_pk_bf16_f32 %0, %1, %2" : "=v"(r) : "v"(lo), "v"(hi));
    return r;
}
#define MFMA16(a, b, c) __builtin_amdgcn_mfma_f32_16x16x32_bf16((a), (b), (c), 0, 0, 0)
#define MFMA32(a, b, c) __builtin_amdgcn_mfma_f32_32x32x16_bf16((a), (b), (c), 0, 0, 0)

// ---------------------------------------------------------------------------
// splitX: X fp32 [M][K] -> Xh bf16 only
// ---------------------------------------------------------------------------
__global__ __launch_bounds__(256)
void splitX_kernel(const float* __restrict__ X, unsigned short* __restrict__ Xh)
{
    const size_t i = ((size_t)blockIdx.x * 256 + threadIdx.x) * 8;
    float4 a = *(const float4*)&X[i];
    float4 b = *(const float4*)&X[i + 4];
    float v[8] = {a.x, a.y, a.z, a.w, b.x, b.y, b.z, b.w};
    s16x8 h8;
#pragma unroll
    for (int e = 0; e < 8; ++e) h8[e] = (short)bf16_rne(v[e]);
    *(s16x8*)&Xh[i] = h8;
}

// ---------------------------------------------------------------------------
// splitT: W fp32 [Kd][Nd]  ->  HiT, LoT bf16 [Nd][Kd] (transposed + hi/lo split)
// ---------------------------------------------------------------------------
__global__ __launch_bounds__(256)
void splitT_kernel(const float* __restrict__ W, unsigned short* __restrict__ HiT,
                   unsigned short* __restrict__ LoT, int Kd, int Nd)
{
    __shared__ float T[32][33];
    const int tid = threadIdx.x;
    const int n0 = blockIdx.x * 32, k0 = blockIdx.y * 32;
    {
        const int row = tid >> 3, c4 = (tid & 7) * 4;
        float4 v = *(const float4*)&W[(size_t)(k0 + row) * Nd + n0 + c4];
        T[row][c4] = v.x; T[row][c4 + 1] = v.y; T[row][c4 + 2] = v.z; T[row][c4 + 3] = v.w;
    }
    __syncthreads();
    {
        const int nr = tid >> 3, c4 = (tid & 7) * 4;
        s16x4 h4, l4;
#pragma unroll
        for (int e = 0; e < 4; ++e) {
            unsigned short h, l;
            split2(T[c4 + e][nr], h, l);
            h4[e] = (short)h; l4[e] = (short)l;
        }
        *(s16x4*)&HiT[(size_t)(n0 + nr) * Kd + k0 + c4] = h4;
        *(s16x4*)&LoT[(size_t)(n0 + nr) * Kd + k0 + c4] = l4;
    }
}

// ---------------------------------------------------------------------------
// QKV GEMM, 2-combo split (Ah.Bh + Ah.Bl), SINGLE-buffered 24 KB LDS ->
// max TLP (~5 blocks/CU). 128x128 tile, BK=32, XCD-swizzled grid,
// combo-outer MFMA (16 independent accumulators).
// ---------------------------------------------------------------------------
__global__ __launch_bounds__(256)
void qkv_gemm_kernel(const unsigned short* __restrict__ Xh_g,
                     const unsigned short* __restrict__ BhT, const unsigned short* __restrict__ BlT,
                     const float* __restrict__ bias,
                     unsigned short* __restrict__ Qh, unsigned short* __restrict__ Ql,
                     unsigned short* __restrict__ Kh, unsigned short* __restrict__ Kl,
                     unsigned short* __restrict__ Vh, unsigned short* __restrict__ Vl)
{
    constexpr int KD = 1024;
    // shorts: Ah [0,4096) Bh [4096,8192) Bl [8192,12288)
    __shared__ __align__(16) short SB[12288];   // 24 KB

    const int tid = threadIdx.x, lane = tid & 63, wid = tid >> 6;
    const int g = lane >> 4, ln = lane & 15;
    const int wm = wid >> 1, wn = wid & 1;

    // XCD swizzle: xcd = bid&7 owns 96 tiles = 4 m-rows x 24 n (m-fastest)
    const int bid = blockIdx.x;
    const int u = bid >> 3, xcd = bid & 7;
    const int by = xcd * 4 + (u & 3);   // m-tile 0..31
    const int bx = u >> 2;              // n-tile 0..23
    const int m0 = by * 128, n0 = bx * 128;

    f32x4 acc[4][4];
#pragma unroll
    for (int i = 0; i < 4; ++i)
#pragma unroll
        for (int j = 0; j < 4; ++j) acc[i][j] = (f32x4){0.f, 0.f, 0.f, 0.f};

    const int srow = lane >> 2, ss = lane & 3;

    for (int k0 = 0; k0 < KD; k0 += 32) {
        __syncthreads();
        // stage 24 segments (3 tiles x 8 KB-sub), 6 per wave
#pragma unroll
        for (int i = 0; i < 6; ++i) {
            const int s = wid * 6 + i;
            const int t = s >> 3, j = s & 7;
            const unsigned short* gsrc = (t == 0) ? Xh_g : (t == 1) ? BhT : BlT;
            const int roff = (t == 0) ? m0 : n0;
            const int row_loc = j * 16 + srow;
            const int kc = ss ^ ((row_loc >> 1) & 3);
            gload16(gsrc + (size_t)(roff + row_loc) * KD + k0 + kc * 8,
                    &SB[t * 4096 + j * 512]);
        }
        __syncthreads();

        const short* Ah = &SB[0];
        const short* Bh = &SB[4096];
        const short* Bl = &SB[8192];

        s16x8 fah[4], fbh[4], fbl[4];
#pragma unroll
        for (int am = 0; am < 4; ++am) {
            int m_loc = wm * 64 + am * 16 + ln;
            int sl = (g ^ ((m_loc >> 1) & 3)) * 8;
            fah[am] = *(const s16x8*)&Ah[m_loc * 32 + sl];
        }
#pragma unroll
        for (int bn = 0; bn < 4; ++bn) {
            int n_loc = wn * 64 + bn * 16 + ln;
            int sl = (g ^ ((n_loc >> 1) & 3)) * 8;
            fbh[bn] = *(const s16x8*)&Bh[n_loc * 32 + sl];
            fbl[bn] = *(const s16x8*)&Bl[n_loc * 32 + sl];
        }
        // combo-outer: reuse distance 16 on each accumulator
#pragma unroll
        for (int am = 0; am < 4; ++am)
#pragma unroll
            for (int bn = 0; bn < 4; ++bn)
                acc[am][bn] = MFMA16(fah[am], fbh[bn], acc[am][bn]);
#pragma unroll
        for (int am = 0; am < 4; ++am)
#pragma unroll
            for (int bn = 0; bn < 4; ++bn)
                acc[am][bn] = MFMA16(fah[am], fbl[bn], acc[am][bn]);
    }

    // epilogue: bias + split scatter (C/D: row=(lane>>4)*4+r, col=lane&15)
#pragma unroll
    for (int am = 0; am < 4; ++am)
#pragma unroll
        for (int bn = 0; bn < 4; ++bn) {
            int n = n0 + wn * 64 + bn * 16 + ln;
            float bv = bias[n];
            int sec = n >> 10, cc = n & 1023, h = cc >> 6, d = cc & 63;
#pragma unroll
            for (int r = 0; r < 4; ++r) {
                int m = m0 + wm * 64 + am * 16 + g * 4 + r;
                int bb = m >> 11, t = m & 2047;
                int bh_i = bb * NH + h;
                float val = acc[am][bn][r] + bv;
                unsigned short hi, lo;
                if (sec == 0) {
                    val *= 0.125f; split2(val, hi, lo);
                    size_t idx = ((size_t)bh_i * SEQ + t) * DH + d;
                    Qh[idx] = hi; Ql[idx] = lo;
                } else if (sec == 1) {
                    split2(val, hi, lo);
                    size_t idx = ((size_t)bh_i * SEQ + t) * DH + d;
                    Kh[idx] = hi; Kl[idx] = lo;
                } else {
                    split2(val, hi, lo);
                    size_t idx = ((size_t)bh_i * DH + d) * SEQ + t;   // V transposed
                    Vh[idx] = hi; Vl[idx] = lo;
                }
            }
        }
}

// ---------------------------------------------------------------------------
// Attention, 32x32 swapped-operand structure + 2-phase pipelined K/V staging
// (double-buffered, 64 KB LDS). Defer-max THR=8; interleaved MFMA
// accumulators. (unchanged from r11)
// ---------------------------------------------------------------------------
__global__ __launch_bounds__(256)
void attn_kernel(const unsigned short* __restrict__ Qh_g, const unsigned short* __restrict__ Ql_g,
                 const unsigned short* __restrict__ Kh_g, const unsigned short* __restrict__ Kl_g,
                 const unsigned short* __restrict__ Vh_g, const unsigned short* __restrict__ Vl_g,
                 unsigned short* __restrict__ Yh, unsigned short* __restrict__ Yl)
{
    __shared__ __align__(16) short SM[2][16384];   // 64 KB: 2 bufs x {Kh,Kl,Vh,Vl}

    const int tid = threadIdx.x, lane = tid & 63, wid = tid >> 6;
    const int l31 = lane & 31, l5 = lane >> 5;
    const int bid = blockIdx.x;
    const int qb = 15 - (bid >> 5), bh = bid & 31;   // heavy q-tiles first
    const int Q0 = qb * 128;
    const int qg = Q0 + wid * 32 + l31;              // this lane's q row

    // Q fragments from global (once per block)
    s16x8 qfh[4], qfl[4];
    {
        const size_t qo = ((size_t)bh * SEQ + qg) * DH;
#pragma unroll
        for (int t = 0; t < 4; ++t) {
            const int ch = t * 2 + l5;
            qfh[t] = *(const s16x8*)&Qh_g[qo + ch * 8];
            qfl[t] = *(const s16x8*)&Ql_g[qo + ch * 8];
        }
    }

    float m_i = -INFINITY, l_i = 0.f;
    f32x16 yacc[2];
#pragma unroll
    for (int e = 0; e < 16; ++e) { yacc[0][e] = 0.f; yacc[1][e] = 0.f; }

    const int srow = lane >> 3, ss = lane & 7;
    const int KT = 2 * qb + 2;
    const unsigned short* gb = (wid == 0) ? Kh_g : (wid == 1) ? Kl_g
                             : (wid == 2) ? Vh_g : Vl_g;
    const bool isK = (wid < 2);

    // prologue: stage kv-tile 0 into buf 0
    {
        short* lb = &SM[0][wid * 4096];
#pragma unroll
        for (int j = 0; j < 8; ++j) {
            int row = j * 8 + srow;
            int kc = ss ^ (row & 7);
            const unsigned short* src = isK
                ? gb + ((size_t)bh * SEQ + row) * DH + kc * 8
                : gb + ((size_t)bh * DH + row) * SEQ + kc * 8;
            gload16(src, lb + j * 512);
        }
    }

    for (int kt = 0; kt < KT; ++kt) {
        const int cur = kt & 1;
        __syncthreads();   // stage(kt) landed; reads of buf[cur] (kt-2) done
        if (kt + 1 < KT) {
            short* lb = &SM[cur ^ 1][wid * 4096];
            const int kn = (kt + 1) * 64;
#pragma unroll
            for (int j = 0; j < 8; ++j) {
                int row = j * 8 + srow;
                int kc = ss ^ (row & 7);
                const unsigned short* src = isK
                    ? gb + ((size_t)bh * SEQ + kn + row) * DH + kc * 8
                    : gb + ((size_t)bh * DH + row) * SEQ + kn + kc * 8;
                gload16(src, lb + j * 512);
            }
        }

        if (kt * 64 > Q0 + wid * 32 + 31) continue;   // fully masked for this wave

        const short* Ksh = &SM[cur][0];
        const short* Ksl = &SM[cur][4096];
        const short* Vsh = &SM[cur][8192];
        const short* Vsl = &SM[cur][12288];

        // ---- S^T = K . Q  (3-combo split; interleaved kb -> distance-2 chains)
        f32x16 s[2];
#pragma unroll
        for (int e = 0; e < 16; ++e) { s[0][e] = 0.f; s[1][e] = 0.f; }
#pragma unroll
        for (int t = 0; t < 4; ++t) {
            s16x8 kh[2], kl[2];
#pragma unroll
            for (int kb = 0; kb < 2; ++kb) {
                const int row = kb * 32 + l31;
                const int sl = ((t * 2 + l5) ^ (row & 7)) * 8;
                kh[kb] = *(const s16x8*)&Ksh[row * 64 + sl];
                kl[kb] = *(const s16x8*)&Ksl[row * 64 + sl];
            }
#pragma unroll
            for (int kb = 0; kb < 2; ++kb) s[kb] = MFMA32(kh[kb], qfh[t], s[kb]);
#pragma unroll
            for (int kb = 0; kb < 2; ++kb) s[kb] = MFMA32(kl[kb], qfh[t], s[kb]);
#pragma unroll
            for (int kb = 0; kb < 2; ++kb) s[kb] = MFMA32(kh[kb], qfl[t], s[kb]);
        }

        // ---- causal mask (only near the diagonal)
        if (kt * 64 + 63 > Q0 + wid * 32) {
#pragma unroll
            for (int kb = 0; kb < 2; ++kb)
#pragma unroll
                for (int r = 0; r < 16; ++r) {
                    const int key = kt * 64 + kb * 32 + (r & 3) + 8 * (r >> 2) + 4 * l5;
                    if (key > qg) s[kb][r] = -INFINITY;
                }
        }

        // ---- online softmax, in-register (q = lane&31), defer-max THR=8
        float mx = s[0][0];
#pragma unroll
        for (int r = 1; r < 16; ++r) mx = fmaxf(mx, s[0][r]);
#pragma unroll
        for (int r = 0; r < 16; ++r) mx = fmaxf(mx, s[1][r]);
        mx = fmaxf(mx, __shfl_xor(mx, 32));
        const bool defer = (__all(mx - m_i <= 8.f) != 0);
        float mref;
        if (defer) {
            mref = m_i;
        } else {
            mref = fmaxf(m_i, mx);
            const float al = __expf(m_i - mref);
            m_i = mref;
            l_i *= al;
#pragma unroll
            for (int e = 0; e < 16; ++e) { yacc[0][e] *= al; yacc[1][e] *= al; }
        }
        float ls = 0.f;
#pragma unroll
        for (int kb = 0; kb < 2; ++kb)
#pragma unroll
            for (int r = 0; r < 16; ++r) {
                s[kb][r] = __expf(s[kb][r] - mref);
                ls += s[kb][r];
            }
        ls += __shfl_xor(ls, 32);
        l_i += ls;

        // ---- P (bf16) fragments in-register: cvt_pk + permlane32_swap
        unsigned pk[2][8];
#pragma unroll
        for (int kb = 0; kb < 2; ++kb)
#pragma unroll
            for (int j = 0; j < 8; ++j)
                pk[kb][j] = cvt_pk_bf16(s[kb][2 * j], s[kb][2 * j + 1]);
        s16x8 pf[2][2];
#pragma unroll
        for (int kb = 0; kb < 2; ++kb) {
            u32x2 sA = __builtin_amdgcn_permlane32_swap(pk[kb][0], pk[kb][2], false, false);
            u32x2 sB = __builtin_amdgcn_permlane32_swap(pk[kb][1], pk[kb][3], false, false);
            u32x4 w0 = {sA[0], sB[0], sA[1], sB[1]};
            pf[kb][0] = __builtin_bit_cast(s16x8, w0);
            u32x2 sC = __builtin_amdgcn_permlane32_swap(pk[kb][4], pk[kb][6], false, false);
            u32x2 sD = __builtin_amdgcn_permlane32_swap(pk[kb][5], pk[kb][7], false, false);
            u32x4 w1 = {sC[0], sD[0], sC[1], sD[1]};
            pf[kb][1] = __builtin_bit_cast(s16x8, w1);
        }

        // ---- Y^T += V^T . P  (interleaved dt -> distance-2 chains)
#pragma unroll
        for (int t = 0; t < 4; ++t) {
            s16x8 vh[2], vl[2];
#pragma unroll
            for (int dt = 0; dt < 2; ++dt) {
                const int row = dt * 32 + l31;
                const int sl = ((t * 2 + l5) ^ (row & 7)) * 8;
                vh[dt] = *(const s16x8*)&Vsh[row * 64 + sl];
                vl[dt] = *(const s16x8*)&Vsl[row * 64 + sl];
            }
            const s16x8 pfr = pf[t >> 1][t & 1];
#pragma unroll
            for (int dt = 0; dt < 2; ++dt) yacc[dt] = MFMA32(vh[dt], pfr, yacc[dt]);
#pragma unroll
            for (int dt = 0; dt < 2; ++dt) yacc[dt] = MFMA32(vl[dt], pfr, yacc[dt]);
        }
    }

    // ---- epilogue: normalize, split, LDS transpose bounce, coalesced write
    __syncthreads();   // everyone done with K/V LDS
    short* SMf = &SM[0][0];
    const float inv = 1.f / l_i;
    const int qlcl = wid * 32 + l31;
#pragma unroll
    for (int dt = 0; dt < 2; ++dt)
#pragma unroll
        for (int rq = 0; rq < 4; ++rq) {
            const int d0 = dt * 32 + rq * 8 + 4 * l5;
            s16x4 h4, l4;
#pragma unroll
            for (int c = 0; c < 4; ++c) {
                unsigned short hh, ll;
                split2(yacc[dt][rq * 4 + c] * inv, hh, ll);
                h4[c] = (short)hh; l4[c] = (short)ll;
            }
            const int base = qlcl * 64 + (((d0 >> 3) ^ (qlcl & 7)) * 8) + (d0 & 7);
            *(s16x4*)&SMf[base] = h4;
            *(s16x4*)&SMf[8192 + base] = l4;
        }
    __syncthreads();
    const int b = bh >> 4, h = bh & 15;
#pragma unroll
    for (int i = 0; i < 4; ++i) {
        const int idx = tid + i * 256;
        const int row = idx >> 3, ch = idx & 7;
        const int sl = (ch ^ (row & 7)) * 8;
        s16x8 vh8 = *(const s16x8*)&SMf[row * 64 + sl];
        s16x8 vl8 = *(const s16x8*)&SMf[8192 + row * 64 + sl];
        const size_t o = ((size_t)(b * SEQ + Q0 + row)) * EMBED + h * DH + ch * 8;
        *(s16x8*)&Yh[o] = vh8;
        *(s16x8*)&Yl[o] = vl8;
    }
}

// ---------------------------------------------------------------------------
// Out GEMM: 2-phase pipelined staging, XCD-swizzled, combo-outer MFMA.
// (Grid-limited to 1 block/CU, so 64 KB dbuf costs no occupancy.) (unchanged)
// ---------------------------------------------------------------------------
__global__ __launch_bounds__(256)
void out_gemm_kernel(const unsigned short* __restrict__ Yh_g, const unsigned short* __restrict__ Yl_g,
                     const unsigned short* __restrict__ WhT, const unsigned short* __restrict__ WlT,
                     const float* __restrict__ bias, float* __restrict__ out)
{
    constexpr int KD = 1024, ND = 1024;
    __shared__ __align__(16) short SB[2][16384];   // 64 KB

    const int tid = threadIdx.x, lane = tid & 63, wid = tid >> 6;
    const int g = lane >> 4, ln = lane & 15;
    const int wm = wid >> 1, wn = wid & 1;

    const int bid = blockIdx.x;
    const int u = bid >> 3, xcd = bid & 7;
    const int by = xcd * 4 + (u & 3);   // m-tile 0..31
    const int bx = u >> 2;              // n-tile 0..7
    const int m0 = by * 128, n0 = bx * 128;

    f32x4 acc[4][4];
#pragma unroll
    for (int i = 0; i < 4; ++i)
#pragma unroll
        for (int j = 0; j < 4; ++j) acc[i][j] = (f32x4){0.f, 0.f, 0.f, 0.f};

    const int srow = lane >> 2, ss = lane & 3;
    const unsigned short* gb = (wid == 0) ? Yh_g : (wid == 1) ? Yl_g
                             : (wid == 2) ? WhT  : WlT;
    const int roff = (wid < 2) ? m0 : n0;

    {
        short* lb = &SB[0][wid * 4096];
#pragma unroll
        for (int j = 0; j < 8; ++j) {
            int row_loc = j * 16 + srow;
            int kc = ss ^ ((row_loc >> 1) & 3);
            gload16(gb + (size_t)(roff + row_loc) * KD + kc * 8, lb + j * 512);
        }
    }

    for (int it = 0; it < 32; ++it) {
        const int cur = it & 1;
        __syncthreads();
        if (it + 1 < 32) {
            short* lb = &SB[cur ^ 1][wid * 4096];
            const int k0n = (it + 1) * 32;
#pragma unroll
            for (int j = 0; j < 8; ++j) {
                int row_loc = j * 16 + srow;
                int kc = ss ^ ((row_loc >> 1) & 3);
                gload16(gb + (size_t)(roff + row_loc) * KD + k0n + kc * 8, lb + j * 512);
            }
        }
        const short* Ah = &SB[cur][0];
        const short* Al = &SB[cur][4096];
        const short* Bh = &SB[cur][8192];
        const short* Bl = &SB[cur][12288];

        s16x8 fah[4], fal[4], fbh[4], fbl[4];
#pragma unroll
        for (int am = 0; am < 4; ++am) {
            int m_loc = wm * 64 + am * 16 + ln;
            int sl = (g ^ ((m_loc >> 1) & 3)) * 8;
            fah[am] = *(const s16x8*)&Ah[m_loc * 32 + sl];
            fal[am] = *(const s16x8*)&Al[m_loc * 32 + sl];
        }
#pragma unroll
        for (int bn = 0; bn < 4; ++bn) {
            int n_loc = wn * 64 + bn * 16 + ln;
            int sl = (g ^ ((n_loc >> 1) & 3)) * 8;
            fbh[bn] = *(const s16x8*)&Bh[n_loc * 32 + sl];
            fbl[bn] = *(const s16x8*)&Bl[n_loc * 32 + sl];
        }
#pragma unroll
        for (int am = 0; am < 4; ++am)
#pragma unroll
            for (int bn = 0; bn < 4; ++bn)
                acc[am][bn] = MFMA16(fah[am], fbh[bn], acc[am][bn]);
#pragma unroll
        for (int am = 0; am < 4; ++am)
#pragma unroll
            for (int bn = 0; bn < 4; ++bn)
                acc[am][bn] = MFMA16(fah[am], fbl[bn], acc[am][bn]);
#pragma unroll
        for (int am = 0; am < 4; ++am)
#pragma unroll
            for (int bn = 0; bn < 4; ++bn)
                acc[am][bn] = MFMA16(fal[am], fbh[bn], acc[am][bn]);
    }

#pragma unroll
    for (int am = 0; am < 4; ++am)
#pragma unroll
        for (int bn = 0; bn < 4; ++bn) {
            int n = n0 + wn * 64 + bn * 16 + ln;
            float bv = bias[n];
#pragma unroll
            for (int r = 0; r < 4; ++r) {
                int m = m0 + wm * 64 + am * 16 + g * 4 + r;
                out[(size_t)m * ND + n] = acc[am][bn][r] + bv;
            }
        }
}

// ---------------------------------------------------------------------------
extern "C" void kernel_launch(void* const* d_in, const int* in_sizes, int n_in,
                              void* d_out, int out_size, void* d_ws, size_t ws_size,
                              hipStream_t stream)
{
    const float* x     = (const float*)d_in[0];
    const float* W_kqv = (const float*)d_in[1];
    const float* b_kqv = (const float*)d_in[2];
    const float* W_out = (const float*)d_in[3];
    const float* b_out = (const float*)d_in[4];
    float* out = (float*)d_out;

    char* ws = (char*)d_ws;
    const size_t MB = 1024 * 1024;
    unsigned short* Qh = (unsigned short*)(ws);
    unsigned short* Ql = Qh + 4194304;
    unsigned short* Kh = Ql + 4194304;
    unsigned short* Kl = Kh + 4194304;
    unsigned short* Vh = Kl + 4194304;
    unsigned short* Vl = Vh + 4194304;
    unsigned short* WhT = (unsigned short*)(ws + 48 * MB);
    unsigned short* WlT = WhT + 3145728;
    unsigned short* Yh  = (unsigned short*)(ws + 48 * MB);
    unsigned short* Yl  = Yh + 4194304;
    unsigned short* WoTh = (unsigned short*)(ws);
    unsigned short* WoTl = WoTh + 1048576;
    // Xh lives in d_out (8 MB of 16): dead until out_gemm rewrites all of it.
    unsigned short* Xh = (unsigned short*)d_out;

    splitX_kernel<<<dim3(MTOT * EMBED / (256 * 8)), 256, 0, stream>>>(x, Xh);
    splitT_kernel<<<dim3(3 * EMBED / 32, EMBED / 32), 256, 0, stream>>>(
        W_kqv, WhT, WlT, EMBED, 3 * EMBED);
    qkv_gemm_kernel<<<dim3(768), 256, 0, stream>>>(
        Xh, WhT, WlT, b_kqv, Qh, Ql, Kh, Kl, Vh, Vl);
    attn_kernel<<<dim3(BHTOT * (SEQ / 128)), 256, 0, stream>>>(
        Qh, Ql, Kh, Kl, Vh, Vl, Yh, Yl);
    splitT_kernel<<<dim3(EMBED / 32, EMBED / 32), 256, 0, stream>>>(
        W_out, WoTh, WoTl, EMBED, EMBED);
    out_gemm_kernel<<<dim3(256), 256, 0, stream>>>(
        Yh, Yl, WoTh, WoTl, b_out, out);
}

// Round 13
// 193.037 us; speedup vs baseline: 1.0239x; 1.0239x over previous
//
#include <hip/hip_runtime.h>
#include <math.h>

#define EMBED 1024
#define NH    16
#define DH    64
#define BATCH 2
#define SEQ   2048
#define MTOT  4096
#define BHTOT 32

typedef float f32x4  __attribute__((ext_vector_type(4)));
typedef float f32x16 __attribute__((ext_vector_type(16)));
typedef short s16x8  __attribute__((ext_vector_type(8)));
typedef short s16x4  __attribute__((ext_vector_type(4)));
typedef unsigned u32x2 __attribute__((ext_vector_type(2)));
typedef unsigned u32x4 __attribute__((ext_vector_type(4)));

#define AS1 __attribute__((address_space(1)))
#define AS3 __attribute__((address_space(3)))

__device__ __forceinline__ unsigned short bf16_rne(float f) {
    unsigned u = __builtin_bit_cast(unsigned, f);
    return (unsigned short)((u + 0x7FFFu + ((u >> 16) & 1u)) >> 16);
}
__device__ __forceinline__ float bf16_f(unsigned short h) {
    unsigned u = ((unsigned)h) << 16;
    return __builtin_bit_cast(float, u);
}
__device__ __forceinline__ void split2(float v, unsigned short& hi, unsigned short& lo) {
    hi = bf16_rne(v);
    lo = bf16_rne(v - bf16_f(hi));
}
__device__ __forceinline__ void gload16(const void* g, void* l) {
    __builtin_amdgcn_global_load_lds((const AS1 void*)g, (AS3 void*)l, 16, 0, 0);
}
__device__ __forceinline__ unsigned cvt_pk_bf16(float lo, float hi) {
    unsigned r;
    asm volatile("v_cvt_pk_bf16_f32 %0, %1, %2" : "=v"(r) : "v"(lo), "v"(hi));
    return r;
}
#define MFMA16(a, b, c) __builtin_amdgcn_mfma_f32_16x16x32_bf16((a), (b), (c), 0, 0, 0)
#define MFMA32(a, b, c) __builtin_amdgcn_mfma_f32_32x32x16_bf16((a), (b), (c), 0, 0, 0)

// ---------------------------------------------------------------------------
// splitX: X fp32 [M][K] -> Xh bf16 only
// ---------------------------------------------------------------------------
__global__ __launch_bounds__(256)
void splitX_kernel(const float* __restrict__ X, unsigned short* __restrict__ Xh)
{
    const size_t i = ((size_t)blockIdx.x * 256 + threadIdx.x) * 8;
    float4 a = *(const float4*)&X[i];
    float4 b = *(const float4*)&X[i + 4];
    float v[8] = {a.x, a.y, a.z, a.w, b.x, b.y, b.z, b.w};
    s16x8 h8;
#pragma unroll
    for (int e = 0; e < 8; ++e) h8[e] = (short)bf16_rne(v[e]);
    *(s16x8*)&Xh[i] = h8;
}

// ---------------------------------------------------------------------------
// splitT: W fp32 [Kd][Nd]  ->  HiT, LoT bf16 [Nd][Kd] (transposed + hi/lo split)
// ---------------------------------------------------------------------------
__global__ __launch_bounds__(256)
void splitT_kernel(const float* __restrict__ W, unsigned short* __restrict__ HiT,
                   unsigned short* __restrict__ LoT, int Kd, int Nd)
{
    __shared__ float T[32][33];
    const int tid = threadIdx.x;
    const int n0 = blockIdx.x * 32, k0 = blockIdx.y * 32;
    {
        const int row = tid >> 3, c4 = (tid & 7) * 4;
        float4 v = *(const float4*)&W[(size_t)(k0 + row) * Nd + n0 + c4];
        T[row][c4] = v.x; T[row][c4 + 1] = v.y; T[row][c4 + 2] = v.z; T[row][c4 + 3] = v.w;
    }
    __syncthreads();
    {
        const int nr = tid >> 3, c4 = (tid & 7) * 4;
        s16x4 h4, l4;
#pragma unroll
        for (int e = 0; e < 4; ++e) {
            unsigned short h, l;
            split2(T[c4 + e][nr], h, l);
            h4[e] = (short)h; l4[e] = (short)l;
        }
        *(s16x4*)&HiT[(size_t)(n0 + nr) * Kd + k0 + c4] = h4;
        *(s16x4*)&LoT[(size_t)(n0 + nr) * Kd + k0 + c4] = l4;
    }
}

// ---------------------------------------------------------------------------
// QKV GEMM, 2-combo split (Ah.Bh + Ah.Bl), double-buffered 48 KB LDS with
// COUNTED-VMCNT pipeline: stage(next) -> vmcnt(6) -> raw s_barrier ->
// ds_read+MFMA -> raw s_barrier. No vmcnt(0) drain in the main loop.
// 128x128 tile, BK=32, XCD-swizzled grid, combo-outer MFMA.
// ---------------------------------------------------------------------------
__global__ __launch_bounds__(256)
void qkv_gemm_kernel(const unsigned short* __restrict__ Xh_g,
                     const unsigned short* __restrict__ BhT, const unsigned short* __restrict__ BlT,
                     const float* __restrict__ bias,
                     unsigned short* __restrict__ Qh, unsigned short* __restrict__ Ql,
                     unsigned short* __restrict__ Kh, unsigned short* __restrict__ Kl,
                     unsigned short* __restrict__ Vh, unsigned short* __restrict__ Vl)
{
    constexpr int KD = 1024;
    // per buf (shorts): Ah [0,4096) Bh [4096,8192) Bl [8192,12288)
    __shared__ __align__(16) short SB[2][12288];   // 48 KB total

    const int tid = threadIdx.x, lane = tid & 63, wid = tid >> 6;
    const int g = lane >> 4, ln = lane & 15;
    const int wm = wid >> 1, wn = wid & 1;

    // XCD swizzle: xcd = bid&7 owns 96 tiles = 4 m-rows x 24 n (m-fastest)
    const int bid = blockIdx.x;
    const int u = bid >> 3, xcd = bid & 7;
    const int by = xcd * 4 + (u & 3);   // m-tile 0..31
    const int bx = u >> 2;              // n-tile 0..23
    const int m0 = by * 128, n0 = bx * 128;

    f32x4 acc[4][4];
#pragma unroll
    for (int i = 0; i < 4; ++i)
#pragma unroll
        for (int j = 0; j < 4; ++j) acc[i][j] = (f32x4){0.f, 0.f, 0.f, 0.f};

    const int srow = lane >> 2, ss = lane & 3;

    // 24 staging segments (3 tiles x 8), 6 per wave.
    // prologue: stage k-tile 0 into buf 0 (6 loads in flight per wave)
    {
#pragma unroll
        for (int i = 0; i < 6; ++i) {
            const int s = wid * 6 + i;
            const int t = s >> 3, j = s & 7;
            const unsigned short* gsrc = (t == 0) ? Xh_g : (t == 1) ? BhT : BlT;
            const int roff = (t == 0) ? m0 : n0;
            const int row_loc = j * 16 + srow;
            const int kc = ss ^ ((row_loc >> 1) & 3);
            gload16(gsrc + (size_t)(roff + row_loc) * KD + kc * 8,
                    &SB[0][t * 4096 + j * 512]);
        }
    }

    for (int it = 0; it < 32; ++it) {
        const int cur = it & 1;
        if (it + 1 < 32) {
            // issue next tile's loads into the other buffer (6 per wave)
            const int k0n = (it + 1) * 32;
#pragma unroll
            for (int i = 0; i < 6; ++i) {
                const int s = wid * 6 + i;
                const int t = s >> 3, j = s & 7;
                const unsigned short* gsrc = (t == 0) ? Xh_g : (t == 1) ? BhT : BlT;
                const int roff = (t == 0) ? m0 : n0;
                const int row_loc = j * 16 + srow;
                const int kc = ss ^ ((row_loc >> 1) & 3);
                gload16(gsrc + (size_t)(roff + row_loc) * KD + k0n + kc * 8,
                        &SB[cur ^ 1][t * 4096 + j * 512]);
            }
            // wait for buf[cur]'s 6 loads (oldest); leave the 6 new in flight
            asm volatile("s_waitcnt vmcnt(6)" ::: "memory");
        } else {
            asm volatile("s_waitcnt vmcnt(0)" ::: "memory");
        }
        __builtin_amdgcn_s_barrier();        // all waves: buf[cur] fully landed
        __builtin_amdgcn_sched_barrier(0);   // rule 18: no hoisting past the wait

        const short* Ah = &SB[cur][0];
        const short* Bh = &SB[cur][4096];
        const short* Bl = &SB[cur][8192];

        s16x8 fah[4], fbh[4], fbl[4];
#pragma unroll
        for (int am = 0; am < 4; ++am) {
            int m_loc = wm * 64 + am * 16 + ln;
            int sl = (g ^ ((m_loc >> 1) & 3)) * 8;
            fah[am] = *(const s16x8*)&Ah[m_loc * 32 + sl];
        }
#pragma unroll
        for (int bn = 0; bn < 4; ++bn) {
            int n_loc = wn * 64 + bn * 16 + ln;
            int sl = (g ^ ((n_loc >> 1) & 3)) * 8;
            fbh[bn] = *(const s16x8*)&Bh[n_loc * 32 + sl];
            fbl[bn] = *(const s16x8*)&Bl[n_loc * 32 + sl];
        }
        // combo-outer: reuse distance 16 on each accumulator
#pragma unroll
        for (int am = 0; am < 4; ++am)
#pragma unroll
            for (int bn = 0; bn < 4; ++bn)
                acc[am][bn] = MFMA16(fah[am], fbh[bn], acc[am][bn]);
#pragma unroll
        for (int am = 0; am < 4; ++am)
#pragma unroll
            for (int bn = 0; bn < 4; ++bn)
                acc[am][bn] = MFMA16(fah[am], fbl[bn], acc[am][bn]);

        // readers of buf[cur] done (lgkm waits precede the MFMAs);
        // safe for next iteration to overwrite buf[cur].
        __builtin_amdgcn_s_barrier();
    }

    // epilogue: bias + split scatter (C/D: row=(lane>>4)*4+r, col=lane&15)
#pragma unroll
    for (int am = 0; am < 4; ++am)
#pragma unroll
        for (int bn = 0; bn < 4; ++bn) {
            int n = n0 + wn * 64 + bn * 16 + ln;
            float bv = bias[n];
            int sec = n >> 10, cc = n & 1023, h = cc >> 6, d = cc & 63;
#pragma unroll
            for (int r = 0; r < 4; ++r) {
                int m = m0 + wm * 64 + am * 16 + g * 4 + r;
                int bb = m >> 11, t = m & 2047;
                int bh_i = bb * NH + h;
                float val = acc[am][bn][r] + bv;
                unsigned short hi, lo;
                if (sec == 0) {
                    val *= 0.125f; split2(val, hi, lo);
                    size_t idx = ((size_t)bh_i * SEQ + t) * DH + d;
                    Qh[idx] = hi; Ql[idx] = lo;
                } else if (sec == 1) {
                    split2(val, hi, lo);
                    size_t idx = ((size_t)bh_i * SEQ + t) * DH + d;
                    Kh[idx] = hi; Kl[idx] = lo;
                } else {
                    split2(val, hi, lo);
                    size_t idx = ((size_t)bh_i * DH + d) * SEQ + t;   // V transposed
                    Vh[idx] = hi; Vl[idx] = lo;
                }
            }
        }
}

// ---------------------------------------------------------------------------
// Attention, 32x32 swapped-operand structure + 2-phase pipelined K/V staging
// (double-buffered, 64 KB LDS). Defer-max THR=8; interleaved MFMA
// accumulators. (unchanged from r11)
// ---------------------------------------------------------------------------
__global__ __launch_bounds__(256)
void attn_kernel(const unsigned short* __restrict__ Qh_g, const unsigned short* __restrict__ Ql_g,
                 const unsigned short* __restrict__ Kh_g, const unsigned short* __restrict__ Kl_g,
                 const unsigned short* __restrict__ Vh_g, const unsigned short* __restrict__ Vl_g,
                 unsigned short* __restrict__ Yh, unsigned short* __restrict__ Yl)
{
    __shared__ __align__(16) short SM[2][16384];   // 64 KB: 2 bufs x {Kh,Kl,Vh,Vl}

    const int tid = threadIdx.x, lane = tid & 63, wid = tid >> 6;
    const int l31 = lane & 31, l5 = lane >> 5;
    const int bid = blockIdx.x;
    const int qb = 15 - (bid >> 5), bh = bid & 31;   // heavy q-tiles first
    const int Q0 = qb * 128;
    const int qg = Q0 + wid * 32 + l31;              // this lane's q row

    // Q fragments from global (once per block)
    s16x8 qfh[4], qfl[4];
    {
        const size_t qo = ((size_t)bh * SEQ + qg) * DH;
#pragma unroll
        for (int t = 0; t < 4; ++t) {
            const int ch = t * 2 + l5;
            qfh[t] = *(const s16x8*)&Qh_g[qo + ch * 8];
            qfl[t] = *(const s16x8*)&Ql_g[qo + ch * 8];
        }
    }

    float m_i = -INFINITY, l_i = 0.f;
    f32x16 yacc[2];
#pragma unroll
    for (int e = 0; e < 16; ++e) { yacc[0][e] = 0.f; yacc[1][e] = 0.f; }

    const int srow = lane >> 3, ss = lane & 7;
    const int KT = 2 * qb + 2;
    const unsigned short* gb = (wid == 0) ? Kh_g : (wid == 1) ? Kl_g
                             : (wid == 2) ? Vh_g : Vl_g;
    const bool isK = (wid < 2);

    // prologue: stage kv-tile 0 into buf 0
    {
        short* lb = &SM[0][wid * 4096];
#pragma unroll
        for (int j = 0; j < 8; ++j) {
            int row = j * 8 + srow;
            int kc = ss ^ (row & 7);
            const unsigned short* src = isK
                ? gb + ((size_t)bh * SEQ + row) * DH + kc * 8
                : gb + ((size_t)bh * DH + row) * SEQ + kc * 8;
            gload16(src, lb + j * 512);
        }
    }

    for (int kt = 0; kt < KT; ++kt) {
        const int cur = kt & 1;
        __syncthreads();   // stage(kt) landed; reads of buf[cur] (kt-2) done
        if (kt + 1 < KT) {
            short* lb = &SM[cur ^ 1][wid * 4096];
            const int kn = (kt + 1) * 64;
#pragma unroll
            for (int j = 0; j < 8; ++j) {
                int row = j * 8 + srow;
                int kc = ss ^ (row & 7);
                const unsigned short* src = isK
                    ? gb + ((size_t)bh * SEQ + kn + row) * DH + kc * 8
                    : gb + ((size_t)bh * DH + row) * SEQ + kn + kc * 8;
                gload16(src, lb + j * 512);
            }
        }

        if (kt * 64 > Q0 + wid * 32 + 31) continue;   // fully masked for this wave

        const short* Ksh = &SM[cur][0];
        const short* Ksl = &SM[cur][4096];
        const short* Vsh = &SM[cur][8192];
        const short* Vsl = &SM[cur][12288];

        // ---- S^T = K . Q  (3-combo split; interleaved kb -> distance-2 chains)
        f32x16 s[2];
#pragma unroll
        for (int e = 0; e < 16; ++e) { s[0][e] = 0.f; s[1][e] = 0.f; }
#pragma unroll
        for (int t = 0; t < 4; ++t) {
            s16x8 kh[2], kl[2];
#pragma unroll
            for (int kb = 0; kb < 2; ++kb) {
                const int row = kb * 32 + l31;
                const int sl = ((t * 2 + l5) ^ (row & 7)) * 8;
                kh[kb] = *(const s16x8*)&Ksh[row * 64 + sl];
                kl[kb] = *(const s16x8*)&Ksl[row * 64 + sl];
            }
#pragma unroll
            for (int kb = 0; kb < 2; ++kb) s[kb] = MFMA32(kh[kb], qfh[t], s[kb]);
#pragma unroll
            for (int kb = 0; kb < 2; ++kb) s[kb] = MFMA32(kl[kb], qfh[t], s[kb]);
#pragma unroll
            for (int kb = 0; kb < 2; ++kb) s[kb] = MFMA32(kh[kb], qfl[t], s[kb]);
        }

        // ---- causal mask (only near the diagonal)
        if (kt * 64 + 63 > Q0 + wid * 32) {
#pragma unroll
            for (int kb = 0; kb < 2; ++kb)
#pragma unroll
                for (int r = 0; r < 16; ++r) {
                    const int key = kt * 64 + kb * 32 + (r & 3) + 8 * (r >> 2) + 4 * l5;
                    if (key > qg) s[kb][r] = -INFINITY;
                }
        }

        // ---- online softmax, in-register (q = lane&31), defer-max THR=8
        float mx = s[0][0];
#pragma unroll
        for (int r = 1; r < 16; ++r) mx = fmaxf(mx, s[0][r]);
#pragma unroll
        for (int r = 0; r < 16; ++r) mx = fmaxf(mx, s[1][r]);
        mx = fmaxf(mx, __shfl_xor(mx, 32));
        const bool defer = (__all(mx - m_i <= 8.f) != 0);
        float mref;
        if (defer) {
            mref = m_i;
        } else {
            mref = fmaxf(m_i, mx);
            const float al = __expf(m_i - mref);
            m_i = mref;
            l_i *= al;
#pragma unroll
            for (int e = 0; e < 16; ++e) { yacc[0][e] *= al; yacc[1][e] *= al; }
        }
        float ls = 0.f;
#pragma unroll
        for (int kb = 0; kb < 2; ++kb)
#pragma unroll
            for (int r = 0; r < 16; ++r) {
                s[kb][r] = __expf(s[kb][r] - mref);
                ls += s[kb][r];
            }
        ls += __shfl_xor(ls, 32);
        l_i += ls;

        // ---- P (bf16) fragments in-register: cvt_pk + permlane32_swap
        unsigned pk[2][8];
#pragma unroll
        for (int kb = 0; kb < 2; ++kb)
#pragma unroll
            for (int j = 0; j < 8; ++j)
                pk[kb][j] = cvt_pk_bf16(s[kb][2 * j], s[kb][2 * j + 1]);
        s16x8 pf[2][2];
#pragma unroll
        for (int kb = 0; kb < 2; ++kb) {
            u32x2 sA = __builtin_amdgcn_permlane32_swap(pk[kb][0], pk[kb][2], false, false);
            u32x2 sB = __builtin_amdgcn_permlane32_swap(pk[kb][1], pk[kb][3], false, false);
            u32x4 w0 = {sA[0], sB[0], sA[1], sB[1]};
            pf[kb][0] = __builtin_bit_cast(s16x8, w0);
            u32x2 sC = __builtin_amdgcn_permlane32_swap(pk[kb][4], pk[kb][6], false, false);
            u32x2 sD = __builtin_amdgcn_permlane32_swap(pk[kb][5], pk[kb][7], false, false);
            u32x4 w1 = {sC[0], sD[0], sC[1], sD[1]};
            pf[kb][1] = __builtin_bit_cast(s16x8, w1);
        }

        // ---- Y^T += V^T . P  (interleaved dt -> distance-2 chains)
#pragma unroll
        for (int t = 0; t < 4; ++t) {
            s16x8 vh[2], vl[2];
#pragma unroll
            for (int dt = 0; dt < 2; ++dt) {
                const int row = dt * 32 + l31;
                const int sl = ((t * 2 + l5) ^ (row & 7)) * 8;
                vh[dt] = *(const s16x8*)&Vsh[row * 64 + sl];
                vl[dt] = *(const s16x8*)&Vsl[row * 64 + sl];
            }
            const s16x8 pfr = pf[t >> 1][t & 1];
#pragma unroll
            for (int dt = 0; dt < 2; ++dt) yacc[dt] = MFMA32(vh[dt], pfr, yacc[dt]);
#pragma unroll
            for (int dt = 0; dt < 2; ++dt) yacc[dt] = MFMA32(vl[dt], pfr, yacc[dt]);
        }
    }

    // ---- epilogue: normalize, split, LDS transpose bounce, coalesced write
    __syncthreads();   // everyone done with K/V LDS
    short* SMf = &SM[0][0];
    const float inv = 1.f / l_i;
    const int qlcl = wid * 32 + l31;
#pragma unroll
    for (int dt = 0; dt < 2; ++dt)
#pragma unroll
        for (int rq = 0; rq < 4; ++rq) {
            const int d0 = dt * 32 + rq * 8 + 4 * l5;
            s16x4 h4, l4;
#pragma unroll
            for (int c = 0; c < 4; ++c) {
                unsigned short hh, ll;
                split2(yacc[dt][rq * 4 + c] * inv, hh, ll);
                h4[c] = (short)hh; l4[c] = (short)ll;
            }
            const int base = qlcl * 64 + (((d0 >> 3) ^ (qlcl & 7)) * 8) + (d0 & 7);
            *(s16x4*)&SMf[base] = h4;
            *(s16x4*)&SMf[8192 + base] = l4;
        }
    __syncthreads();
    const int b = bh >> 4, h = bh & 15;
#pragma unroll
    for (int i = 0; i < 4; ++i) {
        const int idx = tid + i * 256;
        const int row = idx >> 3, ch = idx & 7;
        const int sl = (ch ^ (row & 7)) * 8;
        s16x8 vh8 = *(const s16x8*)&SMf[row * 64 + sl];
        s16x8 vl8 = *(const s16x8*)&SMf[8192 + row * 64 + sl];
        const size_t o = ((size_t)(b * SEQ + Q0 + row)) * EMBED + h * DH + ch * 8;
        *(s16x8*)&Yh[o] = vh8;
        *(s16x8*)&Yl[o] = vl8;
    }
}

// ---------------------------------------------------------------------------
// Out GEMM: 2-phase pipelined staging, XCD-swizzled, combo-outer MFMA.
// (unchanged from r11)
// ---------------------------------------------------------------------------
__global__ __launch_bounds__(256)
void out_gemm_kernel(const unsigned short* __restrict__ Yh_g, const unsigned short* __restrict__ Yl_g,
                     const unsigned short* __restrict__ WhT, const unsigned short* __restrict__ WlT,
                     const float* __restrict__ bias, float* __restrict__ out)
{
    constexpr int KD = 1024, ND = 1024;
    __shared__ __align__(16) short SB[2][16384];   // 64 KB

    const int tid = threadIdx.x, lane = tid & 63, wid = tid >> 6;
    const int g = lane >> 4, ln = lane & 15;
    const int wm = wid >> 1, wn = wid & 1;

    const int bid = blockIdx.x;
    const int u = bid >> 3, xcd = bid & 7;
    const int by = xcd * 4 + (u & 3);   // m-tile 0..31
    const int bx = u >> 2;              // n-tile 0..7
    const int m0 = by * 128, n0 = bx * 128;

    f32x4 acc[4][4];
#pragma unroll
    for (int i = 0; i < 4; ++i)
#pragma unroll
        for (int j = 0; j < 4; ++j) acc[i][j] = (f32x4){0.f, 0.f, 0.f, 0.f};

    const int srow = lane >> 2, ss = lane & 3;
    const unsigned short* gb = (wid == 0) ? Yh_g : (wid == 1) ? Yl_g
                             : (wid == 2) ? WhT  : WlT;
    const int roff = (wid < 2) ? m0 : n0;

    {
        short* lb = &SB[0][wid * 4096];
#pragma unroll
        for (int j = 0; j < 8; ++j) {
            int row_loc = j * 16 + srow;
            int kc = ss ^ ((row_loc >> 1) & 3);
            gload16(gb + (size_t)(roff + row_loc) * KD + kc * 8, lb + j * 512);
        }
    }

    for (int it = 0; it < 32; ++it) {
        const int cur = it & 1;
        __syncthreads();
        if (it + 1 < 32) {
            short* lb = &SB[cur ^ 1][wid * 4096];
            const int k0n = (it + 1) * 32;
#pragma unroll
            for (int j = 0; j < 8; ++j) {
                int row_loc = j * 16 + srow;
                int kc = ss ^ ((row_loc >> 1) & 3);
                gload16(gb + (size_t)(roff + row_loc) * KD + k0n + kc * 8, lb + j * 512);
            }
        }
        const short* Ah = &SB[cur][0];
        const short* Al = &SB[cur][4096];
        const short* Bh = &SB[cur][8192];
        const short* Bl = &SB[cur][12288];

        s16x8 fah[4], fal[4], fbh[4], fbl[4];
#pragma unroll
        for (int am = 0; am < 4; ++am) {
            int m_loc = wm * 64 + am * 16 + ln;
            int sl = (g ^ ((m_loc >> 1) & 3)) * 8;
            fah[am] = *(const s16x8*)&Ah[m_loc * 32 + sl];
            fal[am] = *(const s16x8*)&Al[m_loc * 32 + sl];
        }
#pragma unroll
        for (int bn = 0; bn < 4; ++bn) {
            int n_loc = wn * 64 + bn * 16 + ln;
            int sl = (g ^ ((n_loc >> 1) & 3)) * 8;
            fbh[bn] = *(const s16x8*)&Bh[n_loc * 32 + sl];
            fbl[bn] = *(const s16x8*)&Bl[n_loc * 32 + sl];
        }
#pragma unroll
        for (int am = 0; am < 4; ++am)
#pragma unroll
            for (int bn = 0; bn < 4; ++bn)
                acc[am][bn] = MFMA16(fah[am], fbh[bn], acc[am][bn]);
#pragma unroll
        for (int am = 0; am < 4; ++am)
#pragma unroll
            for (int bn = 0; bn < 4; ++bn)
                acc[am][bn] = MFMA16(fah[am], fbl[bn], acc[am][bn]);
#pragma unroll
        for (int am = 0; am < 4; ++am)
#pragma unroll
            for (int bn = 0; bn < 4; ++bn)
                acc[am][bn] = MFMA16(fal[am], fbh[bn], acc[am][bn]);
    }

#pragma unroll
    for (int am = 0; am < 4; ++am)
#pragma unroll
        for (int bn = 0; bn < 4; ++bn) {
            int n = n0 + wn * 64 + bn * 16 + ln;
            float bv = bias[n];
#pragma unroll
            for (int r = 0; r < 4; ++r) {
                int m = m0 + wm * 64 + am * 16 + g * 4 + r;
                out[(size_t)m * ND + n] = acc[am][bn][r] + bv;
            }
        }
}

// ---------------------------------------------------------------------------
extern "C" void kernel_launch(void* const* d_in, const int* in_sizes, int n_in,
                              void* d_out, int out_size, void* d_ws, size_t ws_size,
                              hipStream_t stream)
{
    const float* x     = (const float*)d_in[0];
    const float* W_kqv = (const float*)d_in[1];
    const float* b_kqv = (const float*)d_in[2];
    const float* W_out = (const float*)d_in[3];
    const float* b_out = (const float*)d_in[4];
    float* out = (float*)d_out;

    char* ws = (char*)d_ws;
    const size_t MB = 1024 * 1024;
    unsigned short* Qh = (unsigned short*)(ws);
    unsigned short* Ql = Qh + 4194304;
    unsigned short* Kh = Ql + 4194304;
    unsigned short* Kl = Kh + 4194304;
    unsigned short* Vh = Kl + 4194304;
    unsigned short* Vl = Vh + 4194304;
    unsigned short* WhT = (unsigned short*)(ws + 48 * MB);
    unsigned short* WlT = WhT + 3145728;
    unsigned short* Yh  = (unsigned short*)(ws + 48 * MB);
    unsigned short* Yl  = Yh + 4194304;
    unsigned short* WoTh = (unsigned short*)(ws);
    unsigned short* WoTl = WoTh + 1048576;
    // Xh lives in d_out (8 MB of 16): dead until out_gemm rewrites all of it.
    unsigned short* Xh = (unsigned short*)d_out;

    splitX_kernel<<<dim3(MTOT * EMBED / (256 * 8)), 256, 0, stream>>>(x, Xh);
    splitT_kernel<<<dim3(3 * EMBED / 32, EMBED / 32), 256, 0, stream>>>(
        W_kqv, WhT, WlT, EMBED, 3 * EMBED);
    qkv_gemm_kernel<<<dim3(768), 256, 0, stream>>>(
        Xh, WhT, WlT, b_kqv, Qh, Ql, Kh, Kl, Vh, Vl);
    attn_kernel<<<dim3(BHTOT * (SEQ / 128)), 256, 0, stream>>>(
        Qh, Ql, Kh, Kl, Vh, Vl, Yh, Yl);
    splitT_kernel<<<dim3(EMBED / 32, EMBED / 32), 256, 0, stream>>>(
        W_out, WoTh, WoTl, EMBED, EMBED);
    out_gemm_kernel<<<dim3(256), 256, 0, stream>>>(
        Yh, Yl, WoTh, WoTl, b_out, out);
}

// Round 14
// 188.437 us; speedup vs baseline: 1.0489x; 1.0244x over previous
//
#include <hip/hip_runtime.h>
#include <math.h>

#define EMBED 1024
#define NH    16
#define DH    64
#define BATCH 2
#define SEQ   2048
#define MTOT  4096
#define BHTOT 32

typedef float f32x4  __attribute__((ext_vector_type(4)));
typedef float f32x16 __attribute__((ext_vector_type(16)));
typedef short s16x8  __attribute__((ext_vector_type(8)));
typedef short s16x4  __attribute__((ext_vector_type(4)));
typedef unsigned u32x2 __attribute__((ext_vector_type(2)));
typedef unsigned u32x4 __attribute__((ext_vector_type(4)));

#define AS1 __attribute__((address_space(1)))
#define AS3 __attribute__((address_space(3)))

__device__ __forceinline__ unsigned short bf16_rne(float f) {
    unsigned u = __builtin_bit_cast(unsigned, f);
    return (unsigned short)((u + 0x7FFFu + ((u >> 16) & 1u)) >> 16);
}
__device__ __forceinline__ float bf16_f(unsigned short h) {
    unsigned u = ((unsigned)h) << 16;
    return __builtin_bit_cast(float, u);
}
__device__ __forceinline__ void split2(float v, unsigned short& hi, unsigned short& lo) {
    hi = bf16_rne(v);
    lo = bf16_rne(v - bf16_f(hi));
}
__device__ __forceinline__ void gload16(const void* g, void* l) {
    __builtin_amdgcn_global_load_lds((const AS1 void*)g, (AS3 void*)l, 16, 0, 0);
}
__device__ __forceinline__ unsigned cvt_pk_bf16(float lo, float hi) {
    unsigned r;
    asm volatile("v_cvt_pk_bf16_f32 %0, %1, %2" : "=v"(r) : "v"(lo), "v"(hi));
    return r;
}
#define MFMA16(a, b, c) __builtin_amdgcn_mfma_f32_16x16x32_bf16((a), (b), (c), 0, 0, 0)
#define MFMA32(a, b, c) __builtin_amdgcn_mfma_f32_32x32x16_bf16((a), (b), (c), 0, 0, 0)

// ---------------------------------------------------------------------------
// prep: one kernel for splitX (blocks [0,2048)), splitT of Wkqv
// (blocks [2048,5120)), and optionally splitT of Wout (blocks [5120,6144)).
// ---------------------------------------------------------------------------
__global__ __launch_bounds__(256)
void prep_kernel(const float* __restrict__ X, const float* __restrict__ Wkqv,
                 const float* __restrict__ Wout,
                 unsigned short* __restrict__ Xh,
                 unsigned short* __restrict__ WhT, unsigned short* __restrict__ WlT,
                 unsigned short* __restrict__ WoTh, unsigned short* __restrict__ WoTl)
{
    __shared__ float T[32][33];
    const int bid = blockIdx.x, tid = threadIdx.x;

    if (bid < 2048) {   // ---- splitX: X fp32 -> Xh bf16
        const size_t i = ((size_t)bid * 256 + tid) * 8;
        float4 a = *(const float4*)&X[i];
        float4 b = *(const float4*)&X[i + 4];
        float v[8] = {a.x, a.y, a.z, a.w, b.x, b.y, b.z, b.w};
        s16x8 h8;
#pragma unroll
        for (int e = 0; e < 8; ++e) h8[e] = (short)bf16_rne(v[e]);
        *(s16x8*)&Xh[i] = h8;
        return;
    }

    // ---- splitT: W fp32 [Kd][Nd] -> Hi/Lo bf16 [Nd][Kd]
    const float* W;
    unsigned short *Hi, *Lo;
    int Nd, n0, k0;
    if (bid < 5120) {
        const int u = bid - 2048;                 // 0..3071
        W = Wkqv; Hi = WhT; Lo = WlT; Nd = 3072;
        n0 = (u % 96) * 32; k0 = (u / 96) * 32;
    } else {
        const int u = bid - 5120;                 // 0..1023
        W = Wout; Hi = WoTh; Lo = WoTl; Nd = 1024;
        n0 = (u & 31) * 32; k0 = (u >> 5) * 32;
    }
    constexpr int Kd = 1024;
    {
        const int row = tid >> 3, c4 = (tid & 7) * 4;
        float4 v = *(const float4*)&W[(size_t)(k0 + row) * Nd + n0 + c4];
        T[row][c4] = v.x; T[row][c4 + 1] = v.y; T[row][c4 + 2] = v.z; T[row][c4 + 3] = v.w;
    }
    __syncthreads();
    {
        const int nr = tid >> 3, c4 = (tid & 7) * 4;
        s16x4 h4, l4;
#pragma unroll
        for (int e = 0; e < 4; ++e) {
            unsigned short h, l;
            split2(T[c4 + e][nr], h, l);
            h4[e] = (short)h; l4[e] = (short)l;
        }
        *(s16x4*)&Hi[(size_t)(n0 + nr) * Kd + k0 + c4] = h4;
        *(s16x4*)&Lo[(size_t)(n0 + nr) * Kd + k0 + c4] = l4;
    }
}

// ---------------------------------------------------------------------------
// splitT (standalone fallback, used only when ws is too small to host WoT
// before attn finishes).
// ---------------------------------------------------------------------------
__global__ __launch_bounds__(256)
void splitT_kernel(const float* __restrict__ W, unsigned short* __restrict__ HiT,
                   unsigned short* __restrict__ LoT, int Kd, int Nd)
{
    __shared__ float T[32][33];
    const int tid = threadIdx.x;
    const int n0 = blockIdx.x * 32, k0 = blockIdx.y * 32;
    {
        const int row = tid >> 3, c4 = (tid & 7) * 4;
        float4 v = *(const float4*)&W[(size_t)(k0 + row) * Nd + n0 + c4];
        T[row][c4] = v.x; T[row][c4 + 1] = v.y; T[row][c4 + 2] = v.z; T[row][c4 + 3] = v.w;
    }
    __syncthreads();
    {
        const int nr = tid >> 3, c4 = (tid & 7) * 4;
        s16x4 h4, l4;
#pragma unroll
        for (int e = 0; e < 4; ++e) {
            unsigned short h, l;
            split2(T[c4 + e][nr], h, l);
            h4[e] = (short)h; l4[e] = (short)l;
        }
        *(s16x4*)&HiT[(size_t)(n0 + nr) * Kd + k0 + c4] = h4;
        *(s16x4*)&LoT[(size_t)(n0 + nr) * Kd + k0 + c4] = l4;
    }
}

// ---------------------------------------------------------------------------
// QKV GEMM (r11 best): 2-combo split (Ah.Bh + Ah.Bl), double-buffered 48 KB
// LDS, issue-early staging with plain __syncthreads. 128x128 tile, BK=32,
// XCD-swizzled grid, combo-outer MFMA (16 independent accumulators).
// ---------------------------------------------------------------------------
__global__ __launch_bounds__(256)
void qkv_gemm_kernel(const unsigned short* __restrict__ Xh_g,
                     const unsigned short* __restrict__ BhT, const unsigned short* __restrict__ BlT,
                     const float* __restrict__ bias,
                     unsigned short* __restrict__ Qh, unsigned short* __restrict__ Ql,
                     unsigned short* __restrict__ Kh, unsigned short* __restrict__ Kl,
                     unsigned short* __restrict__ Vh, unsigned short* __restrict__ Vl)
{
    constexpr int KD = 1024;
    // per buf (shorts): Ah [0,4096) Bh [4096,8192) Bl [8192,12288)
    __shared__ __align__(16) short SB[2][12288];   // 48 KB total

    const int tid = threadIdx.x, lane = tid & 63, wid = tid >> 6;
    const int g = lane >> 4, ln = lane & 15;
    const int wm = wid >> 1, wn = wid & 1;

    // XCD swizzle: xcd = bid&7 owns 96 tiles = 4 m-rows x 24 n (m-fastest)
    const int bid = blockIdx.x;
    const int u = bid >> 3, xcd = bid & 7;
    const int by = xcd * 4 + (u & 3);   // m-tile 0..31
    const int bx = u >> 2;              // n-tile 0..23
    const int m0 = by * 128, n0 = bx * 128;

    f32x4 acc[4][4];
#pragma unroll
    for (int i = 0; i < 4; ++i)
#pragma unroll
        for (int j = 0; j < 4; ++j) acc[i][j] = (f32x4){0.f, 0.f, 0.f, 0.f};

    const int srow = lane >> 2, ss = lane & 3;

    // 24 staging segments (3 tiles x 8), 6 per wave.
    // prologue: stage k-tile 0 into buf 0
    {
#pragma unroll
        for (int i = 0; i < 6; ++i) {
            const int s = wid * 6 + i;
            const int t = s >> 3, j = s & 7;
            const unsigned short* gsrc = (t == 0) ? Xh_g : (t == 1) ? BhT : BlT;
            const int roff = (t == 0) ? m0 : n0;
            const int row_loc = j * 16 + srow;
            const int kc = ss ^ ((row_loc >> 1) & 3);
            gload16(gsrc + (size_t)(roff + row_loc) * KD + kc * 8,
                    &SB[0][t * 4096 + j * 512]);
        }
    }

    for (int it = 0; it < 32; ++it) {
        const int cur = it & 1;
        __syncthreads();   // stage(it) landed; reads of buf[cur] (iter it-2) done
        if (it + 1 < 32) {
            const int k0n = (it + 1) * 32;
#pragma unroll
            for (int i = 0; i < 6; ++i) {
                const int s = wid * 6 + i;
                const int t = s >> 3, j = s & 7;
                const unsigned short* gsrc = (t == 0) ? Xh_g : (t == 1) ? BhT : BlT;
                const int roff = (t == 0) ? m0 : n0;
                const int row_loc = j * 16 + srow;
                const int kc = ss ^ ((row_loc >> 1) & 3);
                gload16(gsrc + (size_t)(roff + row_loc) * KD + k0n + kc * 8,
                        &SB[cur ^ 1][t * 4096 + j * 512]);
            }
        }
        const short* Ah = &SB[cur][0];
        const short* Bh = &SB[cur][4096];
        const short* Bl = &SB[cur][8192];

        s16x8 fah[4], fbh[4], fbl[4];
#pragma unroll
        for (int am = 0; am < 4; ++am) {
            int m_loc = wm * 64 + am * 16 + ln;
            int sl = (g ^ ((m_loc >> 1) & 3)) * 8;
            fah[am] = *(const s16x8*)&Ah[m_loc * 32 + sl];
        }
#pragma unroll
        for (int bn = 0; bn < 4; ++bn) {
            int n_loc = wn * 64 + bn * 16 + ln;
            int sl = (g ^ ((n_loc >> 1) & 3)) * 8;
            fbh[bn] = *(const s16x8*)&Bh[n_loc * 32 + sl];
            fbl[bn] = *(const s16x8*)&Bl[n_loc * 32 + sl];
        }
        // combo-outer: reuse distance 16 on each accumulator
#pragma unroll
        for (int am = 0; am < 4; ++am)
#pragma unroll
            for (int bn = 0; bn < 4; ++bn)
                acc[am][bn] = MFMA16(fah[am], fbh[bn], acc[am][bn]);
#pragma unroll
        for (int am = 0; am < 4; ++am)
#pragma unroll
            for (int bn = 0; bn < 4; ++bn)
                acc[am][bn] = MFMA16(fah[am], fbl[bn], acc[am][bn]);
    }

    // epilogue: bias + split scatter (C/D: row=(lane>>4)*4+r, col=lane&15)
#pragma unroll
    for (int am = 0; am < 4; ++am)
#pragma unroll
        for (int bn = 0; bn < 4; ++bn) {
            int n = n0 + wn * 64 + bn * 16 + ln;
            float bv = bias[n];
            int sec = n >> 10, cc = n & 1023, h = cc >> 6, d = cc & 63;
#pragma unroll
            for (int r = 0; r < 4; ++r) {
                int m = m0 + wm * 64 + am * 16 + g * 4 + r;
                int bb = m >> 11, t = m & 2047;
                int bh_i = bb * NH + h;
                float val = acc[am][bn][r] + bv;
                unsigned short hi, lo;
                if (sec == 0) {
                    val *= 0.125f; split2(val, hi, lo);
                    size_t idx = ((size_t)bh_i * SEQ + t) * DH + d;
                    Qh[idx] = hi; Ql[idx] = lo;
                } else if (sec == 1) {
                    split2(val, hi, lo);
                    size_t idx = ((size_t)bh_i * SEQ + t) * DH + d;
                    Kh[idx] = hi; Kl[idx] = lo;
                } else {
                    split2(val, hi, lo);
                    size_t idx = ((size_t)bh_i * DH + d) * SEQ + t;   // V transposed
                    Vh[idx] = hi; Vl[idx] = lo;
                }
            }
        }
}

// ---------------------------------------------------------------------------
// Attention, 32x32 swapped-operand structure + 2-phase pipelined K/V staging
// (double-buffered, 64 KB LDS). Defer-max THR=8; interleaved MFMA
// accumulators. (unchanged from r11)
// ---------------------------------------------------------------------------
__global__ __launch_bounds__(256)
void attn_kernel(const unsigned short* __restrict__ Qh_g, const unsigned short* __restrict__ Ql_g,
                 const unsigned short* __restrict__ Kh_g, const unsigned short* __restrict__ Kl_g,
                 const unsigned short* __restrict__ Vh_g, const unsigned short* __restrict__ Vl_g,
                 unsigned short* __restrict__ Yh, unsigned short* __restrict__ Yl)
{
    __shared__ __align__(16) short SM[2][16384];   // 64 KB: 2 bufs x {Kh,Kl,Vh,Vl}

    const int tid = threadIdx.x, lane = tid & 63, wid = tid >> 6;
    const int l31 = lane & 31, l5 = lane >> 5;
    const int bid = blockIdx.x;
    const int qb = 15 - (bid >> 5), bh = bid & 31;   // heavy q-tiles first
    const int Q0 = qb * 128;
    const int qg = Q0 + wid * 32 + l31;              // this lane's q row

    // Q fragments from global (once per block)
    s16x8 qfh[4], qfl[4];
    {
        const size_t qo = ((size_t)bh * SEQ + qg) * DH;
#pragma unroll
        for (int t = 0; t < 4; ++t) {
            const int ch = t * 2 + l5;
            qfh[t] = *(const s16x8*)&Qh_g[qo + ch * 8];
            qfl[t] = *(const s16x8*)&Ql_g[qo + ch * 8];
        }
    }

    float m_i = -INFINITY, l_i = 0.f;
    f32x16 yacc[2];
#pragma unroll
    for (int e = 0; e < 16; ++e) { yacc[0][e] = 0.f; yacc[1][e] = 0.f; }

    const int srow = lane >> 3, ss = lane & 7;
    const int KT = 2 * qb + 2;
    const unsigned short* gb = (wid == 0) ? Kh_g : (wid == 1) ? Kl_g
                             : (wid == 2) ? Vh_g : Vl_g;
    const bool isK = (wid < 2);

    // prologue: stage kv-tile 0 into buf 0
    {
        short* lb = &SM[0][wid * 4096];
#pragma unroll
        for (int j = 0; j < 8; ++j) {
            int row = j * 8 + srow;
            int kc = ss ^ (row & 7);
            const unsigned short* src = isK
                ? gb + ((size_t)bh * SEQ + row) * DH + kc * 8
                : gb + ((size_t)bh * DH + row) * SEQ + kc * 8;
            gload16(src, lb + j * 512);
        }
    }

    for (int kt = 0; kt < KT; ++kt) {
        const int cur = kt & 1;
        __syncthreads();   // stage(kt) landed; reads of buf[cur] (kt-2) done
        if (kt + 1 < KT) {
            short* lb = &SM[cur ^ 1][wid * 4096];
            const int kn = (kt + 1) * 64;
#pragma unroll
            for (int j = 0; j < 8; ++j) {
                int row = j * 8 + srow;
                int kc = ss ^ (row & 7);
                const unsigned short* src = isK
                    ? gb + ((size_t)bh * SEQ + kn + row) * DH + kc * 8
                    : gb + ((size_t)bh * DH + row) * SEQ + kn + kc * 8;
                gload16(src, lb + j * 512);
            }
        }

        if (kt * 64 > Q0 + wid * 32 + 31) continue;   // fully masked for this wave

        const short* Ksh = &SM[cur][0];
        const short* Ksl = &SM[cur][4096];
        const short* Vsh = &SM[cur][8192];
        const short* Vsl = &SM[cur][12288];

        // ---- S^T = K . Q  (3-combo split; interleaved kb -> distance-2 chains)
        f32x16 s[2];
#pragma unroll
        for (int e = 0; e < 16; ++e) { s[0][e] = 0.f; s[1][e] = 0.f; }
#pragma unroll
        for (int t = 0; t < 4; ++t) {
            s16x8 kh[2], kl[2];
#pragma unroll
            for (int kb = 0; kb < 2; ++kb) {
                const int row = kb * 32 + l31;
                const int sl = ((t * 2 + l5) ^ (row & 7)) * 8;
                kh[kb] = *(const s16x8*)&Ksh[row * 64 + sl];
                kl[kb] = *(const s16x8*)&Ksl[row * 64 + sl];
            }
#pragma unroll
            for (int kb = 0; kb < 2; ++kb) s[kb] = MFMA32(kh[kb], qfh[t], s[kb]);
#pragma unroll
            for (int kb = 0; kb < 2; ++kb) s[kb] = MFMA32(kl[kb], qfh[t], s[kb]);
#pragma unroll
            for (int kb = 0; kb < 2; ++kb) s[kb] = MFMA32(kh[kb], qfl[t], s[kb]);
        }

        // ---- causal mask (only near the diagonal)
        if (kt * 64 + 63 > Q0 + wid * 32) {
#pragma unroll
            for (int kb = 0; kb < 2; ++kb)
#pragma unroll
                for (int r = 0; r < 16; ++r) {
                    const int key = kt * 64 + kb * 32 + (r & 3) + 8 * (r >> 2) + 4 * l5;
                    if (key > qg) s[kb][r] = -INFINITY;
                }
        }

        // ---- online softmax, in-register (q = lane&31), defer-max THR=8
        float mx = s[0][0];
#pragma unroll
        for (int r = 1; r < 16; ++r) mx = fmaxf(mx, s[0][r]);
#pragma unroll
        for (int r = 0; r < 16; ++r) mx = fmaxf(mx, s[1][r]);
        mx = fmaxf(mx, __shfl_xor(mx, 32));
        const bool defer = (__all(mx - m_i <= 8.f) != 0);
        float mref;
        if (defer) {
            mref = m_i;
        } else {
            mref = fmaxf(m_i, mx);
            const float al = __expf(m_i - mref);
            m_i = mref;
            l_i *= al;
#pragma unroll
            for (int e = 0; e < 16; ++e) { yacc[0][e] *= al; yacc[1][e] *= al; }
        }
        float ls = 0.f;
#pragma unroll
        for (int kb = 0; kb < 2; ++kb)
#pragma unroll
            for (int r = 0; r < 16; ++r) {
                s[kb][r] = __expf(s[kb][r] - mref);
                ls += s[kb][r];
            }
        ls += __shfl_xor(ls, 32);
        l_i += ls;

        // ---- P (bf16) fragments in-register: cvt_pk + permlane32_swap
        unsigned pk[2][8];
#pragma unroll
        for (int kb = 0; kb < 2; ++kb)
#pragma unroll
            for (int j = 0; j < 8; ++j)
                pk[kb][j] = cvt_pk_bf16(s[kb][2 * j], s[kb][2 * j + 1]);
        s16x8 pf[2][2];
#pragma unroll
        for (int kb = 0; kb < 2; ++kb) {
            u32x2 sA = __builtin_amdgcn_permlane32_swap(pk[kb][0], pk[kb][2], false, false);
            u32x2 sB = __builtin_amdgcn_permlane32_swap(pk[kb][1], pk[kb][3], false, false);
            u32x4 w0 = {sA[0], sB[0], sA[1], sB[1]};
            pf[kb][0] = __builtin_bit_cast(s16x8, w0);
            u32x2 sC = __builtin_amdgcn_permlane32_swap(pk[kb][4], pk[kb][6], false, false);
            u32x2 sD = __builtin_amdgcn_permlane32_swap(pk[kb][5], pk[kb][7], false, false);
            u32x4 w1 = {sC[0], sD[0], sC[1], sD[1]};
            pf[kb][1] = __builtin_bit_cast(s16x8, w1);
        }

        // ---- Y^T += V^T . P  (interleaved dt -> distance-2 chains)
#pragma unroll
        for (int t = 0; t < 4; ++t) {
            s16x8 vh[2], vl[2];
#pragma unroll
            for (int dt = 0; dt < 2; ++dt) {
                const int row = dt * 32 + l31;
                const int sl = ((t * 2 + l5) ^ (row & 7)) * 8;
                vh[dt] = *(const s16x8*)&Vsh[row * 64 + sl];
                vl[dt] = *(const s16x8*)&Vsl[row * 64 + sl];
            }
            const s16x8 pfr = pf[t >> 1][t & 1];
#pragma unroll
            for (int dt = 0; dt < 2; ++dt) yacc[dt] = MFMA32(vh[dt], pfr, yacc[dt]);
#pragma unroll
            for (int dt = 0; dt < 2; ++dt) yacc[dt] = MFMA32(vl[dt], pfr, yacc[dt]);
        }
    }

    // ---- epilogue: normalize, split, LDS transpose bounce, coalesced write
    __syncthreads();   // everyone done with K/V LDS
    short* SMf = &SM[0][0];
    const float inv = 1.f / l_i;
    const int qlcl = wid * 32 + l31;
#pragma unroll
    for (int dt = 0; dt < 2; ++dt)
#pragma unroll
        for (int rq = 0; rq < 4; ++rq) {
            const int d0 = dt * 32 + rq * 8 + 4 * l5;
            s16x4 h4, l4;
#pragma unroll
            for (int c = 0; c < 4; ++c) {
                unsigned short hh, ll;
                split2(yacc[dt][rq * 4 + c] * inv, hh, ll);
                h4[c] = (short)hh; l4[c] = (short)ll;
            }
            const int base = qlcl * 64 + (((d0 >> 3) ^ (qlcl & 7)) * 8) + (d0 & 7);
            *(s16x4*)&SMf[base] = h4;
            *(s16x4*)&SMf[8192 + base] = l4;
        }
    __syncthreads();
    const int b = bh >> 4, h = bh & 15;
#pragma unroll
    for (int i = 0; i < 4; ++i) {
        const int idx = tid + i * 256;
        const int row = idx >> 3, ch = idx & 7;
        const int sl = (ch ^ (row & 7)) * 8;
        s16x8 vh8 = *(const s16x8*)&SMf[row * 64 + sl];
        s16x8 vl8 = *(const s16x8*)&SMf[8192 + row * 64 + sl];
        const size_t o = ((size_t)(b * SEQ + Q0 + row)) * EMBED + h * DH + ch * 8;
        *(s16x8*)&Yh[o] = vh8;
        *(s16x8*)&Yl[o] = vl8;
    }
}

// ---------------------------------------------------------------------------
// Out GEMM: 2-phase pipelined staging, XCD-swizzled, combo-outer MFMA.
// (unchanged from r11)
// ---------------------------------------------------------------------------
__global__ __launch_bounds__(256)
void out_gemm_kernel(const unsigned short* __restrict__ Yh_g, const unsigned short* __restrict__ Yl_g,
                     const unsigned short* __restrict__ WhT, const unsigned short* __restrict__ WlT,
                     const float* __restrict__ bias, float* __restrict__ out)
{
    constexpr int KD = 1024, ND = 1024;
    __shared__ __align__(16) short SB[2][16384];   // 64 KB

    const int tid = threadIdx.x, lane = tid & 63, wid = tid >> 6;
    const int g = lane >> 4, ln = lane & 15;
    const int wm = wid >> 1, wn = wid & 1;

    const int bid = blockIdx.x;
    const int u = bid >> 3, xcd = bid & 7;
    const int by = xcd * 4 + (u & 3);   // m-tile 0..31
    const int bx = u >> 2;              // n-tile 0..7
    const int m0 = by * 128, n0 = bx * 128;

    f32x4 acc[4][4];
#pragma unroll
    for (int i = 0; i < 4; ++i)
#pragma unroll
        for (int j = 0; j < 4; ++j) acc[i][j] = (f32x4){0.f, 0.f, 0.f, 0.f};

    const int srow = lane >> 2, ss = lane & 3;
    const unsigned short* gb = (wid == 0) ? Yh_g : (wid == 1) ? Yl_g
                             : (wid == 2) ? WhT  : WlT;
    const int roff = (wid < 2) ? m0 : n0;

    {
        short* lb = &SB[0][wid * 4096];
#pragma unroll
        for (int j = 0; j < 8; ++j) {
            int row_loc = j * 16 + srow;
            int kc = ss ^ ((row_loc >> 1) & 3);
            gload16(gb + (size_t)(roff + row_loc) * KD + kc * 8, lb + j * 512);
        }
    }

    for (int it = 0; it < 32; ++it) {
        const int cur = it & 1;
        __syncthreads();
        if (it + 1 < 32) {
            short* lb = &SB[cur ^ 1][wid * 4096];
            const int k0n = (it + 1) * 32;
#pragma unroll
            for (int j = 0; j < 8; ++j) {
                int row_loc = j * 16 + srow;
                int kc = ss ^ ((row_loc >> 1) & 3);
                gload16(gb + (size_t)(roff + row_loc) * KD + k0n + kc * 8, lb + j * 512);
            }
        }
        const short* Ah = &SB[cur][0];
        const short* Al = &SB[cur][4096];
        const short* Bh = &SB[cur][8192];
        const short* Bl = &SB[cur][12288];

        s16x8 fah[4], fal[4], fbh[4], fbl[4];
#pragma unroll
        for (int am = 0; am < 4; ++am) {
            int m_loc = wm * 64 + am * 16 + ln;
            int sl = (g ^ ((m_loc >> 1) & 3)) * 8;
            fah[am] = *(const s16x8*)&Ah[m_loc * 32 + sl];
            fal[am] = *(const s16x8*)&Al[m_loc * 32 + sl];
        }
#pragma unroll
        for (int bn = 0; bn < 4; ++bn) {
            int n_loc = wn * 64 + bn * 16 + ln;
            int sl = (g ^ ((n_loc >> 1) & 3)) * 8;
            fbh[bn] = *(const s16x8*)&Bh[n_loc * 32 + sl];
            fbl[bn] = *(const s16x8*)&Bl[n_loc * 32 + sl];
        }
#pragma unroll
        for (int am = 0; am < 4; ++am)
#pragma unroll
            for (int bn = 0; bn < 4; ++bn)
                acc[am][bn] = MFMA16(fah[am], fbh[bn], acc[am][bn]);
#pragma unroll
        for (int am = 0; am < 4; ++am)
#pragma unroll
            for (int bn = 0; bn < 4; ++bn)
                acc[am][bn] = MFMA16(fah[am], fbl[bn], acc[am][bn]);
#pragma unroll
        for (int am = 0; am < 4; ++am)
#pragma unroll
            for (int bn = 0; bn < 4; ++bn)
                acc[am][bn] = MFMA16(fal[am], fbh[bn], acc[am][bn]);
    }

#pragma unroll
    for (int am = 0; am < 4; ++am)
#pragma unroll
        for (int bn = 0; bn < 4; ++bn) {
            int n = n0 + wn * 64 + bn * 16 + ln;
            float bv = bias[n];
#pragma unroll
            for (int r = 0; r < 4; ++r) {
                int m = m0 + wm * 64 + am * 16 + g * 4 + r;
                out[(size_t)m * ND + n] = acc[am][bn][r] + bv;
            }
        }
}

// ---------------------------------------------------------------------------
extern "C" void kernel_launch(void* const* d_in, const int* in_sizes, int n_in,
                              void* d_out, int out_size, void* d_ws, size_t ws_size,
                              hipStream_t stream)
{
    const float* x     = (const float*)d_in[0];
    const float* W_kqv = (const float*)d_in[1];
    const float* b_kqv = (const float*)d_in[2];
    const float* W_out = (const float*)d_in[3];
    const float* b_out = (const float*)d_in[4];
    float* out = (float*)d_out;

    char* ws = (char*)d_ws;
    const size_t MB = 1024 * 1024;
    unsigned short* Qh = (unsigned short*)(ws);
    unsigned short* Ql = Qh + 4194304;
    unsigned short* Kh = Ql + 4194304;
    unsigned short* Kl = Kh + 4194304;
    unsigned short* Vh = Kl + 4194304;
    unsigned short* Vl = Vh + 4194304;
    unsigned short* WhT = (unsigned short*)(ws + 48 * MB);
    unsigned short* WlT = WhT + 3145728;
    unsigned short* Yh  = (unsigned short*)(ws + 48 * MB);
    unsigned short* Yl  = Yh + 4194304;
    // Xh lives in d_out (8 MB of 16): dead until out_gemm rewrites all of it.
    unsigned short* Xh = (unsigned short*)d_out;

    // WoT home: if ws has >= 68 MB, park it past the 64 MB working set and
    // produce it in the merged prep kernel (4 launches total). Otherwise it
    // aliases Qh and must be produced after attn (5 launches).
    const bool big = (ws_size >= 68 * MB);
    unsigned short* WoTh = big ? (unsigned short*)(ws + 64 * MB)
                               : (unsigned short*)(ws);
    unsigned short* WoTl = WoTh + 1048576;

    const int prep_blocks = 2048 + 3072 + (big ? 1024 : 0);
    prep_kernel<<<dim3(prep_blocks), 256, 0, stream>>>(
        x, W_kqv, W_out, Xh, WhT, WlT, WoTh, WoTl);
    qkv_gemm_kernel<<<dim3(768), 256, 0, stream>>>(
        Xh, WhT, WlT, b_kqv, Qh, Ql, Kh, Kl, Vh, Vl);
    attn_kernel<<<dim3(BHTOT * (SEQ / 128)), 256, 0, stream>>>(
        Qh, Ql, Kh, Kl, Vh, Vl, Yh, Yl);
    if (!big)
        splitT_kernel<<<dim3(EMBED / 32, EMBED / 32), 256, 0, stream>>>(
            W_out, WoTh, WoTl, EMBED, EMBED);
    out_gemm_kernel<<<dim3(256), 256, 0, stream>>>(
        Yh, Yl, WoTh, WoTl, b_out, out);
}

// Round 15
// 188.370 us; speedup vs baseline: 1.0493x; 1.0004x over previous
//
#include <hip/hip_runtime.h>
#include <math.h>

#define EMBED 1024
#define NH    16
#define DH    64
#define BATCH 2
#define SEQ   2048
#define MTOT  4096
#define BHTOT 32

typedef float f32x4  __attribute__((ext_vector_type(4)));
typedef float f32x16 __attribute__((ext_vector_type(16)));
typedef short s16x8  __attribute__((ext_vector_type(8)));
typedef short s16x4  __attribute__((ext_vector_type(4)));
typedef unsigned u32x2 __attribute__((ext_vector_type(2)));
typedef unsigned u32x4 __attribute__((ext_vector_type(4)));

#define AS1 __attribute__((address_space(1)))
#define AS3 __attribute__((address_space(3)))

__device__ __forceinline__ unsigned short bf16_rne(float f) {
    unsigned u = __builtin_bit_cast(unsigned, f);
    return (unsigned short)((u + 0x7FFFu + ((u >> 16) & 1u)) >> 16);
}
__device__ __forceinline__ float bf16_f(unsigned short h) {
    unsigned u = ((unsigned)h) << 16;
    return __builtin_bit_cast(float, u);
}
__device__ __forceinline__ void split2(float v, unsigned short& hi, unsigned short& lo) {
    hi = bf16_rne(v);
    lo = bf16_rne(v - bf16_f(hi));
}
__device__ __forceinline__ void gload16(const void* g, void* l) {
    __builtin_amdgcn_global_load_lds((const AS1 void*)g, (AS3 void*)l, 16, 0, 0);
}
__device__ __forceinline__ unsigned cvt_pk_bf16(float lo, float hi) {
    unsigned r;
    asm volatile("v_cvt_pk_bf16_f32 %0, %1, %2" : "=v"(r) : "v"(lo), "v"(hi));
    return r;
}
#define MFMA16(a, b, c) __builtin_amdgcn_mfma_f32_16x16x32_bf16((a), (b), (c), 0, 0, 0)
#define MFMA32(a, b, c) __builtin_amdgcn_mfma_f32_32x32x16_bf16((a), (b), (c), 0, 0, 0)

// ---------------------------------------------------------------------------
// prep: one kernel for splitX (blocks [0,2048)), splitT of Wkqv
// (blocks [2048,5120)), and optionally splitT of Wout (blocks [5120,6144)).
// ---------------------------------------------------------------------------
__global__ __launch_bounds__(256)
void prep_kernel(const float* __restrict__ X, const float* __restrict__ Wkqv,
                 const float* __restrict__ Wout,
                 unsigned short* __restrict__ Xh,
                 unsigned short* __restrict__ WhT, unsigned short* __restrict__ WlT,
                 unsigned short* __restrict__ WoTh, unsigned short* __restrict__ WoTl)
{
    __shared__ float T[32][33];
    const int bid = blockIdx.x, tid = threadIdx.x;

    if (bid < 2048) {   // ---- splitX: X fp32 -> Xh bf16
        const size_t i = ((size_t)bid * 256 + tid) * 8;
        float4 a = *(const float4*)&X[i];
        float4 b = *(const float4*)&X[i + 4];
        float v[8] = {a.x, a.y, a.z, a.w, b.x, b.y, b.z, b.w};
        s16x8 h8;
#pragma unroll
        for (int e = 0; e < 8; ++e) h8[e] = (short)bf16_rne(v[e]);
        *(s16x8*)&Xh[i] = h8;
        return;
    }

    // ---- splitT: W fp32 [Kd][Nd] -> Hi/Lo bf16 [Nd][Kd]
    const float* W;
    unsigned short *Hi, *Lo;
    int Nd, n0, k0;
    if (bid < 5120) {
        const int u = bid - 2048;                 // 0..3071
        W = Wkqv; Hi = WhT; Lo = WlT; Nd = 3072;
        n0 = (u % 96) * 32; k0 = (u / 96) * 32;
    } else {
        const int u = bid - 5120;                 // 0..1023
        W = Wout; Hi = WoTh; Lo = WoTl; Nd = 1024;
        n0 = (u & 31) * 32; k0 = (u >> 5) * 32;
    }
    constexpr int Kd = 1024;
    {
        const int row = tid >> 3, c4 = (tid & 7) * 4;
        float4 v = *(const float4*)&W[(size_t)(k0 + row) * Nd + n0 + c4];
        T[row][c4] = v.x; T[row][c4 + 1] = v.y; T[row][c4 + 2] = v.z; T[row][c4 + 3] = v.w;
    }
    __syncthreads();
    {
        const int nr = tid >> 3, c4 = (tid & 7) * 4;
        s16x4 h4, l4;
#pragma unroll
        for (int e = 0; e < 4; ++e) {
            unsigned short h, l;
            split2(T[c4 + e][nr], h, l);
            h4[e] = (short)h; l4[e] = (short)l;
        }
        *(s16x4*)&Hi[(size_t)(n0 + nr) * Kd + k0 + c4] = h4;
        *(s16x4*)&Lo[(size_t)(n0 + nr) * Kd + k0 + c4] = l4;
    }
}

// ---------------------------------------------------------------------------
// splitT (standalone fallback when ws cannot host WoT before attn finishes).
// ---------------------------------------------------------------------------
__global__ __launch_bounds__(256)
void splitT_kernel(const float* __restrict__ W, unsigned short* __restrict__ HiT,
                   unsigned short* __restrict__ LoT, int Kd, int Nd)
{
    __shared__ float T[32][33];
    const int tid = threadIdx.x;
    const int n0 = blockIdx.x * 32, k0 = blockIdx.y * 32;
    {
        const int row = tid >> 3, c4 = (tid & 7) * 4;
        float4 v = *(const float4*)&W[(size_t)(k0 + row) * Nd + n0 + c4];
        T[row][c4] = v.x; T[row][c4 + 1] = v.y; T[row][c4 + 2] = v.z; T[row][c4 + 3] = v.w;
    }
    __syncthreads();
    {
        const int nr = tid >> 3, c4 = (tid & 7) * 4;
        s16x4 h4, l4;
#pragma unroll
        for (int e = 0; e < 4; ++e) {
            unsigned short h, l;
            split2(T[c4 + e][nr], h, l);
            h4[e] = (short)h; l4[e] = (short)l;
        }
        *(s16x4*)&HiT[(size_t)(n0 + nr) * Kd + k0 + c4] = h4;
        *(s16x4*)&LoT[(size_t)(n0 + nr) * Kd + k0 + c4] = l4;
    }
}

// ---------------------------------------------------------------------------
// QKV GEMM: 2-combo split (Ah.Bh + Ah.Bl) on mfma_32x32x16. 128x128 tile,
// BK=32, double-buffered 48 KB LDS, issue-early staging. Per wave: 2x2
// 32x32 fragments (64x64 output). Operand layout: row=lane&31,
// k-half=lane>>5 (8 contiguous k). D: col=lane&31, row=(r&3)+8(r>>2)+4*l5.
// ---------------------------------------------------------------------------
__global__ __launch_bounds__(256)
void qkv_gemm_kernel(const unsigned short* __restrict__ Xh_g,
                     const unsigned short* __restrict__ BhT, const unsigned short* __restrict__ BlT,
                     const float* __restrict__ bias,
                     unsigned short* __restrict__ Qh, unsigned short* __restrict__ Ql,
                     unsigned short* __restrict__ Kh, unsigned short* __restrict__ Kl,
                     unsigned short* __restrict__ Vh, unsigned short* __restrict__ Vl)
{
    constexpr int KD = 1024;
    // per buf (shorts): Ah [0,4096) Bh [4096,8192) Bl [8192,12288)
    __shared__ __align__(16) short SB[2][12288];   // 48 KB total

    const int tid = threadIdx.x, lane = tid & 63, wid = tid >> 6;
    const int l31 = lane & 31, l5 = lane >> 5;
    const int wm = wid >> 1, wn = wid & 1;

    // XCD swizzle: xcd = bid&7 owns 96 tiles = 4 m-rows x 24 n (m-fastest)
    const int bid = blockIdx.x;
    const int u = bid >> 3, xcd = bid & 7;
    const int by = xcd * 4 + (u & 3);   // m-tile 0..31
    const int bx = u >> 2;              // n-tile 0..23
    const int m0 = by * 128, n0 = bx * 128;

    f32x16 acc[2][2];
#pragma unroll
    for (int i = 0; i < 2; ++i)
#pragma unroll
        for (int j = 0; j < 2; ++j)
#pragma unroll
            for (int e = 0; e < 16; ++e) acc[i][j][e] = 0.f;

    const int srow = lane >> 2, ss = lane & 3;

    // 24 staging segments (3 tiles x 8), 6 per wave.
    // prologue: stage k-tile 0 into buf 0
    {
#pragma unroll
        for (int i = 0; i < 6; ++i) {
            const int s = wid * 6 + i;
            const int t = s >> 3, j = s & 7;
            const unsigned short* gsrc = (t == 0) ? Xh_g : (t == 1) ? BhT : BlT;
            const int roff = (t == 0) ? m0 : n0;
            const int row_loc = j * 16 + srow;
            const int kc = ss ^ ((row_loc >> 1) & 3);
            gload16(gsrc + (size_t)(roff + row_loc) * KD + kc * 8,
                    &SB[0][t * 4096 + j * 512]);
        }
    }

    for (int it = 0; it < 32; ++it) {
        const int cur = it & 1;
        __syncthreads();   // stage(it) landed; reads of buf[cur] (iter it-2) done
        if (it + 1 < 32) {
            const int k0n = (it + 1) * 32;
#pragma unroll
            for (int i = 0; i < 6; ++i) {
                const int s = wid * 6 + i;
                const int t = s >> 3, j = s & 7;
                const unsigned short* gsrc = (t == 0) ? Xh_g : (t == 1) ? BhT : BlT;
                const int roff = (t == 0) ? m0 : n0;
                const int row_loc = j * 16 + srow;
                const int kc = ss ^ ((row_loc >> 1) & 3);
                gload16(gsrc + (size_t)(roff + row_loc) * KD + k0n + kc * 8,
                        &SB[cur ^ 1][t * 4096 + j * 512]);
            }
        }
        const short* Ahp = &SB[cur][0];
        const short* Bhp = &SB[cur][4096];
        const short* Blp = &SB[cur][8192];

        // fragments: row=l31 within 32-row group, chunk = khalf*2 + l5
        s16x8 fa[2][2], fbh[2][2], fbl[2][2];
#pragma unroll
        for (int am = 0; am < 2; ++am) {
            const int row = wm * 64 + am * 32 + l31;
            const int sw = (row >> 1) & 3;
#pragma unroll
            for (int kh2 = 0; kh2 < 2; ++kh2) {
                const int sl = ((kh2 * 2 + l5) ^ sw) * 8;
                fa[am][kh2] = *(const s16x8*)&Ahp[row * 32 + sl];
            }
        }
#pragma unroll
        for (int bn = 0; bn < 2; ++bn) {
            const int row = wn * 64 + bn * 32 + l31;
            const int sw = (row >> 1) & 3;
#pragma unroll
            for (int kh2 = 0; kh2 < 2; ++kh2) {
                const int sl = ((kh2 * 2 + l5) ^ sw) * 8;
                fbh[bn][kh2] = *(const s16x8*)&Bhp[row * 32 + sl];
                fbl[bn][kh2] = *(const s16x8*)&Blp[row * 32 + sl];
            }
        }
        // combo-outer; 4 independent accumulators per group (distance 4)
#pragma unroll
        for (int kh2 = 0; kh2 < 2; ++kh2)
#pragma unroll
            for (int am = 0; am < 2; ++am)
#pragma unroll
                for (int bn = 0; bn < 2; ++bn)
                    acc[am][bn] = MFMA32(fa[am][kh2], fbh[bn][kh2], acc[am][bn]);
#pragma unroll
        for (int kh2 = 0; kh2 < 2; ++kh2)
#pragma unroll
            for (int am = 0; am < 2; ++am)
#pragma unroll
                for (int bn = 0; bn < 2; ++bn)
                    acc[am][bn] = MFMA32(fa[am][kh2], fbl[bn][kh2], acc[am][bn]);
    }

    // epilogue: bias + split scatter (D: col=l31, row=(r&3)+8*(r>>2)+4*l5)
#pragma unroll
    for (int am = 0; am < 2; ++am)
#pragma unroll
        for (int bn = 0; bn < 2; ++bn) {
            const int n = n0 + wn * 64 + bn * 32 + l31;
            const float bv = bias[n];
            const int sec = n >> 10, cc = n & 1023, h = cc >> 6, d = cc & 63;
#pragma unroll
            for (int r = 0; r < 16; ++r) {
                const int mrow = (r & 3) + 8 * (r >> 2) + 4 * l5;
                const int m = m0 + wm * 64 + am * 32 + mrow;
                const int bb = m >> 11, t = m & 2047;
                const int bh_i = bb * NH + h;
                float val = acc[am][bn][r] + bv;
                unsigned short hi, lo;
                if (sec == 0) {
                    val *= 0.125f; split2(val, hi, lo);
                    size_t idx = ((size_t)bh_i * SEQ + t) * DH + d;
                    Qh[idx] = hi; Ql[idx] = lo;
                } else if (sec == 1) {
                    split2(val, hi, lo);
                    size_t idx = ((size_t)bh_i * SEQ + t) * DH + d;
                    Kh[idx] = hi; Kl[idx] = lo;
                } else {
                    split2(val, hi, lo);
                    size_t idx = ((size_t)bh_i * DH + d) * SEQ + t;   // V transposed
                    Vh[idx] = hi; Vl[idx] = lo;
                }
            }
        }
}

// ---------------------------------------------------------------------------
// Attention, 32x32 swapped-operand structure + 2-phase pipelined K/V staging
// (double-buffered, 64 KB LDS). Defer-max THR=8; interleaved MFMA
// accumulators. (unchanged from r11)
// ---------------------------------------------------------------------------
__global__ __launch_bounds__(256)
void attn_kernel(const unsigned short* __restrict__ Qh_g, const unsigned short* __restrict__ Ql_g,
                 const unsigned short* __restrict__ Kh_g, const unsigned short* __restrict__ Kl_g,
                 const unsigned short* __restrict__ Vh_g, const unsigned short* __restrict__ Vl_g,
                 unsigned short* __restrict__ Yh, unsigned short* __restrict__ Yl)
{
    __shared__ __align__(16) short SM[2][16384];   // 64 KB: 2 bufs x {Kh,Kl,Vh,Vl}

    const int tid = threadIdx.x, lane = tid & 63, wid = tid >> 6;
    const int l31 = lane & 31, l5 = lane >> 5;
    const int bid = blockIdx.x;
    const int qb = 15 - (bid >> 5), bh = bid & 31;   // heavy q-tiles first
    const int Q0 = qb * 128;
    const int qg = Q0 + wid * 32 + l31;              // this lane's q row

    // Q fragments from global (once per block)
    s16x8 qfh[4], qfl[4];
    {
        const size_t qo = ((size_t)bh * SEQ + qg) * DH;
#pragma unroll
        for (int t = 0; t < 4; ++t) {
            const int ch = t * 2 + l5;
            qfh[t] = *(const s16x8*)&Qh_g[qo + ch * 8];
            qfl[t] = *(const s16x8*)&Ql_g[qo + ch * 8];
        }
    }

    float m_i = -INFINITY, l_i = 0.f;
    f32x16 yacc[2];
#pragma unroll
    for (int e = 0; e < 16; ++e) { yacc[0][e] = 0.f; yacc[1][e] = 0.f; }

    const int srow = lane >> 3, ss = lane & 7;
    const int KT = 2 * qb + 2;
    const unsigned short* gb = (wid == 0) ? Kh_g : (wid == 1) ? Kl_g
                             : (wid == 2) ? Vh_g : Vl_g;
    const bool isK = (wid < 2);

    // prologue: stage kv-tile 0 into buf 0
    {
        short* lb = &SM[0][wid * 4096];
#pragma unroll
        for (int j = 0; j < 8; ++j) {
            int row = j * 8 + srow;
            int kc = ss ^ (row & 7);
            const unsigned short* src = isK
                ? gb + ((size_t)bh * SEQ + row) * DH + kc * 8
                : gb + ((size_t)bh * DH + row) * SEQ + kc * 8;
            gload16(src, lb + j * 512);
        }
    }

    for (int kt = 0; kt < KT; ++kt) {
        const int cur = kt & 1;
        __syncthreads();   // stage(kt) landed; reads of buf[cur] (kt-2) done
        if (kt + 1 < KT) {
            short* lb = &SM[cur ^ 1][wid * 4096];
            const int kn = (kt + 1) * 64;
#pragma unroll
            for (int j = 0; j < 8; ++j) {
                int row = j * 8 + srow;
                int kc = ss ^ (row & 7);
                const unsigned short* src = isK
                    ? gb + ((size_t)bh * SEQ + kn + row) * DH + kc * 8
                    : gb + ((size_t)bh * DH + row) * SEQ + kn + kc * 8;
                gload16(src, lb + j * 512);
            }
        }

        if (kt * 64 > Q0 + wid * 32 + 31) continue;   // fully masked for this wave

        const short* Ksh = &SM[cur][0];
        const short* Ksl = &SM[cur][4096];
        const short* Vsh = &SM[cur][8192];
        const short* Vsl = &SM[cur][12288];

        // ---- S^T = K . Q  (3-combo split; interleaved kb -> distance-2 chains)
        f32x16 s[2];
#pragma unroll
        for (int e = 0; e < 16; ++e) { s[0][e] = 0.f; s[1][e] = 0.f; }
#pragma unroll
        for (int t = 0; t < 4; ++t) {
            s16x8 kh[2], kl[2];
#pragma unroll
            for (int kb = 0; kb < 2; ++kb) {
                const int row = kb * 32 + l31;
                const int sl = ((t * 2 + l5) ^ (row & 7)) * 8;
                kh[kb] = *(const s16x8*)&Ksh[row * 64 + sl];
                kl[kb] = *(const s16x8*)&Ksl[row * 64 + sl];
            }
#pragma unroll
            for (int kb = 0; kb < 2; ++kb) s[kb] = MFMA32(kh[kb], qfh[t], s[kb]);
#pragma unroll
            for (int kb = 0; kb < 2; ++kb) s[kb] = MFMA32(kl[kb], qfh[t], s[kb]);
#pragma unroll
            for (int kb = 0; kb < 2; ++kb) s[kb] = MFMA32(kh[kb], qfl[t], s[kb]);
        }

        // ---- causal mask (only near the diagonal)
        if (kt * 64 + 63 > Q0 + wid * 32) {
#pragma unroll
            for (int kb = 0; kb < 2; ++kb)
#pragma unroll
                for (int r = 0; r < 16; ++r) {
                    const int key = kt * 64 + kb * 32 + (r & 3) + 8 * (r >> 2) + 4 * l5;
                    if (key > qg) s[kb][r] = -INFINITY;
                }
        }

        // ---- online softmax, in-register (q = lane&31), defer-max THR=8
        float mx = s[0][0];
#pragma unroll
        for (int r = 1; r < 16; ++r) mx = fmaxf(mx, s[0][r]);
#pragma unroll
        for (int r = 0; r < 16; ++r) mx = fmaxf(mx, s[1][r]);
        mx = fmaxf(mx, __shfl_xor(mx, 32));
        const bool defer = (__all(mx - m_i <= 8.f) != 0);
        float mref;
        if (defer) {
            mref = m_i;
        } else {
            mref = fmaxf(m_i, mx);
            const float al = __expf(m_i - mref);
            m_i = mref;
            l_i *= al;
#pragma unroll
            for (int e = 0; e < 16; ++e) { yacc[0][e] *= al; yacc[1][e] *= al; }
        }
        float ls = 0.f;
#pragma unroll
        for (int kb = 0; kb < 2; ++kb)
#pragma unroll
            for (int r = 0; r < 16; ++r) {
                s[kb][r] = __expf(s[kb][r] - mref);
                ls += s[kb][r];
            }
        ls += __shfl_xor(ls, 32);
        l_i += ls;

        // ---- P (bf16) fragments in-register: cvt_pk + permlane32_swap
        unsigned pk[2][8];
#pragma unroll
        for (int kb = 0; kb < 2; ++kb)
#pragma unroll
            for (int j = 0; j < 8; ++j)
                pk[kb][j] = cvt_pk_bf16(s[kb][2 * j], s[kb][2 * j + 1]);
        s16x8 pf[2][2];
#pragma unroll
        for (int kb = 0; kb < 2; ++kb) {
            u32x2 sA = __builtin_amdgcn_permlane32_swap(pk[kb][0], pk[kb][2], false, false);
            u32x2 sB = __builtin_amdgcn_permlane32_swap(pk[kb][1], pk[kb][3], false, false);
            u32x4 w0 = {sA[0], sB[0], sA[1], sB[1]};
            pf[kb][0] = __builtin_bit_cast(s16x8, w0);
            u32x2 sC = __builtin_amdgcn_permlane32_swap(pk[kb][4], pk[kb][6], false, false);
            u32x2 sD = __builtin_amdgcn_permlane32_swap(pk[kb][5], pk[kb][7], false, false);
            u32x4 w1 = {sC[0], sD[0], sC[1], sD[1]};
            pf[kb][1] = __builtin_bit_cast(s16x8, w1);
        }

        // ---- Y^T += V^T . P  (interleaved dt -> distance-2 chains)
#pragma unroll
        for (int t = 0; t < 4; ++t) {
            s16x8 vh[2], vl[2];
#pragma unroll
            for (int dt = 0; dt < 2; ++dt) {
                const int row = dt * 32 + l31;
                const int sl = ((t * 2 + l5) ^ (row & 7)) * 8;
                vh[dt] = *(const s16x8*)&Vsh[row * 64 + sl];
                vl[dt] = *(const s16x8*)&Vsl[row * 64 + sl];
            }
            const s16x8 pfr = pf[t >> 1][t & 1];
#pragma unroll
            for (int dt = 0; dt < 2; ++dt) yacc[dt] = MFMA32(vh[dt], pfr, yacc[dt]);
#pragma unroll
            for (int dt = 0; dt < 2; ++dt) yacc[dt] = MFMA32(vl[dt], pfr, yacc[dt]);
        }
    }

    // ---- epilogue: normalize, split, LDS transpose bounce, coalesced write
    __syncthreads();   // everyone done with K/V LDS
    short* SMf = &SM[0][0];
    const float inv = 1.f / l_i;
    const int qlcl = wid * 32 + l31;
#pragma unroll
    for (int dt = 0; dt < 2; ++dt)
#pragma unroll
        for (int rq = 0; rq < 4; ++rq) {
            const int d0 = dt * 32 + rq * 8 + 4 * l5;
            s16x4 h4, l4;
#pragma unroll
            for (int c = 0; c < 4; ++c) {
                unsigned short hh, ll;
                split2(yacc[dt][rq * 4 + c] * inv, hh, ll);
                h4[c] = (short)hh; l4[c] = (short)ll;
            }
            const int base = qlcl * 64 + (((d0 >> 3) ^ (qlcl & 7)) * 8) + (d0 & 7);
            *(s16x4*)&SMf[base] = h4;
            *(s16x4*)&SMf[8192 + base] = l4;
        }
    __syncthreads();
    const int b = bh >> 4, h = bh & 15;
#pragma unroll
    for (int i = 0; i < 4; ++i) {
        const int idx = tid + i * 256;
        const int row = idx >> 3, ch = idx & 7;
        const int sl = (ch ^ (row & 7)) * 8;
        s16x8 vh8 = *(const s16x8*)&SMf[row * 64 + sl];
        s16x8 vl8 = *(const s16x8*)&SMf[8192 + row * 64 + sl];
        const size_t o = ((size_t)(b * SEQ + Q0 + row)) * EMBED + h * DH + ch * 8;
        *(s16x8*)&Yh[o] = vh8;
        *(s16x8*)&Yl[o] = vl8;
    }
}

// ---------------------------------------------------------------------------
// Out GEMM: 2-phase pipelined staging, XCD-swizzled, combo-outer MFMA.
// (unchanged from r11)
// ---------------------------------------------------------------------------
__global__ __launch_bounds__(256)
void out_gemm_kernel(const unsigned short* __restrict__ Yh_g, const unsigned short* __restrict__ Yl_g,
                     const unsigned short* __restrict__ WhT, const unsigned short* __restrict__ WlT,
                     const float* __restrict__ bias, float* __restrict__ out)
{
    constexpr int KD = 1024, ND = 1024;
    __shared__ __align__(16) short SB[2][16384];   // 64 KB

    const int tid = threadIdx.x, lane = tid & 63, wid = tid >> 6;
    const int g = lane >> 4, ln = lane & 15;
    const int wm = wid >> 1, wn = wid & 1;

    const int bid = blockIdx.x;
    const int u = bid >> 3, xcd = bid & 7;
    const int by = xcd * 4 + (u & 3);   // m-tile 0..31
    const int bx = u >> 2;              // n-tile 0..7
    const int m0 = by * 128, n0 = bx * 128;

    f32x4 acc[4][4];
#pragma unroll
    for (int i = 0; i < 4; ++i)
#pragma unroll
        for (int j = 0; j < 4; ++j) acc[i][j] = (f32x4){0.f, 0.f, 0.f, 0.f};

    const int srow = lane >> 2, ss = lane & 3;
    const unsigned short* gb = (wid == 0) ? Yh_g : (wid == 1) ? Yl_g
                             : (wid == 2) ? WhT  : WlT;
    const int roff = (wid < 2) ? m0 : n0;

    {
        short* lb = &SB[0][wid * 4096];
#pragma unroll
        for (int j = 0; j < 8; ++j) {
            int row_loc = j * 16 + srow;
            int kc = ss ^ ((row_loc >> 1) & 3);
            gload16(gb + (size_t)(roff + row_loc) * KD + kc * 8, lb + j * 512);
        }
    }

    for (int it = 0; it < 32; ++it) {
        const int cur = it & 1;
        __syncthreads();
        if (it + 1 < 32) {
            short* lb = &SB[cur ^ 1][wid * 4096];
            const int k0n = (it + 1) * 32;
#pragma unroll
            for (int j = 0; j < 8; ++j) {
                int row_loc = j * 16 + srow;
                int kc = ss ^ ((row_loc >> 1) & 3);
                gload16(gb + (size_t)(roff + row_loc) * KD + k0n + kc * 8, lb + j * 512);
            }
        }
        const short* Ah = &SB[cur][0];
        const short* Al = &SB[cur][4096];
        const short* Bh = &SB[cur][8192];
        const short* Bl = &SB[cur][12288];

        s16x8 fah[4], fal[4], fbh[4], fbl[4];
#pragma unroll
        for (int am = 0; am < 4; ++am) {
            int m_loc = wm * 64 + am * 16 + ln;
            int sl = (g ^ ((m_loc >> 1) & 3)) * 8;
            fah[am] = *(const s16x8*)&Ah[m_loc * 32 + sl];
            fal[am] = *(const s16x8*)&Al[m_loc * 32 + sl];
        }
#pragma unroll
        for (int bn = 0; bn < 4; ++bn) {
            int n_loc = wn * 64 + bn * 16 + ln;
            int sl = (g ^ ((n_loc >> 1) & 3)) * 8;
            fbh[bn] = *(const s16x8*)&Bh[n_loc * 32 + sl];
            fbl[bn] = *(const s16x8*)&Bl[n_loc * 32 + sl];
        }
#pragma unroll
        for (int am = 0; am < 4; ++am)
#pragma unroll
            for (int bn = 0; bn < 4; ++bn)
                acc[am][bn] = MFMA16(fah[am], fbh[bn], acc[am][bn]);
#pragma unroll
        for (int am = 0; am < 4; ++am)
#pragma unroll
            for (int bn = 0; bn < 4; ++bn)
                acc[am][bn] = MFMA16(fah[am], fbl[bn], acc[am][bn]);
#pragma unroll
        for (int am = 0; am < 4; ++am)
#pragma unroll
            for (int bn = 0; bn < 4; ++bn)
                acc[am][bn] = MFMA16(fal[am], fbh[bn], acc[am][bn]);
    }

#pragma unroll
    for (int am = 0; am < 4; ++am)
#pragma unroll
        for (int bn = 0; bn < 4; ++bn) {
            int n = n0 + wn * 64 + bn * 16 + ln;
            float bv = bias[n];
#pragma unroll
            for (int r = 0; r < 4; ++r) {
                int m = m0 + wm * 64 + am * 16 + g * 4 + r;
                out[(size_t)m * ND + n] = acc[am][bn][r] + bv;
            }
        }
}

// ---------------------------------------------------------------------------
extern "C" void kernel_launch(void* const* d_in, const int* in_sizes, int n_in,
                              void* d_out, int out_size, void* d_ws, size_t ws_size,
                              hipStream_t stream)
{
    const float* x     = (const float*)d_in[0];
    const float* W_kqv = (const float*)d_in[1];
    const float* b_kqv = (const float*)d_in[2];
    const float* W_out = (const float*)d_in[3];
    const float* b_out = (const float*)d_in[4];
    float* out = (float*)d_out;

    char* ws = (char*)d_ws;
    const size_t MB = 1024 * 1024;
    unsigned short* Qh = (unsigned short*)(ws);
    unsigned short* Ql = Qh + 4194304;
    unsigned short* Kh = Ql + 4194304;
    unsigned short* Kl = Kh + 4194304;
    unsigned short* Vh = Kl + 4194304;
    unsigned short* Vl = Vh + 4194304;
    unsigned short* WhT = (unsigned short*)(ws + 48 * MB);
    unsigned short* WlT = WhT + 3145728;
    unsigned short* Yh  = (unsigned short*)(ws + 48 * MB);
    unsigned short* Yl  = Yh + 4194304;
    // Xh lives in d_out (8 MB of 16): dead until out_gemm rewrites all of it.
    unsigned short* Xh = (unsigned short*)d_out;

    // WoT home: big-ws -> past the 64 MB working set, produced in prep
    // (4 launches). Otherwise aliases Qh, produced after attn (5 launches).
    const bool big = (ws_size >= 68 * MB);
    unsigned short* WoTh = big ? (unsigned short*)(ws + 64 * MB)
                               : (unsigned short*)(ws);
    unsigned short* WoTl = WoTh + 1048576;

    const int prep_blocks = 2048 + 3072 + (big ? 1024 : 0);
    prep_kernel<<<dim3(prep_blocks), 256, 0, stream>>>(
        x, W_kqv, W_out, Xh, WhT, WlT, WoTh, WoTl);
    qkv_gemm_kernel<<<dim3(768), 256, 0, stream>>>(
        Xh, WhT, WlT, b_kqv, Qh, Ql, Kh, Kl, Vh, Vl);
    attn_kernel<<<dim3(BHTOT * (SEQ / 128)), 256, 0, stream>>>(
        Qh, Ql, Kh, Kl, Vh, Vl, Yh, Yl);
    if (!big)
        splitT_kernel<<<dim3(EMBED / 32, EMBED / 32), 256, 0, stream>>>(
            W_out, WoTh, WoTl, EMBED, EMBED);
    out_gemm_kernel<<<dim3(256), 256, 0, stream>>>(
        Yh, Yl, WoTh, WoTl, b_out, out);
}

// Round 16
// 177.014 us; speedup vs baseline: 1.1166x; 1.0642x over previous
//
#include <hip/hip_runtime.h>
#include <math.h>

#define EMBED 1024
#define NH    16
#define DH    64
#define BATCH 2
#define SEQ   2048
#define MTOT  4096
#define BHTOT 32

typedef float f32x4  __attribute__((ext_vector_type(4)));
typedef float f32x16 __attribute__((ext_vector_type(16)));
typedef short s16x8  __attribute__((ext_vector_type(8)));
typedef short s16x4  __attribute__((ext_vector_type(4)));
typedef unsigned u32x2 __attribute__((ext_vector_type(2)));
typedef unsigned u32x4 __attribute__((ext_vector_type(4)));

#define AS1 __attribute__((address_space(1)))
#define AS3 __attribute__((address_space(3)))

__device__ __forceinline__ unsigned short bf16_rne(float f) {
    unsigned u = __builtin_bit_cast(unsigned, f);
    return (unsigned short)((u + 0x7FFFu + ((u >> 16) & 1u)) >> 16);
}
__device__ __forceinline__ float bf16_f(unsigned short h) {
    unsigned u = ((unsigned)h) << 16;
    return __builtin_bit_cast(float, u);
}
__device__ __forceinline__ void split2(float v, unsigned short& hi, unsigned short& lo) {
    hi = bf16_rne(v);
    lo = bf16_rne(v - bf16_f(hi));
}
__device__ __forceinline__ void gload16(const void* g, void* l) {
    __builtin_amdgcn_global_load_lds((const AS1 void*)g, (AS3 void*)l, 16, 0, 0);
}
__device__ __forceinline__ unsigned cvt_pk_bf16(float lo, float hi) {
    unsigned r;
    asm volatile("v_cvt_pk_bf16_f32 %0, %1, %2" : "=v"(r) : "v"(lo), "v"(hi));
    return r;
}
#define MFMA16(a, b, c) __builtin_amdgcn_mfma_f32_16x16x32_bf16((a), (b), (c), 0, 0, 0)
#define MFMA32(a, b, c) __builtin_amdgcn_mfma_f32_32x32x16_bf16((a), (b), (c), 0, 0, 0)

// ---------------------------------------------------------------------------
// prep: splitX (blocks [0,2048)), splitT Wkqv ([2048,5120)), optional splitT
// Wout ([5120,6144)).
// ---------------------------------------------------------------------------
__global__ __launch_bounds__(256)
void prep_kernel(const float* __restrict__ X, const float* __restrict__ Wkqv,
                 const float* __restrict__ Wout,
                 unsigned short* __restrict__ Xh,
                 unsigned short* __restrict__ WhT, unsigned short* __restrict__ WlT,
                 unsigned short* __restrict__ WoTh, unsigned short* __restrict__ WoTl)
{
    __shared__ float T[32][33];
    const int bid = blockIdx.x, tid = threadIdx.x;

    if (bid < 2048) {   // ---- splitX: X fp32 -> Xh bf16
        const size_t i = ((size_t)bid * 256 + tid) * 8;
        float4 a = *(const float4*)&X[i];
        float4 b = *(const float4*)&X[i + 4];
        float v[8] = {a.x, a.y, a.z, a.w, b.x, b.y, b.z, b.w};
        s16x8 h8;
#pragma unroll
        for (int e = 0; e < 8; ++e) h8[e] = (short)bf16_rne(v[e]);
        *(s16x8*)&Xh[i] = h8;
        return;
    }

    const float* W;
    unsigned short *Hi, *Lo;
    int Nd, n0, k0;
    if (bid < 5120) {
        const int u = bid - 2048;
        W = Wkqv; Hi = WhT; Lo = WlT; Nd = 3072;
        n0 = (u % 96) * 32; k0 = (u / 96) * 32;
    } else {
        const int u = bid - 5120;
        W = Wout; Hi = WoTh; Lo = WoTl; Nd = 1024;
        n0 = (u & 31) * 32; k0 = (u >> 5) * 32;
    }
    constexpr int Kd = 1024;
    {
        const int row = tid >> 3, c4 = (tid & 7) * 4;
        float4 v = *(const float4*)&W[(size_t)(k0 + row) * Nd + n0 + c4];
        T[row][c4] = v.x; T[row][c4 + 1] = v.y; T[row][c4 + 2] = v.z; T[row][c4 + 3] = v.w;
    }
    __syncthreads();
    {
        const int nr = tid >> 3, c4 = (tid & 7) * 4;
        s16x4 h4, l4;
#pragma unroll
        for (int e = 0; e < 4; ++e) {
            unsigned short h, l;
            split2(T[c4 + e][nr], h, l);
            h4[e] = (short)h; l4[e] = (short)l;
        }
        *(s16x4*)&Hi[(size_t)(n0 + nr) * Kd + k0 + c4] = h4;
        *(s16x4*)&Lo[(size_t)(n0 + nr) * Kd + k0 + c4] = l4;
    }
}

// ---------------------------------------------------------------------------
// splitT (standalone fallback when ws cannot host WoT before attn finishes).
// ---------------------------------------------------------------------------
__global__ __launch_bounds__(256)
void splitT_kernel(const float* __restrict__ W, unsigned short* __restrict__ HiT,
                   unsigned short* __restrict__ LoT, int Kd, int Nd)
{
    __shared__ float T[32][33];
    const int tid = threadIdx.x;
    const int n0 = blockIdx.x * 32, k0 = blockIdx.y * 32;
    {
        const int row = tid >> 3, c4 = (tid & 7) * 4;
        float4 v = *(const float4*)&W[(size_t)(k0 + row) * Nd + n0 + c4];
        T[row][c4] = v.x; T[row][c4 + 1] = v.y; T[row][c4 + 2] = v.z; T[row][c4 + 3] = v.w;
    }
    __syncthreads();
    {
        const int nr = tid >> 3, c4 = (tid & 7) * 4;
        s16x4 h4, l4;
#pragma unroll
        for (int e = 0; e < 4; ++e) {
            unsigned short h, l;
            split2(T[c4 + e][nr], h, l);
            h4[e] = (short)h; l4[e] = (short)l;
        }
        *(s16x4*)&HiT[(size_t)(n0 + nr) * Kd + k0 + c4] = h4;
        *(s16x4*)&LoT[(size_t)(n0 + nr) * Kd + k0 + c4] = l4;
    }
}

// ---------------------------------------------------------------------------
// QKV GEMM (r15): 2-combo split on mfma_32x32x16, 128x128 tile, BK=32,
// dbuf 48 KB, issue-early staging, XCD swizzle. K output is hi-only now.
// ---------------------------------------------------------------------------
__global__ __launch_bounds__(256)
void qkv_gemm_kernel(const unsigned short* __restrict__ Xh_g,
                     const unsigned short* __restrict__ BhT, const unsigned short* __restrict__ BlT,
                     const float* __restrict__ bias,
                     unsigned short* __restrict__ Qh, unsigned short* __restrict__ Ql,
                     unsigned short* __restrict__ Kh,
                     unsigned short* __restrict__ Vh, unsigned short* __restrict__ Vl)
{
    constexpr int KD = 1024;
    __shared__ __align__(16) short SB[2][12288];   // 48 KB

    const int tid = threadIdx.x, lane = tid & 63, wid = tid >> 6;
    const int l31 = lane & 31, l5 = lane >> 5;
    const int wm = wid >> 1, wn = wid & 1;

    const int bid = blockIdx.x;
    const int u = bid >> 3, xcd = bid & 7;
    const int by = xcd * 4 + (u & 3);   // m-tile 0..31
    const int bx = u >> 2;              // n-tile 0..23
    const int m0 = by * 128, n0 = bx * 128;

    f32x16 acc[2][2];
#pragma unroll
    for (int i = 0; i < 2; ++i)
#pragma unroll
        for (int j = 0; j < 2; ++j)
#pragma unroll
            for (int e = 0; e < 16; ++e) acc[i][j][e] = 0.f;

    const int srow = lane >> 2, ss = lane & 3;

    {
#pragma unroll
        for (int i = 0; i < 6; ++i) {
            const int s = wid * 6 + i;
            const int t = s >> 3, j = s & 7;
            const unsigned short* gsrc = (t == 0) ? Xh_g : (t == 1) ? BhT : BlT;
            const int roff = (t == 0) ? m0 : n0;
            const int row_loc = j * 16 + srow;
            const int kc = ss ^ ((row_loc >> 1) & 3);
            gload16(gsrc + (size_t)(roff + row_loc) * KD + kc * 8,
                    &SB[0][t * 4096 + j * 512]);
        }
    }

    for (int it = 0; it < 32; ++it) {
        const int cur = it & 1;
        __syncthreads();
        if (it + 1 < 32) {
            const int k0n = (it + 1) * 32;
#pragma unroll
            for (int i = 0; i < 6; ++i) {
                const int s = wid * 6 + i;
                const int t = s >> 3, j = s & 7;
                const unsigned short* gsrc = (t == 0) ? Xh_g : (t == 1) ? BhT : BlT;
                const int roff = (t == 0) ? m0 : n0;
                const int row_loc = j * 16 + srow;
                const int kc = ss ^ ((row_loc >> 1) & 3);
                gload16(gsrc + (size_t)(roff + row_loc) * KD + k0n + kc * 8,
                        &SB[cur ^ 1][t * 4096 + j * 512]);
            }
        }
        const short* Ahp = &SB[cur][0];
        const short* Bhp = &SB[cur][4096];
        const short* Blp = &SB[cur][8192];

        s16x8 fa[2][2], fbh[2][2], fbl[2][2];
#pragma unroll
        for (int am = 0; am < 2; ++am) {
            const int row = wm * 64 + am * 32 + l31;
            const int sw = (row >> 1) & 3;
#pragma unroll
            for (int kh2 = 0; kh2 < 2; ++kh2) {
                const int sl = ((kh2 * 2 + l5) ^ sw) * 8;
                fa[am][kh2] = *(const s16x8*)&Ahp[row * 32 + sl];
            }
        }
#pragma unroll
        for (int bn = 0; bn < 2; ++bn) {
            const int row = wn * 64 + bn * 32 + l31;
            const int sw = (row >> 1) & 3;
#pragma unroll
            for (int kh2 = 0; kh2 < 2; ++kh2) {
                const int sl = ((kh2 * 2 + l5) ^ sw) * 8;
                fbh[bn][kh2] = *(const s16x8*)&Bhp[row * 32 + sl];
                fbl[bn][kh2] = *(const s16x8*)&Blp[row * 32 + sl];
            }
        }
#pragma unroll
        for (int kh2 = 0; kh2 < 2; ++kh2)
#pragma unroll
            for (int am = 0; am < 2; ++am)
#pragma unroll
                for (int bn = 0; bn < 2; ++bn)
                    acc[am][bn] = MFMA32(fa[am][kh2], fbh[bn][kh2], acc[am][bn]);
#pragma unroll
        for (int kh2 = 0; kh2 < 2; ++kh2)
#pragma unroll
            for (int am = 0; am < 2; ++am)
#pragma unroll
                for (int bn = 0; bn < 2; ++bn)
                    acc[am][bn] = MFMA32(fa[am][kh2], fbl[bn][kh2], acc[am][bn]);
    }

    // epilogue (D: col=l31, row=(r&3)+8*(r>>2)+4*l5)
#pragma unroll
    for (int am = 0; am < 2; ++am)
#pragma unroll
        for (int bn = 0; bn < 2; ++bn) {
            const int n = n0 + wn * 64 + bn * 32 + l31;
            const float bv = bias[n];
            const int sec = n >> 10, cc = n & 1023, h = cc >> 6, d = cc & 63;
#pragma unroll
            for (int r = 0; r < 16; ++r) {
                const int mrow = (r & 3) + 8 * (r >> 2) + 4 * l5;
                const int m = m0 + wm * 64 + am * 32 + mrow;
                const int bb = m >> 11, t = m & 2047;
                const int bh_i = bb * NH + h;
                float val = acc[am][bn][r] + bv;
                unsigned short hi, lo;
                if (sec == 0) {
                    val *= 0.125f; split2(val, hi, lo);
                    size_t idx = ((size_t)bh_i * SEQ + t) * DH + d;
                    Qh[idx] = hi; Ql[idx] = lo;
                } else if (sec == 1) {
                    size_t idx = ((size_t)bh_i * SEQ + t) * DH + d;
                    Kh[idx] = bf16_rne(val);          // K hi-only
                } else {
                    split2(val, hi, lo);
                    size_t idx = ((size_t)bh_i * DH + d) * SEQ + t;   // V transposed
                    Vh[idx] = hi; Vl[idx] = lo;
                }
            }
        }
}

// ---------------------------------------------------------------------------
// Attention: K hi-only -> QK^T 2-combo (kh.qh + kh.ql); PV 2-combo.
// 3 staged arrays {Kh,Vh,Vl} double-buffered in 48 KB LDS, 24-segment
// staging (6/wave). Defer-max THR=8; interleaved MFMA accumulators.
// ---------------------------------------------------------------------------
__global__ __launch_bounds__(256)
void attn_kernel(const unsigned short* __restrict__ Qh_g, const unsigned short* __restrict__ Ql_g,
                 const unsigned short* __restrict__ Kh_g,
                 const unsigned short* __restrict__ Vh_g, const unsigned short* __restrict__ Vl_g,
                 unsigned short* __restrict__ Yh, unsigned short* __restrict__ Yl)
{
    __shared__ __align__(16) short SM[2][12288];   // 48 KB: 2 bufs x {Kh,Vh,Vl}

    const int tid = threadIdx.x, lane = tid & 63, wid = tid >> 6;
    const int l31 = lane & 31, l5 = lane >> 5;
    const int bid = blockIdx.x;
    const int qb = 15 - (bid >> 5), bh = bid & 31;   // heavy q-tiles first
    const int Q0 = qb * 128;
    const int qg = Q0 + wid * 32 + l31;              // this lane's q row

    // Q fragments from global (once per block)
    s16x8 qfh[4], qfl[4];
    {
        const size_t qo = ((size_t)bh * SEQ + qg) * DH;
#pragma unroll
        for (int t = 0; t < 4; ++t) {
            const int ch = t * 2 + l5;
            qfh[t] = *(const s16x8*)&Qh_g[qo + ch * 8];
            qfl[t] = *(const s16x8*)&Ql_g[qo + ch * 8];
        }
    }

    float m_i = -INFINITY, l_i = 0.f;
    f32x16 yacc[2];
#pragma unroll
    for (int e = 0; e < 16; ++e) { yacc[0][e] = 0.f; yacc[1][e] = 0.f; }

    const int srow = lane >> 3, ss = lane & 7;
    const int KT = 2 * qb + 2;

    // staging: 24 segments = 3 arrays {Kh,Vh,Vl} x 8; 6 per wave.
    // t = s>>3 (0=K,1=Vh,2=Vl), j = s&7, row = j*8+srow, kc = ss^(row&7)
    {
#pragma unroll
        for (int i = 0; i < 6; ++i) {
            const int s = wid * 6 + i;
            const int t = s >> 3, j = s & 7;
            const int row = j * 8 + srow;
            const int kc = ss ^ (row & 7);
            const unsigned short* src = (t == 0)
                ? Kh_g + ((size_t)bh * SEQ + row) * DH + kc * 8
                : ((t == 1) ? Vh_g : Vl_g) + ((size_t)bh * DH + row) * SEQ + kc * 8;
            gload16(src, &SM[0][t * 4096 + j * 512]);
        }
    }

    for (int kt = 0; kt < KT; ++kt) {
        const int cur = kt & 1;
        __syncthreads();   // stage(kt) landed; reads of buf[cur] (kt-2) done
        if (kt + 1 < KT) {
            const int kn = (kt + 1) * 64;
#pragma unroll
            for (int i = 0; i < 6; ++i) {
                const int s = wid * 6 + i;
                const int t = s >> 3, j = s & 7;
                const int row = j * 8 + srow;
                const int kc = ss ^ (row & 7);
                const unsigned short* src = (t == 0)
                    ? Kh_g + ((size_t)bh * SEQ + kn + row) * DH + kc * 8
                    : ((t == 1) ? Vh_g : Vl_g) + ((size_t)bh * DH + row) * SEQ + kn + kc * 8;
                gload16(src, &SM[cur ^ 1][t * 4096 + j * 512]);
            }
        }

        if (kt * 64 > Q0 + wid * 32 + 31) continue;   // fully masked for this wave

        const short* Ksh = &SM[cur][0];
        const short* Vsh = &SM[cur][4096];
        const short* Vsl = &SM[cur][8192];

        // ---- S^T = K . Q  (2-combo: kh.qh + kh.ql; interleaved kb)
        f32x16 s[2];
#pragma unroll
        for (int e = 0; e < 16; ++e) { s[0][e] = 0.f; s[1][e] = 0.f; }
#pragma unroll
        for (int t = 0; t < 4; ++t) {
            s16x8 kh[2];
#pragma unroll
            for (int kb = 0; kb < 2; ++kb) {
                const int row = kb * 32 + l31;
                const int sl = ((t * 2 + l5) ^ (row & 7)) * 8;
                kh[kb] = *(const s16x8*)&Ksh[row * 64 + sl];
            }
#pragma unroll
            for (int kb = 0; kb < 2; ++kb) s[kb] = MFMA32(kh[kb], qfh[t], s[kb]);
#pragma unroll
            for (int kb = 0; kb < 2; ++kb) s[kb] = MFMA32(kh[kb], qfl[t], s[kb]);
        }

        // ---- causal mask (only near the diagonal)
        if (kt * 64 + 63 > Q0 + wid * 32) {
#pragma unroll
            for (int kb = 0; kb < 2; ++kb)
#pragma unroll
                for (int r = 0; r < 16; ++r) {
                    const int key = kt * 64 + kb * 32 + (r & 3) + 8 * (r >> 2) + 4 * l5;
                    if (key > qg) s[kb][r] = -INFINITY;
                }
        }

        // ---- online softmax, in-register (q = lane&31), defer-max THR=8
        float mx = s[0][0];
#pragma unroll
        for (int r = 1; r < 16; ++r) mx = fmaxf(mx, s[0][r]);
#pragma unroll
        for (int r = 0; r < 16; ++r) mx = fmaxf(mx, s[1][r]);
        mx = fmaxf(mx, __shfl_xor(mx, 32));
        const bool defer = (__all(mx - m_i <= 8.f) != 0);
        float mref;
        if (defer) {
            mref = m_i;
        } else {
            mref = fmaxf(m_i, mx);
            const float al = __expf(m_i - mref);
            m_i = mref;
            l_i *= al;
#pragma unroll
            for (int e = 0; e < 16; ++e) { yacc[0][e] *= al; yacc[1][e] *= al; }
        }
        float ls = 0.f;
#pragma unroll
        for (int kb = 0; kb < 2; ++kb)
#pragma unroll
            for (int r = 0; r < 16; ++r) {
                s[kb][r] = __expf(s[kb][r] - mref);
                ls += s[kb][r];
            }
        ls += __shfl_xor(ls, 32);
        l_i += ls;

        // ---- P (bf16) fragments in-register: cvt_pk + permlane32_swap
        unsigned pk[2][8];
#pragma unroll
        for (int kb = 0; kb < 2; ++kb)
#pragma unroll
            for (int j = 0; j < 8; ++j)
                pk[kb][j] = cvt_pk_bf16(s[kb][2 * j], s[kb][2 * j + 1]);
        s16x8 pf[2][2];
#pragma unroll
        for (int kb = 0; kb < 2; ++kb) {
            u32x2 sA = __builtin_amdgcn_permlane32_swap(pk[kb][0], pk[kb][2], false, false);
            u32x2 sB = __builtin_amdgcn_permlane32_swap(pk[kb][1], pk[kb][3], false, false);
            u32x4 w0 = {sA[0], sB[0], sA[1], sB[1]};
            pf[kb][0] = __builtin_bit_cast(s16x8, w0);
            u32x2 sC = __builtin_amdgcn_permlane32_swap(pk[kb][4], pk[kb][6], false, false);
            u32x2 sD = __builtin_amdgcn_permlane32_swap(pk[kb][5], pk[kb][7], false, false);
            u32x4 w1 = {sC[0], sD[0], sC[1], sD[1]};
            pf[kb][1] = __builtin_bit_cast(s16x8, w1);
        }

        // ---- Y^T += V^T . P  (interleaved dt -> distance-2 chains)
#pragma unroll
        for (int t = 0; t < 4; ++t) {
            s16x8 vh[2], vl[2];
#pragma unroll
            for (int dt = 0; dt < 2; ++dt) {
                const int row = dt * 32 + l31;
                const int sl = ((t * 2 + l5) ^ (row & 7)) * 8;
                vh[dt] = *(const s16x8*)&Vsh[row * 64 + sl];
                vl[dt] = *(const s16x8*)&Vsl[row * 64 + sl];
            }
            const s16x8 pfr = pf[t >> 1][t & 1];
#pragma unroll
            for (int dt = 0; dt < 2; ++dt) yacc[dt] = MFMA32(vh[dt], pfr, yacc[dt]);
#pragma unroll
            for (int dt = 0; dt < 2; ++dt) yacc[dt] = MFMA32(vl[dt], pfr, yacc[dt]);
        }
    }

    // ---- epilogue: normalize, split, LDS transpose bounce, coalesced write
    __syncthreads();   // everyone done with K/V LDS
    short* SMf = &SM[0][0];
    const float inv = 1.f / l_i;
    const int qlcl = wid * 32 + l31;
#pragma unroll
    for (int dt = 0; dt < 2; ++dt)
#pragma unroll
        for (int rq = 0; rq < 4; ++rq) {
            const int d0 = dt * 32 + rq * 8 + 4 * l5;
            s16x4 h4, l4;
#pragma unroll
            for (int c = 0; c < 4; ++c) {
                unsigned short hh, ll;
                split2(yacc[dt][rq * 4 + c] * inv, hh, ll);
                h4[c] = (short)hh; l4[c] = (short)ll;
            }
            const int base = qlcl * 64 + (((d0 >> 3) ^ (qlcl & 7)) * 8) + (d0 & 7);
            *(s16x4*)&SMf[base] = h4;
            *(s16x4*)&SMf[8192 + base] = l4;
        }
    __syncthreads();
    const int b = bh >> 4, h = bh & 15;
#pragma unroll
    for (int i = 0; i < 4; ++i) {
        const int idx = tid + i * 256;
        const int row = idx >> 3, ch = idx & 7;
        const int sl = (ch ^ (row & 7)) * 8;
        s16x8 vh8 = *(const s16x8*)&SMf[row * 64 + sl];
        s16x8 vl8 = *(const s16x8*)&SMf[8192 + row * 64 + sl];
        const size_t o = ((size_t)(b * SEQ + Q0 + row)) * EMBED + h * DH + ch * 8;
        *(s16x8*)&Yh[o] = vh8;
        *(s16x8*)&Yl[o] = vl8;
    }
}

// ---------------------------------------------------------------------------
// Out GEMM: 2-phase pipelined staging, XCD-swizzled, combo-outer MFMA16.
// (unchanged)
// ---------------------------------------------------------------------------
__global__ __launch_bounds__(256)
void out_gemm_kernel(const unsigned short* __restrict__ Yh_g, const unsigned short* __restrict__ Yl_g,
                     const unsigned short* __restrict__ WhT, const unsigned short* __restrict__ WlT,
                     const float* __restrict__ bias, float* __restrict__ out)
{
    constexpr int KD = 1024, ND = 1024;
    __shared__ __align__(16) short SB[2][16384];   // 64 KB

    const int tid = threadIdx.x, lane = tid & 63, wid = tid >> 6;
    const int g = lane >> 4, ln = lane & 15;
    const int wm = wid >> 1, wn = wid & 1;

    const int bid = blockIdx.x;
    const int u = bid >> 3, xcd = bid & 7;
    const int by = xcd * 4 + (u & 3);   // m-tile 0..31
    const int bx = u >> 2;              // n-tile 0..7
    const int m0 = by * 128, n0 = bx * 128;

    f32x4 acc[4][4];
#pragma unroll
    for (int i = 0; i < 4; ++i)
#pragma unroll
        for (int j = 0; j < 4; ++j) acc[i][j] = (f32x4){0.f, 0.f, 0.f, 0.f};

    const int srow = lane >> 2, ss = lane & 3;
    const unsigned short* gb = (wid == 0) ? Yh_g : (wid == 1) ? Yl_g
                             : (wid == 2) ? WhT  : WlT;
    const int roff = (wid < 2) ? m0 : n0;

    {
        short* lb = &SB[0][wid * 4096];
#pragma unroll
        for (int j = 0; j < 8; ++j) {
            int row_loc = j * 16 + srow;
            int kc = ss ^ ((row_loc >> 1) & 3);
            gload16(gb + (size_t)(roff + row_loc) * KD + kc * 8, lb + j * 512);
        }
    }

    for (int it = 0; it < 32; ++it) {
        const int cur = it & 1;
        __syncthreads();
        if (it + 1 < 32) {
            short* lb = &SB[cur ^ 1][wid * 4096];
            const int k0n = (it + 1) * 32;
#pragma unroll
            for (int j = 0; j < 8; ++j) {
                int row_loc = j * 16 + srow;
                int kc = ss ^ ((row_loc >> 1) & 3);
                gload16(gb + (size_t)(roff + row_loc) * KD + k0n + kc * 8, lb + j * 512);
            }
        }
        const short* Ah = &SB[cur][0];
        const short* Al = &SB[cur][4096];
        const short* Bh = &SB[cur][8192];
        const short* Bl = &SB[cur][12288];

        s16x8 fah[4], fal[4], fbh[4], fbl[4];
#pragma unroll
        for (int am = 0; am < 4; ++am) {
            int m_loc = wm * 64 + am * 16 + ln;
            int sl = (g ^ ((m_loc >> 1) & 3)) * 8;
            fah[am] = *(const s16x8*)&Ah[m_loc * 32 + sl];
            fal[am] = *(const s16x8*)&Al[m_loc * 32 + sl];
        }
#pragma unroll
        for (int bn = 0; bn < 4; ++bn) {
            int n_loc = wn * 64 + bn * 16 + ln;
            int sl = (g ^ ((n_loc >> 1) & 3)) * 8;
            fbh[bn] = *(const s16x8*)&Bh[n_loc * 32 + sl];
            fbl[bn] = *(const s16x8*)&Bl[n_loc * 32 + sl];
        }
#pragma unroll
        for (int am = 0; am < 4; ++am)
#pragma unroll
            for (int bn = 0; bn < 4; ++bn)
                acc[am][bn] = MFMA16(fah[am], fbh[bn], acc[am][bn]);
#pragma unroll
        for (int am = 0; am < 4; ++am)
#pragma unroll
            for (int bn = 0; bn < 4; ++bn)
                acc[am][bn] = MFMA16(fah[am], fbl[bn], acc[am][bn]);
#pragma unroll
        for (int am = 0; am < 4; ++am)
#pragma unroll
            for (int bn = 0; bn < 4; ++bn)
                acc[am][bn] = MFMA16(fal[am], fbh[bn], acc[am][bn]);
    }

#pragma unroll
    for (int am = 0; am < 4; ++am)
#pragma unroll
        for (int bn = 0; bn < 4; ++bn) {
            int n = n0 + wn * 64 + bn * 16 + ln;
            float bv = bias[n];
#pragma unroll
            for (int r = 0; r < 4; ++r) {
                int m = m0 + wm * 64 + am * 16 + g * 4 + r;
                out[(size_t)m * ND + n] = acc[am][bn][r] + bv;
            }
        }
}

// ---------------------------------------------------------------------------
extern "C" void kernel_launch(void* const* d_in, const int* in_sizes, int n_in,
                              void* d_out, int out_size, void* d_ws, size_t ws_size,
                              hipStream_t stream)
{
    const float* x     = (const float*)d_in[0];
    const float* W_kqv = (const float*)d_in[1];
    const float* b_kqv = (const float*)d_in[2];
    const float* W_out = (const float*)d_in[3];
    const float* b_out = (const float*)d_in[4];
    float* out = (float*)d_out;

    char* ws = (char*)d_ws;
    const size_t MB = 1024 * 1024;
    unsigned short* Qh = (unsigned short*)(ws);
    unsigned short* Ql = Qh + 4194304;
    unsigned short* Kh = Ql + 4194304;
    unsigned short* Vh = Kh + 8388608;   // (old Kl slot left unused)
    unsigned short* Vl = Vh + 4194304;
    unsigned short* WhT = (unsigned short*)(ws + 48 * MB);
    unsigned short* WlT = WhT + 3145728;
    unsigned short* Yh  = (unsigned short*)(ws + 48 * MB);
    unsigned short* Yl  = Yh + 4194304;
    // Xh lives in d_out (8 MB of 16): dead until out_gemm rewrites all of it.
    unsigned short* Xh = (unsigned short*)d_out;

    const bool big = (ws_size >= 68 * MB);
    unsigned short* WoTh = big ? (unsigned short*)(ws + 64 * MB)
                               : (unsigned short*)(ws);
    unsigned short* WoTl = WoTh + 1048576;

    const int prep_blocks = 2048 + 3072 + (big ? 1024 : 0);
    prep_kernel<<<dim3(prep_blocks), 256, 0, stream>>>(
        x, W_kqv, W_out, Xh, WhT, WlT, WoTh, WoTl);
    qkv_gemm_kernel<<<dim3(768), 256, 0, stream>>>(
        Xh, WhT, WlT, b_kqv, Qh, Ql, Kh, Vh, Vl);
    attn_kernel<<<dim3(BHTOT * (SEQ / 128)), 256, 0, stream>>>(
        Qh, Ql, Kh, Vh, Vl, Yh, Yl);
    if (!big)
        splitT_kernel<<<dim3(EMBED / 32, EMBED / 32), 256, 0, stream>>>(
            W_out, WoTh, WoTl, EMBED, EMBED);
    out_gemm_kernel<<<dim3(256), 256, 0, stream>>>(
        Yh, Yl, WoTh, WoTl, b_out, out);
}

// Round 17
// 172.120 us; speedup vs baseline: 1.1484x; 1.0284x over previous
//
#include <hip/hip_runtime.h>
#include <math.h>

#define EMBED 1024
#define NH    16
#define DH    64
#define BATCH 2
#define SEQ   2048
#define MTOT  4096
#define BHTOT 32

typedef float f32x4  __attribute__((ext_vector_type(4)));
typedef float f32x16 __attribute__((ext_vector_type(16)));
typedef short s16x8  __attribute__((ext_vector_type(8)));
typedef short s16x4  __attribute__((ext_vector_type(4)));
typedef unsigned u32x2 __attribute__((ext_vector_type(2)));
typedef unsigned u32x4 __attribute__((ext_vector_type(4)));

#define AS1 __attribute__((address_space(1)))
#define AS3 __attribute__((address_space(3)))

__device__ __forceinline__ unsigned short bf16_rne(float f) {
    unsigned u = __builtin_bit_cast(unsigned, f);
    return (unsigned short)((u + 0x7FFFu + ((u >> 16) & 1u)) >> 16);
}
__device__ __forceinline__ float bf16_f(unsigned short h) {
    unsigned u = ((unsigned)h) << 16;
    return __builtin_bit_cast(float, u);
}
__device__ __forceinline__ void split2(float v, unsigned short& hi, unsigned short& lo) {
    hi = bf16_rne(v);
    lo = bf16_rne(v - bf16_f(hi));
}
__device__ __forceinline__ void gload16(const void* g, void* l) {
    __builtin_amdgcn_global_load_lds((const AS1 void*)g, (AS3 void*)l, 16, 0, 0);
}
__device__ __forceinline__ unsigned cvt_pk_bf16(float lo, float hi) {
    unsigned r;
    asm volatile("v_cvt_pk_bf16_f32 %0, %1, %2" : "=v"(r) : "v"(lo), "v"(hi));
    return r;
}
#define MFMA16(a, b, c) __builtin_amdgcn_mfma_f32_16x16x32_bf16((a), (b), (c), 0, 0, 0)
#define MFMA32(a, b, c) __builtin_amdgcn_mfma_f32_32x32x16_bf16((a), (b), (c), 0, 0, 0)

// ---------------------------------------------------------------------------
// prep: splitX (blocks [0,2048)), splitT Wkqv ([2048,5120)), optional splitT
// Wout ([5120,6144)).
// ---------------------------------------------------------------------------
__global__ __launch_bounds__(256)
void prep_kernel(const float* __restrict__ X, const float* __restrict__ Wkqv,
                 const float* __restrict__ Wout,
                 unsigned short* __restrict__ Xh,
                 unsigned short* __restrict__ WhT, unsigned short* __restrict__ WlT,
                 unsigned short* __restrict__ WoTh, unsigned short* __restrict__ WoTl)
{
    __shared__ float T[32][33];
    const int bid = blockIdx.x, tid = threadIdx.x;

    if (bid < 2048) {   // ---- splitX: X fp32 -> Xh bf16
        const size_t i = ((size_t)bid * 256 + tid) * 8;
        float4 a = *(const float4*)&X[i];
        float4 b = *(const float4*)&X[i + 4];
        float v[8] = {a.x, a.y, a.z, a.w, b.x, b.y, b.z, b.w};
        s16x8 h8;
#pragma unroll
        for (int e = 0; e < 8; ++e) h8[e] = (short)bf16_rne(v[e]);
        *(s16x8*)&Xh[i] = h8;
        return;
    }

    const float* W;
    unsigned short *Hi, *Lo;
    int Nd, n0, k0;
    if (bid < 5120) {
        const int u = bid - 2048;
        W = Wkqv; Hi = WhT; Lo = WlT; Nd = 3072;
        n0 = (u % 96) * 32; k0 = (u / 96) * 32;
    } else {
        const int u = bid - 5120;
        W = Wout; Hi = WoTh; Lo = WoTl; Nd = 1024;
        n0 = (u & 31) * 32; k0 = (u >> 5) * 32;
    }
    constexpr int Kd = 1024;
    {
        const int row = tid >> 3, c4 = (tid & 7) * 4;
        float4 v = *(const float4*)&W[(size_t)(k0 + row) * Nd + n0 + c4];
        T[row][c4] = v.x; T[row][c4 + 1] = v.y; T[row][c4 + 2] = v.z; T[row][c4 + 3] = v.w;
    }
    __syncthreads();
    {
        const int nr = tid >> 3, c4 = (tid & 7) * 4;
        s16x4 h4, l4;
#pragma unroll
        for (int e = 0; e < 4; ++e) {
            unsigned short h, l;
            split2(T[c4 + e][nr], h, l);
            h4[e] = (short)h; l4[e] = (short)l;
        }
        *(s16x4*)&Hi[(size_t)(n0 + nr) * Kd + k0 + c4] = h4;
        *(s16x4*)&Lo[(size_t)(n0 + nr) * Kd + k0 + c4] = l4;
    }
}

// ---------------------------------------------------------------------------
// splitT (standalone fallback when ws cannot host WoT before attn finishes).
// ---------------------------------------------------------------------------
__global__ __launch_bounds__(256)
void splitT_kernel(const float* __restrict__ W, unsigned short* __restrict__ HiT,
                   unsigned short* __restrict__ LoT, int Kd, int Nd)
{
    __shared__ float T[32][33];
    const int tid = threadIdx.x;
    const int n0 = blockIdx.x * 32, k0 = blockIdx.y * 32;
    {
        const int row = tid >> 3, c4 = (tid & 7) * 4;
        float4 v = *(const float4*)&W[(size_t)(k0 + row) * Nd + n0 + c4];
        T[row][c4] = v.x; T[row][c4 + 1] = v.y; T[row][c4 + 2] = v.z; T[row][c4 + 3] = v.w;
    }
    __syncthreads();
    {
        const int nr = tid >> 3, c4 = (tid & 7) * 4;
        s16x4 h4, l4;
#pragma unroll
        for (int e = 0; e < 4; ++e) {
            unsigned short h, l;
            split2(T[c4 + e][nr], h, l);
            h4[e] = (short)h; l4[e] = (short)l;
        }
        *(s16x4*)&HiT[(size_t)(n0 + nr) * Kd + k0 + c4] = h4;
        *(s16x4*)&LoT[(size_t)(n0 + nr) * Kd + k0 + c4] = l4;
    }
}

// ---------------------------------------------------------------------------
// QKV GEMM (unchanged from r16): 2-combo split on mfma_32x32x16, 128x128
// tile, BK=32, dbuf 48 KB, issue-early staging, XCD swizzle. K hi-only.
// ---------------------------------------------------------------------------
__global__ __launch_bounds__(256)
void qkv_gemm_kernel(const unsigned short* __restrict__ Xh_g,
                     const unsigned short* __restrict__ BhT, const unsigned short* __restrict__ BlT,
                     const float* __restrict__ bias,
                     unsigned short* __restrict__ Qh, unsigned short* __restrict__ Ql,
                     unsigned short* __restrict__ Kh,
                     unsigned short* __restrict__ Vh, unsigned short* __restrict__ Vl)
{
    constexpr int KD = 1024;
    __shared__ __align__(16) short SB[2][12288];   // 48 KB

    const int tid = threadIdx.x, lane = tid & 63, wid = tid >> 6;
    const int l31 = lane & 31, l5 = lane >> 5;
    const int wm = wid >> 1, wn = wid & 1;

    const int bid = blockIdx.x;
    const int u = bid >> 3, xcd = bid & 7;
    const int by = xcd * 4 + (u & 3);   // m-tile 0..31
    const int bx = u >> 2;              // n-tile 0..23
    const int m0 = by * 128, n0 = bx * 128;

    f32x16 acc[2][2];
#pragma unroll
    for (int i = 0; i < 2; ++i)
#pragma unroll
        for (int j = 0; j < 2; ++j)
#pragma unroll
            for (int e = 0; e < 16; ++e) acc[i][j][e] = 0.f;

    const int srow = lane >> 2, ss = lane & 3;

    {
#pragma unroll
        for (int i = 0; i < 6; ++i) {
            const int s = wid * 6 + i;
            const int t = s >> 3, j = s & 7;
            const unsigned short* gsrc = (t == 0) ? Xh_g : (t == 1) ? BhT : BlT;
            const int roff = (t == 0) ? m0 : n0;
            const int row_loc = j * 16 + srow;
            const int kc = ss ^ ((row_loc >> 1) & 3);
            gload16(gsrc + (size_t)(roff + row_loc) * KD + kc * 8,
                    &SB[0][t * 4096 + j * 512]);
        }
    }

    for (int it = 0; it < 32; ++it) {
        const int cur = it & 1;
        __syncthreads();
        if (it + 1 < 32) {
            const int k0n = (it + 1) * 32;
#pragma unroll
            for (int i = 0; i < 6; ++i) {
                const int s = wid * 6 + i;
                const int t = s >> 3, j = s & 7;
                const unsigned short* gsrc = (t == 0) ? Xh_g : (t == 1) ? BhT : BlT;
                const int roff = (t == 0) ? m0 : n0;
                const int row_loc = j * 16 + srow;
                const int kc = ss ^ ((row_loc >> 1) & 3);
                gload16(gsrc + (size_t)(roff + row_loc) * KD + k0n + kc * 8,
                        &SB[cur ^ 1][t * 4096 + j * 512]);
            }
        }
        const short* Ahp = &SB[cur][0];
        const short* Bhp = &SB[cur][4096];
        const short* Blp = &SB[cur][8192];

        s16x8 fa[2][2], fbh[2][2], fbl[2][2];
#pragma unroll
        for (int am = 0; am < 2; ++am) {
            const int row = wm * 64 + am * 32 + l31;
            const int sw = (row >> 1) & 3;
#pragma unroll
            for (int kh2 = 0; kh2 < 2; ++kh2) {
                const int sl = ((kh2 * 2 + l5) ^ sw) * 8;
                fa[am][kh2] = *(const s16x8*)&Ahp[row * 32 + sl];
            }
        }
#pragma unroll
        for (int bn = 0; bn < 2; ++bn) {
            const int row = wn * 64 + bn * 32 + l31;
            const int sw = (row >> 1) & 3;
#pragma unroll
            for (int kh2 = 0; kh2 < 2; ++kh2) {
                const int sl = ((kh2 * 2 + l5) ^ sw) * 8;
                fbh[bn][kh2] = *(const s16x8*)&Bhp[row * 32 + sl];
                fbl[bn][kh2] = *(const s16x8*)&Blp[row * 32 + sl];
            }
        }
#pragma unroll
        for (int kh2 = 0; kh2 < 2; ++kh2)
#pragma unroll
            for (int am = 0; am < 2; ++am)
#pragma unroll
                for (int bn = 0; bn < 2; ++bn)
                    acc[am][bn] = MFMA32(fa[am][kh2], fbh[bn][kh2], acc[am][bn]);
#pragma unroll
        for (int kh2 = 0; kh2 < 2; ++kh2)
#pragma unroll
            for (int am = 0; am < 2; ++am)
#pragma unroll
                for (int bn = 0; bn < 2; ++bn)
                    acc[am][bn] = MFMA32(fa[am][kh2], fbl[bn][kh2], acc[am][bn]);
    }

    // epilogue (D: col=l31, row=(r&3)+8*(r>>2)+4*l5)
#pragma unroll
    for (int am = 0; am < 2; ++am)
#pragma unroll
        for (int bn = 0; bn < 2; ++bn) {
            const int n = n0 + wn * 64 + bn * 32 + l31;
            const float bv = bias[n];
            const int sec = n >> 10, cc = n & 1023, h = cc >> 6, d = cc & 63;
#pragma unroll
            for (int r = 0; r < 16; ++r) {
                const int mrow = (r & 3) + 8 * (r >> 2) + 4 * l5;
                const int m = m0 + wm * 64 + am * 32 + mrow;
                const int bb = m >> 11, t = m & 2047;
                const int bh_i = bb * NH + h;
                float val = acc[am][bn][r] + bv;
                unsigned short hi, lo;
                if (sec == 0) {
                    val *= 0.125f; split2(val, hi, lo);
                    size_t idx = ((size_t)bh_i * SEQ + t) * DH + d;
                    Qh[idx] = hi; Ql[idx] = lo;
                } else if (sec == 1) {
                    size_t idx = ((size_t)bh_i * SEQ + t) * DH + d;
                    Kh[idx] = bf16_rne(val);          // K hi-only
                } else {
                    split2(val, hi, lo);
                    size_t idx = ((size_t)bh_i * DH + d) * SEQ + t;   // V transposed
                    Vh[idx] = hi; Vl[idx] = lo;
                }
            }
        }
}

// ---------------------------------------------------------------------------
// Attention (r16 structure), Y output hi-only now: epilogue writes Yh
// (bf16_rne), half the LDS bounce and global writes.
// ---------------------------------------------------------------------------
__global__ __launch_bounds__(256)
void attn_kernel(const unsigned short* __restrict__ Qh_g, const unsigned short* __restrict__ Ql_g,
                 const unsigned short* __restrict__ Kh_g,
                 const unsigned short* __restrict__ Vh_g, const unsigned short* __restrict__ Vl_g,
                 unsigned short* __restrict__ Yh)
{
    __shared__ __align__(16) short SM[2][12288];   // 48 KB: 2 bufs x {Kh,Vh,Vl}

    const int tid = threadIdx.x, lane = tid & 63, wid = tid >> 6;
    const int l31 = lane & 31, l5 = lane >> 5;
    const int bid = blockIdx.x;
    const int qb = 15 - (bid >> 5), bh = bid & 31;   // heavy q-tiles first
    const int Q0 = qb * 128;
    const int qg = Q0 + wid * 32 + l31;              // this lane's q row

    // Q fragments from global (once per block)
    s16x8 qfh[4], qfl[4];
    {
        const size_t qo = ((size_t)bh * SEQ + qg) * DH;
#pragma unroll
        for (int t = 0; t < 4; ++t) {
            const int ch = t * 2 + l5;
            qfh[t] = *(const s16x8*)&Qh_g[qo + ch * 8];
            qfl[t] = *(const s16x8*)&Ql_g[qo + ch * 8];
        }
    }

    float m_i = -INFINITY, l_i = 0.f;
    f32x16 yacc[2];
#pragma unroll
    for (int e = 0; e < 16; ++e) { yacc[0][e] = 0.f; yacc[1][e] = 0.f; }

    const int srow = lane >> 3, ss = lane & 7;
    const int KT = 2 * qb + 2;

    // staging: 24 segments = 3 arrays {Kh,Vh,Vl} x 8; 6 per wave.
    {
#pragma unroll
        for (int i = 0; i < 6; ++i) {
            const int s = wid * 6 + i;
            const int t = s >> 3, j = s & 7;
            const int row = j * 8 + srow;
            const int kc = ss ^ (row & 7);
            const unsigned short* src = (t == 0)
                ? Kh_g + ((size_t)bh * SEQ + row) * DH + kc * 8
                : ((t == 1) ? Vh_g : Vl_g) + ((size_t)bh * DH + row) * SEQ + kc * 8;
            gload16(src, &SM[0][t * 4096 + j * 512]);
        }
    }

    for (int kt = 0; kt < KT; ++kt) {
        const int cur = kt & 1;
        __syncthreads();   // stage(kt) landed; reads of buf[cur] (kt-2) done
        if (kt + 1 < KT) {
            const int kn = (kt + 1) * 64;
#pragma unroll
            for (int i = 0; i < 6; ++i) {
                const int s = wid * 6 + i;
                const int t = s >> 3, j = s & 7;
                const int row = j * 8 + srow;
                const int kc = ss ^ (row & 7);
                const unsigned short* src = (t == 0)
                    ? Kh_g + ((size_t)bh * SEQ + kn + row) * DH + kc * 8
                    : ((t == 1) ? Vh_g : Vl_g) + ((size_t)bh * DH + row) * SEQ + kn + kc * 8;
                gload16(src, &SM[cur ^ 1][t * 4096 + j * 512]);
            }
        }

        if (kt * 64 > Q0 + wid * 32 + 31) continue;   // fully masked for this wave

        const short* Ksh = &SM[cur][0];
        const short* Vsh = &SM[cur][4096];
        const short* Vsl = &SM[cur][8192];

        // ---- S^T = K . Q  (2-combo: kh.qh + kh.ql; interleaved kb)
        f32x16 s[2];
#pragma unroll
        for (int e = 0; e < 16; ++e) { s[0][e] = 0.f; s[1][e] = 0.f; }
#pragma unroll
        for (int t = 0; t < 4; ++t) {
            s16x8 kh[2];
#pragma unroll
            for (int kb = 0; kb < 2; ++kb) {
                const int row = kb * 32 + l31;
                const int sl = ((t * 2 + l5) ^ (row & 7)) * 8;
                kh[kb] = *(const s16x8*)&Ksh[row * 64 + sl];
            }
#pragma unroll
            for (int kb = 0; kb < 2; ++kb) s[kb] = MFMA32(kh[kb], qfh[t], s[kb]);
#pragma unroll
            for (int kb = 0; kb < 2; ++kb) s[kb] = MFMA32(kh[kb], qfl[t], s[kb]);
        }

        // ---- causal mask (only near the diagonal)
        if (kt * 64 + 63 > Q0 + wid * 32) {
#pragma unroll
            for (int kb = 0; kb < 2; ++kb)
#pragma unroll
                for (int r = 0; r < 16; ++r) {
                    const int key = kt * 64 + kb * 32 + (r & 3) + 8 * (r >> 2) + 4 * l5;
                    if (key > qg) s[kb][r] = -INFINITY;
                }
        }

        // ---- online softmax, in-register (q = lane&31), defer-max THR=8
        float mx = s[0][0];
#pragma unroll
        for (int r = 1; r < 16; ++r) mx = fmaxf(mx, s[0][r]);
#pragma unroll
        for (int r = 0; r < 16; ++r) mx = fmaxf(mx, s[1][r]);
        mx = fmaxf(mx, __shfl_xor(mx, 32));
        const bool defer = (__all(mx - m_i <= 8.f) != 0);
        float mref;
        if (defer) {
            mref = m_i;
        } else {
            mref = fmaxf(m_i, mx);
            const float al = __expf(m_i - mref);
            m_i = mref;
            l_i *= al;
#pragma unroll
            for (int e = 0; e < 16; ++e) { yacc[0][e] *= al; yacc[1][e] *= al; }
        }
        float ls = 0.f;
#pragma unroll
        for (int kb = 0; kb < 2; ++kb)
#pragma unroll
            for (int r = 0; r < 16; ++r) {
                s[kb][r] = __expf(s[kb][r] - mref);
                ls += s[kb][r];
            }
        ls += __shfl_xor(ls, 32);
        l_i += ls;

        // ---- P (bf16) fragments in-register: cvt_pk + permlane32_swap
        unsigned pk[2][8];
#pragma unroll
        for (int kb = 0; kb < 2; ++kb)
#pragma unroll
            for (int j = 0; j < 8; ++j)
                pk[kb][j] = cvt_pk_bf16(s[kb][2 * j], s[kb][2 * j + 1]);
        s16x8 pf[2][2];
#pragma unroll
        for (int kb = 0; kb < 2; ++kb) {
            u32x2 sA = __builtin_amdgcn_permlane32_swap(pk[kb][0], pk[kb][2], false, false);
            u32x2 sB = __builtin_amdgcn_permlane32_swap(pk[kb][1], pk[kb][3], false, false);
            u32x4 w0 = {sA[0], sB[0], sA[1], sB[1]};
            pf[kb][0] = __builtin_bit_cast(s16x8, w0);
            u32x2 sC = __builtin_amdgcn_permlane32_swap(pk[kb][4], pk[kb][6], false, false);
            u32x2 sD = __builtin_amdgcn_permlane32_swap(pk[kb][5], pk[kb][7], false, false);
            u32x4 w1 = {sC[0], sD[0], sC[1], sD[1]};
            pf[kb][1] = __builtin_bit_cast(s16x8, w1);
        }

        // ---- Y^T += V^T . P  (interleaved dt -> distance-2 chains)
#pragma unroll
        for (int t = 0; t < 4; ++t) {
            s16x8 vh[2], vl[2];
#pragma unroll
            for (int dt = 0; dt < 2; ++dt) {
                const int row = dt * 32 + l31;
                const int sl = ((t * 2 + l5) ^ (row & 7)) * 8;
                vh[dt] = *(const s16x8*)&Vsh[row * 64 + sl];
                vl[dt] = *(const s16x8*)&Vsl[row * 64 + sl];
            }
            const s16x8 pfr = pf[t >> 1][t & 1];
#pragma unroll
            for (int dt = 0; dt < 2; ++dt) yacc[dt] = MFMA32(vh[dt], pfr, yacc[dt]);
#pragma unroll
            for (int dt = 0; dt < 2; ++dt) yacc[dt] = MFMA32(vl[dt], pfr, yacc[dt]);
        }
    }

    // ---- epilogue: normalize, hi-only bf16, LDS transpose bounce, write Yh
    __syncthreads();   // everyone done with K/V LDS
    short* SMf = &SM[0][0];
    const float inv = 1.f / l_i;
    const int qlcl = wid * 32 + l31;
#pragma unroll
    for (int dt = 0; dt < 2; ++dt)
#pragma unroll
        for (int rq = 0; rq < 4; ++rq) {
            const int d0 = dt * 32 + rq * 8 + 4 * l5;
            s16x4 h4;
#pragma unroll
            for (int c = 0; c < 4; ++c)
                h4[c] = (short)bf16_rne(yacc[dt][rq * 4 + c] * inv);
            const int base = qlcl * 64 + (((d0 >> 3) ^ (qlcl & 7)) * 8) + (d0 & 7);
            *(s16x4*)&SMf[base] = h4;
        }
    __syncthreads();
    const int b = bh >> 4, h = bh & 15;
#pragma unroll
    for (int i = 0; i < 4; ++i) {
        const int idx = tid + i * 256;
        const int row = idx >> 3, ch = idx & 7;
        const int sl = (ch ^ (row & 7)) * 8;
        s16x8 vh8 = *(const s16x8*)&SMf[row * 64 + sl];
        const size_t o = ((size_t)(b * SEQ + Q0 + row)) * EMBED + h * DH + ch * 8;
        *(s16x8*)&Yh[o] = vh8;
    }
}

// ---------------------------------------------------------------------------
// Out GEMM: 2-combo (Yh.Wh + Yh.Wl), 3 staged arrays, dbuf 48 KB,
// 24-segment issue-early staging, XCD swizzle, combo-outer MFMA16.
// ---------------------------------------------------------------------------
__global__ __launch_bounds__(256)
void out_gemm_kernel(const unsigned short* __restrict__ Yh_g,
                     const unsigned short* __restrict__ WhT, const unsigned short* __restrict__ WlT,
                     const float* __restrict__ bias, float* __restrict__ out)
{
    constexpr int KD = 1024, ND = 1024;
    __shared__ __align__(16) short SB[2][12288];   // 48 KB

    const int tid = threadIdx.x, lane = tid & 63, wid = tid >> 6;
    const int g = lane >> 4, ln = lane & 15;
    const int wm = wid >> 1, wn = wid & 1;

    const int bid = blockIdx.x;
    const int u = bid >> 3, xcd = bid & 7;
    const int by = xcd * 4 + (u & 3);   // m-tile 0..31
    const int bx = u >> 2;              // n-tile 0..7
    const int m0 = by * 128, n0 = bx * 128;

    f32x4 acc[4][4];
#pragma unroll
    for (int i = 0; i < 4; ++i)
#pragma unroll
        for (int j = 0; j < 4; ++j) acc[i][j] = (f32x4){0.f, 0.f, 0.f, 0.f};

    const int srow = lane >> 2, ss = lane & 3;

    {
#pragma unroll
        for (int i = 0; i < 6; ++i) {
            const int s = wid * 6 + i;
            const int t = s >> 3, j = s & 7;
            const unsigned short* gsrc = (t == 0) ? Yh_g : (t == 1) ? WhT : WlT;
            const int roff = (t == 0) ? m0 : n0;
            const int row_loc = j * 16 + srow;
            const int kc = ss ^ ((row_loc >> 1) & 3);
            gload16(gsrc + (size_t)(roff + row_loc) * KD + kc * 8,
                    &SB[0][t * 4096 + j * 512]);
        }
    }

    for (int it = 0; it < 32; ++it) {
        const int cur = it & 1;
        __syncthreads();
        if (it + 1 < 32) {
            const int k0n = (it + 1) * 32;
#pragma unroll
            for (int i = 0; i < 6; ++i) {
                const int s = wid * 6 + i;
                const int t = s >> 3, j = s & 7;
                const unsigned short* gsrc = (t == 0) ? Yh_g : (t == 1) ? WhT : WlT;
                const int roff = (t == 0) ? m0 : n0;
                const int row_loc = j * 16 + srow;
                const int kc = ss ^ ((row_loc >> 1) & 3);
                gload16(gsrc + (size_t)(roff + row_loc) * KD + k0n + kc * 8,
                        &SB[cur ^ 1][t * 4096 + j * 512]);
            }
        }
        const short* Ah = &SB[cur][0];
        const short* Bh = &SB[cur][4096];
        const short* Bl = &SB[cur][8192];

        s16x8 fah[4], fbh[4], fbl[4];
#pragma unroll
        for (int am = 0; am < 4; ++am) {
            int m_loc = wm * 64 + am * 16 + ln;
            int sl = (g ^ ((m_loc >> 1) & 3)) * 8;
            fah[am] = *(const s16x8*)&Ah[m_loc * 32 + sl];
        }
#pragma unroll
        for (int bn = 0; bn < 4; ++bn) {
            int n_loc = wn * 64 + bn * 16 + ln;
            int sl = (g ^ ((n_loc >> 1) & 3)) * 8;
            fbh[bn] = *(const s16x8*)&Bh[n_loc * 32 + sl];
            fbl[bn] = *(const s16x8*)&Bl[n_loc * 32 + sl];
        }
#pragma unroll
        for (int am = 0; am < 4; ++am)
#pragma unroll
            for (int bn = 0; bn < 4; ++bn)
                acc[am][bn] = MFMA16(fah[am], fbh[bn], acc[am][bn]);
#pragma unroll
        for (int am = 0; am < 4; ++am)
#pragma unroll
            for (int bn = 0; bn < 4; ++bn)
                acc[am][bn] = MFMA16(fah[am], fbl[bn], acc[am][bn]);
    }

#pragma unroll
    for (int am = 0; am < 4; ++am)
#pragma unroll
        for (int bn = 0; bn < 4; ++bn) {
            int n = n0 + wn * 64 + bn * 16 + ln;
            float bv = bias[n];
#pragma unroll
            for (int r = 0; r < 4; ++r) {
                int m = m0 + wm * 64 + am * 16 + g * 4 + r;
                out[(size_t)m * ND + n] = acc[am][bn][r] + bv;
            }
        }
}

// ---------------------------------------------------------------------------
extern "C" void kernel_launch(void* const* d_in, const int* in_sizes, int n_in,
                              void* d_out, int out_size, void* d_ws, size_t ws_size,
                              hipStream_t stream)
{
    const float* x     = (const float*)d_in[0];
    const float* W_kqv = (const float*)d_in[1];
    const float* b_kqv = (const float*)d_in[2];
    const float* W_out = (const float*)d_in[3];
    const float* b_out = (const float*)d_in[4];
    float* out = (float*)d_out;

    char* ws = (char*)d_ws;
    const size_t MB = 1024 * 1024;
    unsigned short* Qh = (unsigned short*)(ws);
    unsigned short* Ql = Qh + 4194304;
    unsigned short* Kh = Ql + 4194304;
    unsigned short* Vh = Kh + 8388608;   // (old Kl slot unused)
    unsigned short* Vl = Vh + 4194304;
    unsigned short* WhT = (unsigned short*)(ws + 48 * MB);
    unsigned short* WlT = WhT + 3145728;
    unsigned short* Yh  = (unsigned short*)(ws + 48 * MB);
    // Xh lives in d_out (8 MB of 16): dead until out_gemm rewrites all of it.
    unsigned short* Xh = (unsigned short*)d_out;

    const bool big = (ws_size >= 68 * MB);
    unsigned short* WoTh = big ? (unsigned short*)(ws + 64 * MB)
                               : (unsigned short*)(ws);
    unsigned short* WoTl = WoTh + 1048576;

    const int prep_blocks = 2048 + 3072 + (big ? 1024 : 0);
    prep_kernel<<<dim3(prep_blocks), 256, 0, stream>>>(
        x, W_kqv, W_out, Xh, WhT, WlT, WoTh, WoTl);
    qkv_gemm_kernel<<<dim3(768), 256, 0, stream>>>(
        Xh, WhT, WlT, b_kqv, Qh, Ql, Kh, Vh, Vl);
    attn_kernel<<<dim3(BHTOT * (SEQ / 128)), 256, 0, stream>>>(
        Qh, Ql, Kh, Vh, Vl, Yh);
    if (!big)
        splitT_kernel<<<dim3(EMBED / 32, EMBED / 32), 256, 0, stream>>>(
            W_out, WoTh, WoTl, EMBED, EMBED);
    out_gemm_kernel<<<dim3(256), 256, 0, stream>>>(
        Yh, WoTh, WoTl, b_out, out);
}

// Round 18
// 152.414 us; speedup vs baseline: 1.2969x; 1.1293x over previous
//
#include <hip/hip_runtime.h>
#include <math.h>

#define EMBED 1024
#define NH    16
#define DH    64
#define BATCH 2
#define SEQ   2048
#define MTOT  4096
#define BHTOT 32

typedef float f32x4  __attribute__((ext_vector_type(4)));
typedef float f32x16 __attribute__((ext_vector_type(16)));
typedef short s16x8  __attribute__((ext_vector_type(8)));
typedef short s16x4  __attribute__((ext_vector_type(4)));
typedef unsigned u32x2 __attribute__((ext_vector_type(2)));
typedef unsigned u32x4 __attribute__((ext_vector_type(4)));

#define AS1 __attribute__((address_space(1)))
#define AS3 __attribute__((address_space(3)))

__device__ __forceinline__ unsigned short bf16_rne(float f) {
    unsigned u = __builtin_bit_cast(unsigned, f);
    return (unsigned short)((u + 0x7FFFu + ((u >> 16) & 1u)) >> 16);
}
__device__ __forceinline__ float bf16_f(unsigned short h) {
    unsigned u = ((unsigned)h) << 16;
    return __builtin_bit_cast(float, u);
}
__device__ __forceinline__ void split2(float v, unsigned short& hi, unsigned short& lo) {
    hi = bf16_rne(v);
    lo = bf16_rne(v - bf16_f(hi));
}
__device__ __forceinline__ void gload16(const void* g, void* l) {
    __builtin_amdgcn_global_load_lds((const AS1 void*)g, (AS3 void*)l, 16, 0, 0);
}
__device__ __forceinline__ unsigned cvt_pk_bf16(float lo, float hi) {
    unsigned r;
    asm volatile("v_cvt_pk_bf16_f32 %0, %1, %2" : "=v"(r) : "v"(lo), "v"(hi));
    return r;
}
#define MFMA16(a, b, c) __builtin_amdgcn_mfma_f32_16x16x32_bf16((a), (b), (c), 0, 0, 0)
#define MFMA32(a, b, c) __builtin_amdgcn_mfma_f32_32x32x16_bf16((a), (b), (c), 0, 0, 0)

// ---------------------------------------------------------------------------
// prep: splitX (blocks [0,2048)), splitT Wkqv ([2048,5120)), optional splitT
// Wout ([5120,6144)).
// ---------------------------------------------------------------------------
__global__ __launch_bounds__(256)
void prep_kernel(const float* __restrict__ X, const float* __restrict__ Wkqv,
                 const float* __restrict__ Wout,
                 unsigned short* __restrict__ Xh,
                 unsigned short* __restrict__ WhT, unsigned short* __restrict__ WlT,
                 unsigned short* __restrict__ WoTh, unsigned short* __restrict__ WoTl)
{
    __shared__ float T[32][33];
    const int bid = blockIdx.x, tid = threadIdx.x;

    if (bid < 2048) {   // ---- splitX: X fp32 -> Xh bf16
        const size_t i = ((size_t)bid * 256 + tid) * 8;
        float4 a = *(const float4*)&X[i];
        float4 b = *(const float4*)&X[i + 4];
        float v[8] = {a.x, a.y, a.z, a.w, b.x, b.y, b.z, b.w};
        s16x8 h8;
#pragma unroll
        for (int e = 0; e < 8; ++e) h8[e] = (short)bf16_rne(v[e]);
        *(s16x8*)&Xh[i] = h8;
        return;
    }

    const float* W;
    unsigned short *Hi, *Lo;
    int Nd, n0, k0;
    if (bid < 5120) {
        const int u = bid - 2048;
        W = Wkqv; Hi = WhT; Lo = WlT; Nd = 3072;
        n0 = (u % 96) * 32; k0 = (u / 96) * 32;
    } else {
        const int u = bid - 5120;
        W = Wout; Hi = WoTh; Lo = WoTl; Nd = 1024;
        n0 = (u & 31) * 32; k0 = (u >> 5) * 32;
    }
    constexpr int Kd = 1024;
    {
        const int row = tid >> 3, c4 = (tid & 7) * 4;
        float4 v = *(const float4*)&W[(size_t)(k0 + row) * Nd + n0 + c4];
        T[row][c4] = v.x; T[row][c4 + 1] = v.y; T[row][c4 + 2] = v.z; T[row][c4 + 3] = v.w;
    }
    __syncthreads();
    {
        const int nr = tid >> 3, c4 = (tid & 7) * 4;
        s16x4 h4, l4;
#pragma unroll
        for (int e = 0; e < 4; ++e) {
            unsigned short h, l;
            split2(T[c4 + e][nr], h, l);
            h4[e] = (short)h; l4[e] = (short)l;
        }
        *(s16x4*)&Hi[(size_t)(n0 + nr) * Kd + k0 + c4] = h4;
        *(s16x4*)&Lo[(size_t)(n0 + nr) * Kd + k0 + c4] = l4;
    }
}

// ---------------------------------------------------------------------------
// splitT (standalone fallback when ws cannot host WoT before attn finishes).
// ---------------------------------------------------------------------------
__global__ __launch_bounds__(256)
void splitT_kernel(const float* __restrict__ W, unsigned short* __restrict__ HiT,
                   unsigned short* __restrict__ LoT, int Kd, int Nd)
{
    __shared__ float T[32][33];
    const int tid = threadIdx.x;
    const int n0 = blockIdx.x * 32, k0 = blockIdx.y * 32;
    {
        const int row = tid >> 3, c4 = (tid & 7) * 4;
        float4 v = *(const float4*)&W[(size_t)(k0 + row) * Nd + n0 + c4];
        T[row][c4] = v.x; T[row][c4 + 1] = v.y; T[row][c4 + 2] = v.z; T[row][c4 + 3] = v.w;
    }
    __syncthreads();
    {
        const int nr = tid >> 3, c4 = (tid & 7) * 4;
        s16x4 h4, l4;
#pragma unroll
        for (int e = 0; e < 4; ++e) {
            unsigned short h, l;
            split2(T[c4 + e][nr], h, l);
            h4[e] = (short)h; l4[e] = (short)l;
        }
        *(s16x4*)&HiT[(size_t)(n0 + nr) * Kd + k0 + c4] = h4;
        *(s16x4*)&LoT[(size_t)(n0 + nr) * Kd + k0 + c4] = l4;
    }
}

// ---------------------------------------------------------------------------
// QKV GEMM: 2-combo split on mfma_32x32x16, 128x128 tile, BK=32, dbuf 48 KB,
// issue-early staging, XCD swizzle. K hi-only; V hi-only now.
// ---------------------------------------------------------------------------
__global__ __launch_bounds__(256)
void qkv_gemm_kernel(const unsigned short* __restrict__ Xh_g,
                     const unsigned short* __restrict__ BhT, const unsigned short* __restrict__ BlT,
                     const float* __restrict__ bias,
                     unsigned short* __restrict__ Qh, unsigned short* __restrict__ Ql,
                     unsigned short* __restrict__ Kh,
                     unsigned short* __restrict__ Vh)
{
    constexpr int KD = 1024;
    __shared__ __align__(16) short SB[2][12288];   // 48 KB

    const int tid = threadIdx.x, lane = tid & 63, wid = tid >> 6;
    const int l31 = lane & 31, l5 = lane >> 5;
    const int wm = wid >> 1, wn = wid & 1;

    const int bid = blockIdx.x;
    const int u = bid >> 3, xcd = bid & 7;
    const int by = xcd * 4 + (u & 3);   // m-tile 0..31
    const int bx = u >> 2;              // n-tile 0..23
    const int m0 = by * 128, n0 = bx * 128;

    f32x16 acc[2][2];
#pragma unroll
    for (int i = 0; i < 2; ++i)
#pragma unroll
        for (int j = 0; j < 2; ++j)
#pragma unroll
            for (int e = 0; e < 16; ++e) acc[i][j][e] = 0.f;

    const int srow = lane >> 2, ss = lane & 3;

    {
#pragma unroll
        for (int i = 0; i < 6; ++i) {
            const int s = wid * 6 + i;
            const int t = s >> 3, j = s & 7;
            const unsigned short* gsrc = (t == 0) ? Xh_g : (t == 1) ? BhT : BlT;
            const int roff = (t == 0) ? m0 : n0;
            const int row_loc = j * 16 + srow;
            const int kc = ss ^ ((row_loc >> 1) & 3);
            gload16(gsrc + (size_t)(roff + row_loc) * KD + kc * 8,
                    &SB[0][t * 4096 + j * 512]);
        }
    }

    for (int it = 0; it < 32; ++it) {
        const int cur = it & 1;
        __syncthreads();
        if (it + 1 < 32) {
            const int k0n = (it + 1) * 32;
#pragma unroll
            for (int i = 0; i < 6; ++i) {
                const int s = wid * 6 + i;
                const int t = s >> 3, j = s & 7;
                const unsigned short* gsrc = (t == 0) ? Xh_g : (t == 1) ? BhT : BlT;
                const int roff = (t == 0) ? m0 : n0;
                const int row_loc = j * 16 + srow;
                const int kc = ss ^ ((row_loc >> 1) & 3);
                gload16(gsrc + (size_t)(roff + row_loc) * KD + k0n + kc * 8,
                        &SB[cur ^ 1][t * 4096 + j * 512]);
            }
        }
        const short* Ahp = &SB[cur][0];
        const short* Bhp = &SB[cur][4096];
        const short* Blp = &SB[cur][8192];

        s16x8 fa[2][2], fbh[2][2], fbl[2][2];
#pragma unroll
        for (int am = 0; am < 2; ++am) {
            const int row = wm * 64 + am * 32 + l31;
            const int sw = (row >> 1) & 3;
#pragma unroll
            for (int kh2 = 0; kh2 < 2; ++kh2) {
                const int sl = ((kh2 * 2 + l5) ^ sw) * 8;
                fa[am][kh2] = *(const s16x8*)&Ahp[row * 32 + sl];
            }
        }
#pragma unroll
        for (int bn = 0; bn < 2; ++bn) {
            const int row = wn * 64 + bn * 32 + l31;
            const int sw = (row >> 1) & 3;
#pragma unroll
            for (int kh2 = 0; kh2 < 2; ++kh2) {
                const int sl = ((kh2 * 2 + l5) ^ sw) * 8;
                fbh[bn][kh2] = *(const s16x8*)&Bhp[row * 32 + sl];
                fbl[bn][kh2] = *(const s16x8*)&Blp[row * 32 + sl];
            }
        }
#pragma unroll
        for (int kh2 = 0; kh2 < 2; ++kh2)
#pragma unroll
            for (int am = 0; am < 2; ++am)
#pragma unroll
                for (int bn = 0; bn < 2; ++bn)
                    acc[am][bn] = MFMA32(fa[am][kh2], fbh[bn][kh2], acc[am][bn]);
#pragma unroll
        for (int kh2 = 0; kh2 < 2; ++kh2)
#pragma unroll
            for (int am = 0; am < 2; ++am)
#pragma unroll
                for (int bn = 0; bn < 2; ++bn)
                    acc[am][bn] = MFMA32(fa[am][kh2], fbl[bn][kh2], acc[am][bn]);
    }

    // epilogue (D: col=l31, row=(r&3)+8*(r>>2)+4*l5)
#pragma unroll
    for (int am = 0; am < 2; ++am)
#pragma unroll
        for (int bn = 0; bn < 2; ++bn) {
            const int n = n0 + wn * 64 + bn * 32 + l31;
            const float bv = bias[n];
            const int sec = n >> 10, cc = n & 1023, h = cc >> 6, d = cc & 63;
#pragma unroll
            for (int r = 0; r < 16; ++r) {
                const int mrow = (r & 3) + 8 * (r >> 2) + 4 * l5;
                const int m = m0 + wm * 64 + am * 32 + mrow;
                const int bb = m >> 11, t = m & 2047;
                const int bh_i = bb * NH + h;
                float val = acc[am][bn][r] + bv;
                unsigned short hi, lo;
                if (sec == 0) {
                    val *= 0.125f; split2(val, hi, lo);
                    size_t idx = ((size_t)bh_i * SEQ + t) * DH + d;
                    Qh[idx] = hi; Ql[idx] = lo;
                } else if (sec == 1) {
                    size_t idx = ((size_t)bh_i * SEQ + t) * DH + d;
                    Kh[idx] = bf16_rne(val);          // K hi-only
                } else {
                    size_t idx = ((size_t)bh_i * DH + d) * SEQ + t;   // V transposed
                    Vh[idx] = bf16_rne(val);          // V hi-only
                }
            }
        }
}

// ---------------------------------------------------------------------------
// Attention: K hi-only, V hi-only. QK^T 2-combo (kh.qh + kh.ql); PV 1-combo.
// 2 staged arrays {Kh,Vh} double-buffered in 32 KB LDS, 16-segment staging
// (4/wave). Defer-max THR=8; interleaved MFMA accumulators. Y hi-only out.
// ---------------------------------------------------------------------------
__global__ __launch_bounds__(256)
void attn_kernel(const unsigned short* __restrict__ Qh_g, const unsigned short* __restrict__ Ql_g,
                 const unsigned short* __restrict__ Kh_g,
                 const unsigned short* __restrict__ Vh_g,
                 unsigned short* __restrict__ Yh)
{
    __shared__ __align__(16) short SM[2][8192];   // 32 KB: 2 bufs x {Kh,Vh}

    const int tid = threadIdx.x, lane = tid & 63, wid = tid >> 6;
    const int l31 = lane & 31, l5 = lane >> 5;
    const int bid = blockIdx.x;
    const int qb = 15 - (bid >> 5), bh = bid & 31;   // heavy q-tiles first
    const int Q0 = qb * 128;
    const int qg = Q0 + wid * 32 + l31;              // this lane's q row

    // Q fragments from global (once per block)
    s16x8 qfh[4], qfl[4];
    {
        const size_t qo = ((size_t)bh * SEQ + qg) * DH;
#pragma unroll
        for (int t = 0; t < 4; ++t) {
            const int ch = t * 2 + l5;
            qfh[t] = *(const s16x8*)&Qh_g[qo + ch * 8];
            qfl[t] = *(const s16x8*)&Ql_g[qo + ch * 8];
        }
    }

    float m_i = -INFINITY, l_i = 0.f;
    f32x16 yacc[2];
#pragma unroll
    for (int e = 0; e < 16; ++e) { yacc[0][e] = 0.f; yacc[1][e] = 0.f; }

    const int srow = lane >> 3, ss = lane & 7;
    const int KT = 2 * qb + 2;

    // staging: 16 segments = 2 arrays {Kh,Vh} x 8; 4 per wave.
    // t = s>>3 (0=K,1=Vh), j = s&7, row = j*8+srow, kc = ss^(row&7)
    {
#pragma unroll
        for (int i = 0; i < 4; ++i) {
            const int s = wid * 4 + i;
            const int t = s >> 3, j = s & 7;
            const int row = j * 8 + srow;
            const int kc = ss ^ (row & 7);
            const unsigned short* src = (t == 0)
                ? Kh_g + ((size_t)bh * SEQ + row) * DH + kc * 8
                : Vh_g + ((size_t)bh * DH + row) * SEQ + kc * 8;
            gload16(src, &SM[0][t * 4096 + j * 512]);
        }
    }

    for (int kt = 0; kt < KT; ++kt) {
        const int cur = kt & 1;
        __syncthreads();   // stage(kt) landed; reads of buf[cur] (kt-2) done
        if (kt + 1 < KT) {
            const int kn = (kt + 1) * 64;
#pragma unroll
            for (int i = 0; i < 4; ++i) {
                const int s = wid * 4 + i;
                const int t = s >> 3, j = s & 7;
                const int row = j * 8 + srow;
                const int kc = ss ^ (row & 7);
                const unsigned short* src = (t == 0)
                    ? Kh_g + ((size_t)bh * SEQ + kn + row) * DH + kc * 8
                    : Vh_g + ((size_t)bh * DH + row) * SEQ + kn + kc * 8;
                gload16(src, &SM[cur ^ 1][t * 4096 + j * 512]);
            }
        }

        if (kt * 64 > Q0 + wid * 32 + 31) continue;   // fully masked for this wave

        const short* Ksh = &SM[cur][0];
        const short* Vsh = &SM[cur][4096];

        // ---- S^T = K . Q  (2-combo: kh.qh + kh.ql; interleaved kb)
        f32x16 s[2];
#pragma unroll
        for (int e = 0; e < 16; ++e) { s[0][e] = 0.f; s[1][e] = 0.f; }
#pragma unroll
        for (int t = 0; t < 4; ++t) {
            s16x8 kh[2];
#pragma unroll
            for (int kb = 0; kb < 2; ++kb) {
                const int row = kb * 32 + l31;
                const int sl = ((t * 2 + l5) ^ (row & 7)) * 8;
                kh[kb] = *(const s16x8*)&Ksh[row * 64 + sl];
            }
#pragma unroll
            for (int kb = 0; kb < 2; ++kb) s[kb] = MFMA32(kh[kb], qfh[t], s[kb]);
#pragma unroll
            for (int kb = 0; kb < 2; ++kb) s[kb] = MFMA32(kh[kb], qfl[t], s[kb]);
        }

        // ---- causal mask (only near the diagonal)
        if (kt * 64 + 63 > Q0 + wid * 32) {
#pragma unroll
            for (int kb = 0; kb < 2; ++kb)
#pragma unroll
                for (int r = 0; r < 16; ++r) {
                    const int key = kt * 64 + kb * 32 + (r & 3) + 8 * (r >> 2) + 4 * l5;
                    if (key > qg) s[kb][r] = -INFINITY;
                }
        }

        // ---- online softmax, in-register (q = lane&31), defer-max THR=8
        float mx = s[0][0];
#pragma unroll
        for (int r = 1; r < 16; ++r) mx = fmaxf(mx, s[0][r]);
#pragma unroll
        for (int r = 0; r < 16; ++r) mx = fmaxf(mx, s[1][r]);
        mx = fmaxf(mx, __shfl_xor(mx, 32));
        const bool defer = (__all(mx - m_i <= 8.f) != 0);
        float mref;
        if (defer) {
            mref = m_i;
        } else {
            mref = fmaxf(m_i, mx);
            const float al = __expf(m_i - mref);
            m_i = mref;
            l_i *= al;
#pragma unroll
            for (int e = 0; e < 16; ++e) { yacc[0][e] *= al; yacc[1][e] *= al; }
        }
        float ls = 0.f;
#pragma unroll
        for (int kb = 0; kb < 2; ++kb)
#pragma unroll
            for (int r = 0; r < 16; ++r) {
                s[kb][r] = __expf(s[kb][r] - mref);
                ls += s[kb][r];
            }
        ls += __shfl_xor(ls, 32);
        l_i += ls;

        // ---- P (bf16) fragments in-register: cvt_pk + permlane32_swap
        unsigned pk[2][8];
#pragma unroll
        for (int kb = 0; kb < 2; ++kb)
#pragma unroll
            for (int j = 0; j < 8; ++j)
                pk[kb][j] = cvt_pk_bf16(s[kb][2 * j], s[kb][2 * j + 1]);
        s16x8 pf[2][2];
#pragma unroll
        for (int kb = 0; kb < 2; ++kb) {
            u32x2 sA = __builtin_amdgcn_permlane32_swap(pk[kb][0], pk[kb][2], false, false);
            u32x2 sB = __builtin_amdgcn_permlane32_swap(pk[kb][1], pk[kb][3], false, false);
            u32x4 w0 = {sA[0], sB[0], sA[1], sB[1]};
            pf[kb][0] = __builtin_bit_cast(s16x8, w0);
            u32x2 sC = __builtin_amdgcn_permlane32_swap(pk[kb][4], pk[kb][6], false, false);
            u32x2 sD = __builtin_amdgcn_permlane32_swap(pk[kb][5], pk[kb][7], false, false);
            u32x4 w1 = {sC[0], sD[0], sC[1], sD[1]};
            pf[kb][1] = __builtin_bit_cast(s16x8, w1);
        }

        // ---- Y^T += V^T . P  (1-combo; interleaved dt -> distance-2 chains)
#pragma unroll
        for (int t = 0; t < 4; ++t) {
            s16x8 vh[2];
#pragma unroll
            for (int dt = 0; dt < 2; ++dt) {
                const int row = dt * 32 + l31;
                const int sl = ((t * 2 + l5) ^ (row & 7)) * 8;
                vh[dt] = *(const s16x8*)&Vsh[row * 64 + sl];
            }
            const s16x8 pfr = pf[t >> 1][t & 1];
#pragma unroll
            for (int dt = 0; dt < 2; ++dt) yacc[dt] = MFMA32(vh[dt], pfr, yacc[dt]);
        }
    }

    // ---- epilogue: normalize, hi-only bf16, LDS transpose bounce, write Yh
    __syncthreads();   // everyone done with K/V LDS
    short* SMf = &SM[0][0];
    const float inv = 1.f / l_i;
    const int qlcl = wid * 32 + l31;
#pragma unroll
    for (int dt = 0; dt < 2; ++dt)
#pragma unroll
        for (int rq = 0; rq < 4; ++rq) {
            const int d0 = dt * 32 + rq * 8 + 4 * l5;
            s16x4 h4;
#pragma unroll
            for (int c = 0; c < 4; ++c)
                h4[c] = (short)bf16_rne(yacc[dt][rq * 4 + c] * inv);
            const int base = qlcl * 64 + (((d0 >> 3) ^ (qlcl & 7)) * 8) + (d0 & 7);
            *(s16x4*)&SMf[base] = h4;
        }
    __syncthreads();
    const int b = bh >> 4, h = bh & 15;
#pragma unroll
    for (int i = 0; i < 4; ++i) {
        const int idx = tid + i * 256;
        const int row = idx >> 3, ch = idx & 7;
        const int sl = (ch ^ (row & 7)) * 8;
        s16x8 vh8 = *(const s16x8*)&SMf[row * 64 + sl];
        const size_t o = ((size_t)(b * SEQ + Q0 + row)) * EMBED + h * DH + ch * 8;
        *(s16x8*)&Yh[o] = vh8;
    }
}

// ---------------------------------------------------------------------------
// Out GEMM: 2-combo (Yh.Wh + Yh.Wl), 3 staged arrays, dbuf 48 KB,
// 24-segment issue-early staging, XCD swizzle, combo-outer MFMA16.
// (unchanged from r17)
// ---------------------------------------------------------------------------
__global__ __launch_bounds__(256)
void out_gemm_kernel(const unsigned short* __restrict__ Yh_g,
                     const unsigned short* __restrict__ WhT, const unsigned short* __restrict__ WlT,
                     const float* __restrict__ bias, float* __restrict__ out)
{
    constexpr int KD = 1024, ND = 1024;
    __shared__ __align__(16) short SB[2][12288];   // 48 KB

    const int tid = threadIdx.x, lane = tid & 63, wid = tid >> 6;
    const int g = lane >> 4, ln = lane & 15;
    const int wm = wid >> 1, wn = wid & 1;

    const int bid = blockIdx.x;
    const int u = bid >> 3, xcd = bid & 7;
    const int by = xcd * 4 + (u & 3);   // m-tile 0..31
    const int bx = u >> 2;              // n-tile 0..7
    const int m0 = by * 128, n0 = bx * 128;

    f32x4 acc[4][4];
#pragma unroll
    for (int i = 0; i < 4; ++i)
#pragma unroll
        for (int j = 0; j < 4; ++j) acc[i][j] = (f32x4){0.f, 0.f, 0.f, 0.f};

    const int srow = lane >> 2, ss = lane & 3;

    {
#pragma unroll
        for (int i = 0; i < 6; ++i) {
            const int s = wid * 6 + i;
            const int t = s >> 3, j = s & 7;
            const unsigned short* gsrc = (t == 0) ? Yh_g : (t == 1) ? WhT : WlT;
            const int roff = (t == 0) ? m0 : n0;
            const int row_loc = j * 16 + srow;
            const int kc = ss ^ ((row_loc >> 1) & 3);
            gload16(gsrc + (size_t)(roff + row_loc) * KD + kc * 8,
                    &SB[0][t * 4096 + j * 512]);
        }
    }

    for (int it = 0; it < 32; ++it) {
        const int cur = it & 1;
        __syncthreads();
        if (it + 1 < 32) {
            const int k0n = (it + 1) * 32;
#pragma unroll
            for (int i = 0; i < 6; ++i) {
                const int s = wid * 6 + i;
                const int t = s >> 3, j = s & 7;
                const unsigned short* gsrc = (t == 0) ? Yh_g : (t == 1) ? WhT : WlT;
                const int roff = (t == 0) ? m0 : n0;
                const int row_loc = j * 16 + srow;
                const int kc = ss ^ ((row_loc >> 1) & 3);
                gload16(gsrc + (size_t)(roff + row_loc) * KD + k0n + kc * 8,
                        &SB[cur ^ 1][t * 4096 + j * 512]);
            }
        }
        const short* Ah = &SB[cur][0];
        const short* Bh = &SB[cur][4096];
        const short* Bl = &SB[cur][8192];

        s16x8 fah[4], fbh[4], fbl[4];
#pragma unroll
        for (int am = 0; am < 4; ++am) {
            int m_loc = wm * 64 + am * 16 + ln;
            int sl = (g ^ ((m_loc >> 1) & 3)) * 8;
            fah[am] = *(const s16x8*)&Ah[m_loc * 32 + sl];
        }
#pragma unroll
        for (int bn = 0; bn < 4; ++bn) {
            int n_loc = wn * 64 + bn * 16 + ln;
            int sl = (g ^ ((n_loc >> 1) & 3)) * 8;
            fbh[bn] = *(const s16x8*)&Bh[n_loc * 32 + sl];
            fbl[bn] = *(const s16x8*)&Bl[n_loc * 32 + sl];
        }
#pragma unroll
        for (int am = 0; am < 4; ++am)
#pragma unroll
            for (int bn = 0; bn < 4; ++bn)
                acc[am][bn] = MFMA16(fah[am], fbh[bn], acc[am][bn]);
#pragma unroll
        for (int am = 0; am < 4; ++am)
#pragma unroll
            for (int bn = 0; bn < 4; ++bn)
                acc[am][bn] = MFMA16(fah[am], fbl[bn], acc[am][bn]);
    }

#pragma unroll
    for (int am = 0; am < 4; ++am)
#pragma unroll
        for (int bn = 0; bn < 4; ++bn) {
            int n = n0 + wn * 64 + bn * 16 + ln;
            float bv = bias[n];
#pragma unroll
            for (int r = 0; r < 4; ++r) {
                int m = m0 + wm * 64 + am * 16 + g * 4 + r;
                out[(size_t)m * ND + n] = acc[am][bn][r] + bv;
            }
        }
}

// ---------------------------------------------------------------------------
extern "C" void kernel_launch(void* const* d_in, const int* in_sizes, int n_in,
                              void* d_out, int out_size, void* d_ws, size_t ws_size,
                              hipStream_t stream)
{
    const float* x     = (const float*)d_in[0];
    const float* W_kqv = (const float*)d_in[1];
    const float* b_kqv = (const float*)d_in[2];
    const float* W_out = (const float*)d_in[3];
    const float* b_out = (const float*)d_in[4];
    float* out = (float*)d_out;

    char* ws = (char*)d_ws;
    const size_t MB = 1024 * 1024;
    unsigned short* Qh = (unsigned short*)(ws);
    unsigned short* Ql = Qh + 4194304;
    unsigned short* Kh = Ql + 4194304;
    unsigned short* Vh = Kh + 8388608;
    unsigned short* WhT = (unsigned short*)(ws + 48 * MB);
    unsigned short* WlT = WhT + 3145728;
    unsigned short* Yh  = (unsigned short*)(ws + 48 * MB);
    // Xh lives in d_out (8 MB of 16): dead until out_gemm rewrites all of it.
    unsigned short* Xh = (unsigned short*)d_out;

    const bool big = (ws_size >= 68 * MB);
    unsigned short* WoTh = big ? (unsigned short*)(ws + 64 * MB)
                               : (unsigned short*)(ws);
    unsigned short* WoTl = WoTh + 1048576;

    const int prep_blocks = 2048 + 3072 + (big ? 1024 : 0);
    prep_kernel<<<dim3(prep_blocks), 256, 0, stream>>>(
        x, W_kqv, W_out, Xh, WhT, WlT, WoTh, WoTl);
    qkv_gemm_kernel<<<dim3(768), 256, 0, stream>>>(
        Xh, WhT, WlT, b_kqv, Qh, Ql, Kh, Vh);
    attn_kernel<<<dim3(BHTOT * (SEQ / 128)), 256, 0, stream>>>(
        Qh, Ql, Kh, Vh, Yh);
    if (!big)
        splitT_kernel<<<dim3(EMBED / 32, EMBED / 32), 256, 0, stream>>>(
            W_out, WoTh, WoTl, EMBED, EMBED);
    out_gemm_kernel<<<dim3(256), 256, 0, stream>>>(
        Yh, WoTh, WoTl, b_out, out);
}

// Round 19
// 146.925 us; speedup vs baseline: 1.3453x; 1.0374x over previous
//
#include <hip/hip_runtime.h>
#include <math.h>

#define EMBED 1024
#define NH    16
#define DH    64
#define BATCH 2
#define SEQ   2048
#define MTOT  4096
#define BHTOT 32

typedef float f32x4  __attribute__((ext_vector_type(4)));
typedef float f32x16 __attribute__((ext_vector_type(16)));
typedef short s16x8  __attribute__((ext_vector_type(8)));
typedef short s16x4  __attribute__((ext_vector_type(4)));
typedef unsigned u32x2 __attribute__((ext_vector_type(2)));
typedef unsigned u32x4 __attribute__((ext_vector_type(4)));

#define AS1 __attribute__((address_space(1)))
#define AS3 __attribute__((address_space(3)))

__device__ __forceinline__ unsigned short bf16_rne(float f) {
    unsigned u = __builtin_bit_cast(unsigned, f);
    return (unsigned short)((u + 0x7FFFu + ((u >> 16) & 1u)) >> 16);
}
__device__ __forceinline__ float bf16_f(unsigned short h) {
    unsigned u = ((unsigned)h) << 16;
    return __builtin_bit_cast(float, u);
}
__device__ __forceinline__ void split2(float v, unsigned short& hi, unsigned short& lo) {
    hi = bf16_rne(v);
    lo = bf16_rne(v - bf16_f(hi));
}
__device__ __forceinline__ void gload16(const void* g, void* l) {
    __builtin_amdgcn_global_load_lds((const AS1 void*)g, (AS3 void*)l, 16, 0, 0);
}
__device__ __forceinline__ unsigned cvt_pk_bf16(float lo, float hi) {
    unsigned r;
    asm volatile("v_cvt_pk_bf16_f32 %0, %1, %2" : "=v"(r) : "v"(lo), "v"(hi));
    return r;
}
#define MFMA16(a, b, c) __builtin_amdgcn_mfma_f32_16x16x32_bf16((a), (b), (c), 0, 0, 0)
#define MFMA32(a, b, c) __builtin_amdgcn_mfma_f32_32x32x16_bf16((a), (b), (c), 0, 0, 0)

// ---------------------------------------------------------------------------
// prep: splitX (blocks [0,2048)), splitT Wkqv ([2048,5120)), optional splitT
// Wout ([5120,6144)).
// ---------------------------------------------------------------------------
__global__ __launch_bounds__(256)
void prep_kernel(const float* __restrict__ X, const float* __restrict__ Wkqv,
                 const float* __restrict__ Wout,
                 unsigned short* __restrict__ Xh,
                 unsigned short* __restrict__ WhT, unsigned short* __restrict__ WlT,
                 unsigned short* __restrict__ WoTh, unsigned short* __restrict__ WoTl)
{
    __shared__ float T[32][33];
    const int bid = blockIdx.x, tid = threadIdx.x;

    if (bid < 2048) {   // ---- splitX: X fp32 -> Xh bf16
        const size_t i = ((size_t)bid * 256 + tid) * 8;
        float4 a = *(const float4*)&X[i];
        float4 b = *(const float4*)&X[i + 4];
        float v[8] = {a.x, a.y, a.z, a.w, b.x, b.y, b.z, b.w};
        s16x8 h8;
#pragma unroll
        for (int e = 0; e < 8; ++e) h8[e] = (short)bf16_rne(v[e]);
        *(s16x8*)&Xh[i] = h8;
        return;
    }

    const float* W;
    unsigned short *Hi, *Lo;
    int Nd, n0, k0;
    if (bid < 5120) {
        const int u = bid - 2048;
        W = Wkqv; Hi = WhT; Lo = WlT; Nd = 3072;
        n0 = (u % 96) * 32; k0 = (u / 96) * 32;
    } else {
        const int u = bid - 5120;
        W = Wout; Hi = WoTh; Lo = WoTl; Nd = 1024;
        n0 = (u & 31) * 32; k0 = (u >> 5) * 32;
    }
    constexpr int Kd = 1024;
    {
        const int row = tid >> 3, c4 = (tid & 7) * 4;
        float4 v = *(const float4*)&W[(size_t)(k0 + row) * Nd + n0 + c4];
        T[row][c4] = v.x; T[row][c4 + 1] = v.y; T[row][c4 + 2] = v.z; T[row][c4 + 3] = v.w;
    }
    __syncthreads();
    {
        const int nr = tid >> 3, c4 = (tid & 7) * 4;
        s16x4 h4, l4;
#pragma unroll
        for (int e = 0; e < 4; ++e) {
            unsigned short h, l;
            split2(T[c4 + e][nr], h, l);
            h4[e] = (short)h; l4[e] = (short)l;
        }
        *(s16x4*)&Hi[(size_t)(n0 + nr) * Kd + k0 + c4] = h4;
        *(s16x4*)&Lo[(size_t)(n0 + nr) * Kd + k0 + c4] = l4;
    }
}

// ---------------------------------------------------------------------------
// splitT (standalone fallback when ws cannot host WoT before attn finishes).
// ---------------------------------------------------------------------------
__global__ __launch_bounds__(256)
void splitT_kernel(const float* __restrict__ W, unsigned short* __restrict__ HiT,
                   unsigned short* __restrict__ LoT, int Kd, int Nd)
{
    __shared__ float T[32][33];
    const int tid = threadIdx.x;
    const int n0 = blockIdx.x * 32, k0 = blockIdx.y * 32;
    {
        const int row = tid >> 3, c4 = (tid & 7) * 4;
        float4 v = *(const float4*)&W[(size_t)(k0 + row) * Nd + n0 + c4];
        T[row][c4] = v.x; T[row][c4 + 1] = v.y; T[row][c4 + 2] = v.z; T[row][c4 + 3] = v.w;
    }
    __syncthreads();
    {
        const int nr = tid >> 3, c4 = (tid & 7) * 4;
        s16x4 h4, l4;
#pragma unroll
        for (int e = 0; e < 4; ++e) {
            unsigned short h, l;
            split2(T[c4 + e][nr], h, l);
            h4[e] = (short)h; l4[e] = (short)l;
        }
        *(s16x4*)&HiT[(size_t)(n0 + nr) * Kd + k0 + c4] = h4;
        *(s16x4*)&LoT[(size_t)(n0 + nr) * Kd + k0 + c4] = l4;
    }
}

// ---------------------------------------------------------------------------
// QKV GEMM: 2-combo split on mfma_32x32x16, 128x128 tile, BK=32, dbuf 48 KB,
// issue-early staging, XCD swizzle. Q/K/V all hi-only outputs now.
// ---------------------------------------------------------------------------
__global__ __launch_bounds__(256)
void qkv_gemm_kernel(const unsigned short* __restrict__ Xh_g,
                     const unsigned short* __restrict__ BhT, const unsigned short* __restrict__ BlT,
                     const float* __restrict__ bias,
                     unsigned short* __restrict__ Qh,
                     unsigned short* __restrict__ Kh,
                     unsigned short* __restrict__ Vh)
{
    constexpr int KD = 1024;
    __shared__ __align__(16) short SB[2][12288];   // 48 KB

    const int tid = threadIdx.x, lane = tid & 63, wid = tid >> 6;
    const int l31 = lane & 31, l5 = lane >> 5;
    const int wm = wid >> 1, wn = wid & 1;

    const int bid = blockIdx.x;
    const int u = bid >> 3, xcd = bid & 7;
    const int by = xcd * 4 + (u & 3);   // m-tile 0..31
    const int bx = u >> 2;              // n-tile 0..23
    const int m0 = by * 128, n0 = bx * 128;

    f32x16 acc[2][2];
#pragma unroll
    for (int i = 0; i < 2; ++i)
#pragma unroll
        for (int j = 0; j < 2; ++j)
#pragma unroll
            for (int e = 0; e < 16; ++e) acc[i][j][e] = 0.f;

    const int srow = lane >> 2, ss = lane & 3;

    {
#pragma unroll
        for (int i = 0; i < 6; ++i) {
            const int s = wid * 6 + i;
            const int t = s >> 3, j = s & 7;
            const unsigned short* gsrc = (t == 0) ? Xh_g : (t == 1) ? BhT : BlT;
            const int roff = (t == 0) ? m0 : n0;
            const int row_loc = j * 16 + srow;
            const int kc = ss ^ ((row_loc >> 1) & 3);
            gload16(gsrc + (size_t)(roff + row_loc) * KD + kc * 8,
                    &SB[0][t * 4096 + j * 512]);
        }
    }

    for (int it = 0; it < 32; ++it) {
        const int cur = it & 1;
        __syncthreads();
        if (it + 1 < 32) {
            const int k0n = (it + 1) * 32;
#pragma unroll
            for (int i = 0; i < 6; ++i) {
                const int s = wid * 6 + i;
                const int t = s >> 3, j = s & 7;
                const unsigned short* gsrc = (t == 0) ? Xh_g : (t == 1) ? BhT : BlT;
                const int roff = (t == 0) ? m0 : n0;
                const int row_loc = j * 16 + srow;
                const int kc = ss ^ ((row_loc >> 1) & 3);
                gload16(gsrc + (size_t)(roff + row_loc) * KD + k0n + kc * 8,
                        &SB[cur ^ 1][t * 4096 + j * 512]);
            }
        }
        const short* Ahp = &SB[cur][0];
        const short* Bhp = &SB[cur][4096];
        const short* Blp = &SB[cur][8192];

        s16x8 fa[2][2], fbh[2][2], fbl[2][2];
#pragma unroll
        for (int am = 0; am < 2; ++am) {
            const int row = wm * 64 + am * 32 + l31;
            const int sw = (row >> 1) & 3;
#pragma unroll
            for (int kh2 = 0; kh2 < 2; ++kh2) {
                const int sl = ((kh2 * 2 + l5) ^ sw) * 8;
                fa[am][kh2] = *(const s16x8*)&Ahp[row * 32 + sl];
            }
        }
#pragma unroll
        for (int bn = 0; bn < 2; ++bn) {
            const int row = wn * 64 + bn * 32 + l31;
            const int sw = (row >> 1) & 3;
#pragma unroll
            for (int kh2 = 0; kh2 < 2; ++kh2) {
                const int sl = ((kh2 * 2 + l5) ^ sw) * 8;
                fbh[bn][kh2] = *(const s16x8*)&Bhp[row * 32 + sl];
                fbl[bn][kh2] = *(const s16x8*)&Blp[row * 32 + sl];
            }
        }
#pragma unroll
        for (int kh2 = 0; kh2 < 2; ++kh2)
#pragma unroll
            for (int am = 0; am < 2; ++am)
#pragma unroll
                for (int bn = 0; bn < 2; ++bn)
                    acc[am][bn] = MFMA32(fa[am][kh2], fbh[bn][kh2], acc[am][bn]);
#pragma unroll
        for (int kh2 = 0; kh2 < 2; ++kh2)
#pragma unroll
            for (int am = 0; am < 2; ++am)
#pragma unroll
                for (int bn = 0; bn < 2; ++bn)
                    acc[am][bn] = MFMA32(fa[am][kh2], fbl[bn][kh2], acc[am][bn]);
    }

    // epilogue (D: col=l31, row=(r&3)+8*(r>>2)+4*l5); all outputs hi-only
#pragma unroll
    for (int am = 0; am < 2; ++am)
#pragma unroll
        for (int bn = 0; bn < 2; ++bn) {
            const int n = n0 + wn * 64 + bn * 32 + l31;
            const float bv = bias[n];
            const int sec = n >> 10, cc = n & 1023, h = cc >> 6, d = cc & 63;
#pragma unroll
            for (int r = 0; r < 16; ++r) {
                const int mrow = (r & 3) + 8 * (r >> 2) + 4 * l5;
                const int m = m0 + wm * 64 + am * 32 + mrow;
                const int bb = m >> 11, t = m & 2047;
                const int bh_i = bb * NH + h;
                float val = acc[am][bn][r] + bv;
                if (sec == 0) {
                    size_t idx = ((size_t)bh_i * SEQ + t) * DH + d;
                    Qh[idx] = bf16_rne(val * 0.125f);   // Q hi-only
                } else if (sec == 1) {
                    size_t idx = ((size_t)bh_i * SEQ + t) * DH + d;
                    Kh[idx] = bf16_rne(val);            // K hi-only
                } else {
                    size_t idx = ((size_t)bh_i * DH + d) * SEQ + t;   // V transposed
                    Vh[idx] = bf16_rne(val);            // V hi-only
                }
            }
        }
}

// ---------------------------------------------------------------------------
// Attention: Q/K/V all hi-only. QK^T 1-combo; PV 1-combo. 2 staged arrays
// {Kh,Vh} dbuf in 32 KB LDS, 16-segment staging (4/wave). Defer-max THR=8.
// ---------------------------------------------------------------------------
__global__ __launch_bounds__(256)
void attn_kernel(const unsigned short* __restrict__ Qh_g,
                 const unsigned short* __restrict__ Kh_g,
                 const unsigned short* __restrict__ Vh_g,
                 unsigned short* __restrict__ Yh)
{
    __shared__ __align__(16) short SM[2][8192];   // 32 KB: 2 bufs x {Kh,Vh}

    const int tid = threadIdx.x, lane = tid & 63, wid = tid >> 6;
    const int l31 = lane & 31, l5 = lane >> 5;
    const int bid = blockIdx.x;
    const int qb = 15 - (bid >> 5), bh = bid & 31;   // heavy q-tiles first
    const int Q0 = qb * 128;
    const int qg = Q0 + wid * 32 + l31;              // this lane's q row

    // Q fragments from global (once per block)
    s16x8 qfh[4];
    {
        const size_t qo = ((size_t)bh * SEQ + qg) * DH;
#pragma unroll
        for (int t = 0; t < 4; ++t) {
            const int ch = t * 2 + l5;
            qfh[t] = *(const s16x8*)&Qh_g[qo + ch * 8];
        }
    }

    float m_i = -INFINITY, l_i = 0.f;
    f32x16 yacc[2];
#pragma unroll
    for (int e = 0; e < 16; ++e) { yacc[0][e] = 0.f; yacc[1][e] = 0.f; }

    const int srow = lane >> 3, ss = lane & 7;
    const int KT = 2 * qb + 2;

    // staging: 16 segments = 2 arrays {Kh,Vh} x 8; 4 per wave.
    {
#pragma unroll
        for (int i = 0; i < 4; ++i) {
            const int s = wid * 4 + i;
            const int t = s >> 3, j = s & 7;
            const int row = j * 8 + srow;
            const int kc = ss ^ (row & 7);
            const unsigned short* src = (t == 0)
                ? Kh_g + ((size_t)bh * SEQ + row) * DH + kc * 8
                : Vh_g + ((size_t)bh * DH + row) * SEQ + kc * 8;
            gload16(src, &SM[0][t * 4096 + j * 512]);
        }
    }

    for (int kt = 0; kt < KT; ++kt) {
        const int cur = kt & 1;
        __syncthreads();   // stage(kt) landed; reads of buf[cur] (kt-2) done
        if (kt + 1 < KT) {
            const int kn = (kt + 1) * 64;
#pragma unroll
            for (int i = 0; i < 4; ++i) {
                const int s = wid * 4 + i;
                const int t = s >> 3, j = s & 7;
                const int row = j * 8 + srow;
                const int kc = ss ^ (row & 7);
                const unsigned short* src = (t == 0)
                    ? Kh_g + ((size_t)bh * SEQ + kn + row) * DH + kc * 8
                    : Vh_g + ((size_t)bh * DH + row) * SEQ + kn + kc * 8;
                gload16(src, &SM[cur ^ 1][t * 4096 + j * 512]);
            }
        }

        if (kt * 64 > Q0 + wid * 32 + 31) continue;   // fully masked for this wave

        const short* Ksh = &SM[cur][0];
        const short* Vsh = &SM[cur][4096];

        // ---- S^T = K . Q  (1-combo; interleaved kb -> distance-2 chains)
        f32x16 s[2];
#pragma unroll
        for (int e = 0; e < 16; ++e) { s[0][e] = 0.f; s[1][e] = 0.f; }
#pragma unroll
        for (int t = 0; t < 4; ++t) {
            s16x8 kh[2];
#pragma unroll
            for (int kb = 0; kb < 2; ++kb) {
                const int row = kb * 32 + l31;
                const int sl = ((t * 2 + l5) ^ (row & 7)) * 8;
                kh[kb] = *(const s16x8*)&Ksh[row * 64 + sl];
            }
#pragma unroll
            for (int kb = 0; kb < 2; ++kb) s[kb] = MFMA32(kh[kb], qfh[t], s[kb]);
        }

        // ---- causal mask (only near the diagonal)
        if (kt * 64 + 63 > Q0 + wid * 32) {
#pragma unroll
            for (int kb = 0; kb < 2; ++kb)
#pragma unroll
                for (int r = 0; r < 16; ++r) {
                    const int key = kt * 64 + kb * 32 + (r & 3) + 8 * (r >> 2) + 4 * l5;
                    if (key > qg) s[kb][r] = -INFINITY;
                }
        }

        // ---- online softmax, in-register (q = lane&31), defer-max THR=8
        float mx = s[0][0];
#pragma unroll
        for (int r = 1; r < 16; ++r) mx = fmaxf(mx, s[0][r]);
#pragma unroll
        for (int r = 0; r < 16; ++r) mx = fmaxf(mx, s[1][r]);
        mx = fmaxf(mx, __shfl_xor(mx, 32));
        const bool defer = (__all(mx - m_i <= 8.f) != 0);
        float mref;
        if (defer) {
            mref = m_i;
        } else {
            mref = fmaxf(m_i, mx);
            const float al = __expf(m_i - mref);
            m_i = mref;
            l_i *= al;
#pragma unroll
            for (int e = 0; e < 16; ++e) { yacc[0][e] *= al; yacc[1][e] *= al; }
        }
        float ls = 0.f;
#pragma unroll
        for (int kb = 0; kb < 2; ++kb)
#pragma unroll
            for (int r = 0; r < 16; ++r) {
                s[kb][r] = __expf(s[kb][r] - mref);
                ls += s[kb][r];
            }
        ls += __shfl_xor(ls, 32);
        l_i += ls;

        // ---- P (bf16) fragments in-register: cvt_pk + permlane32_swap
        unsigned pk[2][8];
#pragma unroll
        for (int kb = 0; kb < 2; ++kb)
#pragma unroll
            for (int j = 0; j < 8; ++j)
                pk[kb][j] = cvt_pk_bf16(s[kb][2 * j], s[kb][2 * j + 1]);
        s16x8 pf[2][2];
#pragma unroll
        for (int kb = 0; kb < 2; ++kb) {
            u32x2 sA = __builtin_amdgcn_permlane32_swap(pk[kb][0], pk[kb][2], false, false);
            u32x2 sB = __builtin_amdgcn_permlane32_swap(pk[kb][1], pk[kb][3], false, false);
            u32x4 w0 = {sA[0], sB[0], sA[1], sB[1]};
            pf[kb][0] = __builtin_bit_cast(s16x8, w0);
            u32x2 sC = __builtin_amdgcn_permlane32_swap(pk[kb][4], pk[kb][6], false, false);
            u32x2 sD = __builtin_amdgcn_permlane32_swap(pk[kb][5], pk[kb][7], false, false);
            u32x4 w1 = {sC[0], sD[0], sC[1], sD[1]};
            pf[kb][1] = __builtin_bit_cast(s16x8, w1);
        }

        // ---- Y^T += V^T . P  (1-combo; interleaved dt -> distance-2 chains)
#pragma unroll
        for (int t = 0; t < 4; ++t) {
            s16x8 vh[2];
#pragma unroll
            for (int dt = 0; dt < 2; ++dt) {
                const int row = dt * 32 + l31;
                const int sl = ((t * 2 + l5) ^ (row & 7)) * 8;
                vh[dt] = *(const s16x8*)&Vsh[row * 64 + sl];
            }
            const s16x8 pfr = pf[t >> 1][t & 1];
#pragma unroll
            for (int dt = 0; dt < 2; ++dt) yacc[dt] = MFMA32(vh[dt], pfr, yacc[dt]);
        }
    }

    // ---- epilogue: normalize, hi-only bf16, LDS transpose bounce, write Yh
    __syncthreads();   // everyone done with K/V LDS
    short* SMf = &SM[0][0];
    const float inv = 1.f / l_i;
    const int qlcl = wid * 32 + l31;
#pragma unroll
    for (int dt = 0; dt < 2; ++dt)
#pragma unroll
        for (int rq = 0; rq < 4; ++rq) {
            const int d0 = dt * 32 + rq * 8 + 4 * l5;
            s16x4 h4;
#pragma unroll
            for (int c = 0; c < 4; ++c)
                h4[c] = (short)bf16_rne(yacc[dt][rq * 4 + c] * inv);
            const int base = qlcl * 64 + (((d0 >> 3) ^ (qlcl & 7)) * 8) + (d0 & 7);
            *(s16x4*)&SMf[base] = h4;
        }
    __syncthreads();
    const int b = bh >> 4, h = bh & 15;
#pragma unroll
    for (int i = 0; i < 4; ++i) {
        const int idx = tid + i * 256;
        const int row = idx >> 3, ch = idx & 7;
        const int sl = (ch ^ (row & 7)) * 8;
        s16x8 vh8 = *(const s16x8*)&SMf[row * 64 + sl];
        const size_t o = ((size_t)(b * SEQ + Q0 + row)) * EMBED + h * DH + ch * 8;
        *(s16x8*)&Yh[o] = vh8;
    }
}

// ---------------------------------------------------------------------------
// Out GEMM: 2-combo (Yh.Wh + Yh.Wl), 3 staged arrays, dbuf 48 KB,
// 24-segment issue-early staging, XCD swizzle, combo-outer MFMA16.
// (unchanged)
// ---------------------------------------------------------------------------
__global__ __launch_bounds__(256)
void out_gemm_kernel(const unsigned short* __restrict__ Yh_g,
                     const unsigned short* __restrict__ WhT, const unsigned short* __restrict__ WlT,
                     const float* __restrict__ bias, float* __restrict__ out)
{
    constexpr int KD = 1024, ND = 1024;
    __shared__ __align__(16) short SB[2][12288];   // 48 KB

    const int tid = threadIdx.x, lane = tid & 63, wid = tid >> 6;
    const int g = lane >> 4, ln = lane & 15;
    const int wm = wid >> 1, wn = wid & 1;

    const int bid = blockIdx.x;
    const int u = bid >> 3, xcd = bid & 7;
    const int by = xcd * 4 + (u & 3);   // m-tile 0..31
    const int bx = u >> 2;              // n-tile 0..7
    const int m0 = by * 128, n0 = bx * 128;

    f32x4 acc[4][4];
#pragma unroll
    for (int i = 0; i < 4; ++i)
#pragma unroll
        for (int j = 0; j < 4; ++j) acc[i][j] = (f32x4){0.f, 0.f, 0.f, 0.f};

    const int srow = lane >> 2, ss = lane & 3;

    {
#pragma unroll
        for (int i = 0; i < 6; ++i) {
            const int s = wid * 6 + i;
            const int t = s >> 3, j = s & 7;
            const unsigned short* gsrc = (t == 0) ? Yh_g : (t == 1) ? WhT : WlT;
            const int roff = (t == 0) ? m0 : n0;
            const int row_loc = j * 16 + srow;
            const int kc = ss ^ ((row_loc >> 1) & 3);
            gload16(gsrc + (size_t)(roff + row_loc) * KD + kc * 8,
                    &SB[0][t * 4096 + j * 512]);
        }
    }

    for (int it = 0; it < 32; ++it) {
        const int cur = it & 1;
        __syncthreads();
        if (it + 1 < 32) {
            const int k0n = (it + 1) * 32;
#pragma unroll
            for (int i = 0; i < 6; ++i) {
                const int s = wid * 6 + i;
                const int t = s >> 3, j = s & 7;
                const unsigned short* gsrc = (t == 0) ? Yh_g : (t == 1) ? WhT : WlT;
                const int roff = (t == 0) ? m0 : n0;
                const int row_loc = j * 16 + srow;
                const int kc = ss ^ ((row_loc >> 1) & 3);
                gload16(gsrc + (size_t)(roff + row_loc) * KD + k0n + kc * 8,
                        &SB[cur ^ 1][t * 4096 + j * 512]);
            }
        }
        const short* Ah = &SB[cur][0];
        const short* Bh = &SB[cur][4096];
        const short* Bl = &SB[cur][8192];

        s16x8 fah[4], fbh[4], fbl[4];
#pragma unroll
        for (int am = 0; am < 4; ++am) {
            int m_loc = wm * 64 + am * 16 + ln;
            int sl = (g ^ ((m_loc >> 1) & 3)) * 8;
            fah[am] = *(const s16x8*)&Ah[m_loc * 32 + sl];
        }
#pragma unroll
        for (int bn = 0; bn < 4; ++bn) {
            int n_loc = wn * 64 + bn * 16 + ln;
            int sl = (g ^ ((n_loc >> 1) & 3)) * 8;
            fbh[bn] = *(const s16x8*)&Bh[n_loc * 32 + sl];
            fbl[bn] = *(const s16x8*)&Bl[n_loc * 32 + sl];
        }
#pragma unroll
        for (int am = 0; am < 4; ++am)
#pragma unroll
            for (int bn = 0; bn < 4; ++bn)
                acc[am][bn] = MFMA16(fah[am], fbh[bn], acc[am][bn]);
#pragma unroll
        for (int am = 0; am < 4; ++am)
#pragma unroll
            for (int bn = 0; bn < 4; ++bn)
                acc[am][bn] = MFMA16(fah[am], fbl[bn], acc[am][bn]);
    }

#pragma unroll
    for (int am = 0; am < 4; ++am)
#pragma unroll
        for (int bn = 0; bn < 4; ++bn) {
            int n = n0 + wn * 64 + bn * 16 + ln;
            float bv = bias[n];
#pragma unroll
            for (int r = 0; r < 4; ++r) {
                int m = m0 + wm * 64 + am * 16 + g * 4 + r;
                out[(size_t)m * ND + n] = acc[am][bn][r] + bv;
            }
        }
}

// ---------------------------------------------------------------------------
extern "C" void kernel_launch(void* const* d_in, const int* in_sizes, int n_in,
                              void* d_out, int out_size, void* d_ws, size_t ws_size,
                              hipStream_t stream)
{
    const float* x     = (const float*)d_in[0];
    const float* W_kqv = (const float*)d_in[1];
    const float* b_kqv = (const float*)d_in[2];
    const float* W_out = (const float*)d_in[3];
    const float* b_out = (const float*)d_in[4];
    float* out = (float*)d_out;

    char* ws = (char*)d_ws;
    const size_t MB = 1024 * 1024;
    unsigned short* Qh = (unsigned short*)(ws);
    unsigned short* Kh = Qh + 8388608;    // ws+16MB
    unsigned short* Vh = Kh + 8388608;    // ws+32MB
    unsigned short* WhT = (unsigned short*)(ws + 48 * MB);
    unsigned short* WlT = WhT + 3145728;
    unsigned short* Yh  = (unsigned short*)(ws + 48 * MB);
    // Xh lives in d_out (8 MB of 16): dead until out_gemm rewrites all of it.
    unsigned short* Xh = (unsigned short*)d_out;

    const bool big = (ws_size >= 68 * MB);
    unsigned short* WoTh = big ? (unsigned short*)(ws + 64 * MB)
                               : (unsigned short*)(ws);
    unsigned short* WoTl = WoTh + 1048576;

    const int prep_blocks = 2048 + 3072 + (big ? 1024 : 0);
    prep_kernel<<<dim3(prep_blocks), 256, 0, stream>>>(
        x, W_kqv, W_out, Xh, WhT, WlT, WoTh, WoTl);
    qkv_gemm_kernel<<<dim3(768), 256, 0, stream>>>(
        Xh, WhT, WlT, b_kqv, Qh, Kh, Vh);
    attn_kernel<<<dim3(BHTOT * (SEQ / 128)), 256, 0, stream>>>(
        Qh, Kh, Vh, Yh);
    if (!big)
        splitT_kernel<<<dim3(EMBED / 32, EMBED / 32), 256, 0, stream>>>(
            W_out, WoTh, WoTl, EMBED, EMBED);
    out_gemm_kernel<<<dim3(256), 256, 0, stream>>>(
        Yh, WoTh, WoTl, b_out, out);
}

// Round 20
// 125.497 us; speedup vs baseline: 1.5750x; 1.1707x over previous
//
#include <hip/hip_runtime.h>
#include <math.h>

#define EMBED 1024
#define NH    16
#define DH    64
#define BATCH 2
#define SEQ   2048
#define MTOT  4096
#define BHTOT 32

typedef float f32x4  __attribute__((ext_vector_type(4)));
typedef float f32x16 __attribute__((ext_vector_type(16)));
typedef short s16x8  __attribute__((ext_vector_type(8)));
typedef short s16x4  __attribute__((ext_vector_type(4)));
typedef unsigned u32x2 __attribute__((ext_vector_type(2)));
typedef unsigned u32x4 __attribute__((ext_vector_type(4)));

#define AS1 __attribute__((address_space(1)))
#define AS3 __attribute__((address_space(3)))

__device__ __forceinline__ unsigned short bf16_rne(float f) {
    unsigned u = __builtin_bit_cast(unsigned, f);
    return (unsigned short)((u + 0x7FFFu + ((u >> 16) & 1u)) >> 16);
}
__device__ __forceinline__ float bf16_f(unsigned short h) {
    unsigned u = ((unsigned)h) << 16;
    return __builtin_bit_cast(float, u);
}
__device__ __forceinline__ void split2(float v, unsigned short& hi, unsigned short& lo) {
    hi = bf16_rne(v);
    lo = bf16_rne(v - bf16_f(hi));
}
__device__ __forceinline__ void gload16(const void* g, void* l) {
    __builtin_amdgcn_global_load_lds((const AS1 void*)g, (AS3 void*)l, 16, 0, 0);
}
__device__ __forceinline__ unsigned cvt_pk_bf16(float lo, float hi) {
    unsigned r;
    asm volatile("v_cvt_pk_bf16_f32 %0, %1, %2" : "=v"(r) : "v"(lo), "v"(hi));
    return r;
}
#define MFMA16(a, b, c) __builtin_amdgcn_mfma_f32_16x16x32_bf16((a), (b), (c), 0, 0, 0)
#define MFMA32(a, b, c) __builtin_amdgcn_mfma_f32_32x32x16_bf16((a), (b), (c), 0, 0, 0)

// ---------------------------------------------------------------------------
// prep: splitX (blocks [0,2048)), splitT Wkqv hi-only ([2048,5120)),
// optional splitT Wout hi+lo ([5120,6144)).
// ---------------------------------------------------------------------------
__global__ __launch_bounds__(256)
void prep_kernel(const float* __restrict__ X, const float* __restrict__ Wkqv,
                 const float* __restrict__ Wout,
                 unsigned short* __restrict__ Xh,
                 unsigned short* __restrict__ WhT,
                 unsigned short* __restrict__ WoTh, unsigned short* __restrict__ WoTl)
{
    __shared__ float T[32][33];
    const int bid = blockIdx.x, tid = threadIdx.x;

    if (bid < 2048) {   // ---- splitX: X fp32 -> Xh bf16
        const size_t i = ((size_t)bid * 256 + tid) * 8;
        float4 a = *(const float4*)&X[i];
        float4 b = *(const float4*)&X[i + 4];
        float v[8] = {a.x, a.y, a.z, a.w, b.x, b.y, b.z, b.w};
        s16x8 h8;
#pragma unroll
        for (int e = 0; e < 8; ++e) h8[e] = (short)bf16_rne(v[e]);
        *(s16x8*)&Xh[i] = h8;
        return;
    }

    const float* W;
    unsigned short *Hi, *Lo;
    int Nd, n0, k0;
    bool wantLo;
    if (bid < 5120) {
        const int u = bid - 2048;
        W = Wkqv; Hi = WhT; Lo = nullptr; Nd = 3072; wantLo = false;
        n0 = (u % 96) * 32; k0 = (u / 96) * 32;
    } else {
        const int u = bid - 5120;
        W = Wout; Hi = WoTh; Lo = WoTl; Nd = 1024; wantLo = true;
        n0 = (u & 31) * 32; k0 = (u >> 5) * 32;
    }
    constexpr int Kd = 1024;
    {
        const int row = tid >> 3, c4 = (tid & 7) * 4;
        float4 v = *(const float4*)&W[(size_t)(k0 + row) * Nd + n0 + c4];
        T[row][c4] = v.x; T[row][c4 + 1] = v.y; T[row][c4 + 2] = v.z; T[row][c4 + 3] = v.w;
    }
    __syncthreads();
    {
        const int nr = tid >> 3, c4 = (tid & 7) * 4;
        s16x4 h4, l4;
#pragma unroll
        for (int e = 0; e < 4; ++e) {
            unsigned short h, l;
            split2(T[c4 + e][nr], h, l);
            h4[e] = (short)h; l4[e] = (short)l;
        }
        *(s16x4*)&Hi[(size_t)(n0 + nr) * Kd + k0 + c4] = h4;
        if (wantLo)
            *(s16x4*)&Lo[(size_t)(n0 + nr) * Kd + k0 + c4] = l4;
    }
}

// ---------------------------------------------------------------------------
// splitT (standalone fallback when ws cannot host WoT before attn finishes).
// ---------------------------------------------------------------------------
__global__ __launch_bounds__(256)
void splitT_kernel(const float* __restrict__ W, unsigned short* __restrict__ HiT,
                   unsigned short* __restrict__ LoT, int Kd, int Nd)
{
    __shared__ float T[32][33];
    const int tid = threadIdx.x;
    const int n0 = blockIdx.x * 32, k0 = blockIdx.y * 32;
    {
        const int row = tid >> 3, c4 = (tid & 7) * 4;
        float4 v = *(const float4*)&W[(size_t)(k0 + row) * Nd + n0 + c4];
        T[row][c4] = v.x; T[row][c4 + 1] = v.y; T[row][c4 + 2] = v.z; T[row][c4 + 3] = v.w;
    }
    __syncthreads();
    {
        const int nr = tid >> 3, c4 = (tid & 7) * 4;
        s16x4 h4, l4;
#pragma unroll
        for (int e = 0; e < 4; ++e) {
            unsigned short h, l;
            split2(T[c4 + e][nr], h, l);
            h4[e] = (short)h; l4[e] = (short)l;
        }
        *(s16x4*)&HiT[(size_t)(n0 + nr) * Kd + k0 + c4] = h4;
        *(s16x4*)&LoT[(size_t)(n0 + nr) * Kd + k0 + c4] = l4;
    }
}

// ---------------------------------------------------------------------------
// QKV GEMM: pure bf16 (1-combo Xh.Wh), mfma_32x32x16, 128x128 tile, BK=32,
// dbuf 32 KB LDS (2 arrays x 8 KB x 2 bufs), issue-early staging (4/wave),
// XCD swizzle. Q/K/V hi-only outputs.
// ---------------------------------------------------------------------------
__global__ __launch_bounds__(256)
void qkv_gemm_kernel(const unsigned short* __restrict__ Xh_g,
                     const unsigned short* __restrict__ BhT,
                     const float* __restrict__ bias,
                     unsigned short* __restrict__ Qh,
                     unsigned short* __restrict__ Kh,
                     unsigned short* __restrict__ Vh)
{
    constexpr int KD = 1024;
    __shared__ __align__(16) short SB[2][8192];   // 32 KB: {Ah, Bh} x 2 bufs

    const int tid = threadIdx.x, lane = tid & 63, wid = tid >> 6;
    const int l31 = lane & 31, l5 = lane >> 5;
    const int wm = wid >> 1, wn = wid & 1;

    const int bid = blockIdx.x;
    const int u = bid >> 3, xcd = bid & 7;
    const int by = xcd * 4 + (u & 3);   // m-tile 0..31
    const int bx = u >> 2;              // n-tile 0..23
    const int m0 = by * 128, n0 = bx * 128;

    f32x16 acc[2][2];
#pragma unroll
    for (int i = 0; i < 2; ++i)
#pragma unroll
        for (int j = 0; j < 2; ++j)
#pragma unroll
            for (int e = 0; e < 16; ++e) acc[i][j][e] = 0.f;

    const int srow = lane >> 2, ss = lane & 3;

    // staging: 16 segments = 2 arrays {A,B} x 8; 4 per wave.
    {
#pragma unroll
        for (int i = 0; i < 4; ++i) {
            const int s = wid * 4 + i;
            const int t = s >> 3, j = s & 7;
            const unsigned short* gsrc = (t == 0) ? Xh_g : BhT;
            const int roff = (t == 0) ? m0 : n0;
            const int row_loc = j * 16 + srow;
            const int kc = ss ^ ((row_loc >> 1) & 3);
            gload16(gsrc + (size_t)(roff + row_loc) * KD + kc * 8,
                    &SB[0][t * 4096 + j * 512]);
        }
    }

    for (int it = 0; it < 32; ++it) {
        const int cur = it & 1;
        __syncthreads();
        if (it + 1 < 32) {
            const int k0n = (it + 1) * 32;
#pragma unroll
            for (int i = 0; i < 4; ++i) {
                const int s = wid * 4 + i;
                const int t = s >> 3, j = s & 7;
                const unsigned short* gsrc = (t == 0) ? Xh_g : BhT;
                const int roff = (t == 0) ? m0 : n0;
                const int row_loc = j * 16 + srow;
                const int kc = ss ^ ((row_loc >> 1) & 3);
                gload16(gsrc + (size_t)(roff + row_loc) * KD + k0n + kc * 8,
                        &SB[cur ^ 1][t * 4096 + j * 512]);
            }
        }
        const short* Ahp = &SB[cur][0];
        const short* Bhp = &SB[cur][4096];

        s16x8 fa[2][2], fbh[2][2];
#pragma unroll
        for (int am = 0; am < 2; ++am) {
            const int row = wm * 64 + am * 32 + l31;
            const int sw = (row >> 1) & 3;
#pragma unroll
            for (int kh2 = 0; kh2 < 2; ++kh2) {
                const int sl = ((kh2 * 2 + l5) ^ sw) * 8;
                fa[am][kh2] = *(const s16x8*)&Ahp[row * 32 + sl];
            }
        }
#pragma unroll
        for (int bn = 0; bn < 2; ++bn) {
            const int row = wn * 64 + bn * 32 + l31;
            const int sw = (row >> 1) & 3;
#pragma unroll
            for (int kh2 = 0; kh2 < 2; ++kh2) {
                const int sl = ((kh2 * 2 + l5) ^ sw) * 8;
                fbh[bn][kh2] = *(const s16x8*)&Bhp[row * 32 + sl];
            }
        }
#pragma unroll
        for (int kh2 = 0; kh2 < 2; ++kh2)
#pragma unroll
            for (int am = 0; am < 2; ++am)
#pragma unroll
                for (int bn = 0; bn < 2; ++bn)
                    acc[am][bn] = MFMA32(fa[am][kh2], fbh[bn][kh2], acc[am][bn]);
    }

    // epilogue (D: col=l31, row=(r&3)+8*(r>>2)+4*l5); all outputs hi-only
#pragma unroll
    for (int am = 0; am < 2; ++am)
#pragma unroll
        for (int bn = 0; bn < 2; ++bn) {
            const int n = n0 + wn * 64 + bn * 32 + l31;
            const float bv = bias[n];
            const int sec = n >> 10, cc = n & 1023, h = cc >> 6, d = cc & 63;
#pragma unroll
            for (int r = 0; r < 16; ++r) {
                const int mrow = (r & 3) + 8 * (r >> 2) + 4 * l5;
                const int m = m0 + wm * 64 + am * 32 + mrow;
                const int bb = m >> 11, t = m & 2047;
                const int bh_i = bb * NH + h;
                float val = acc[am][bn][r] + bv;
                if (sec == 0) {
                    size_t idx = ((size_t)bh_i * SEQ + t) * DH + d;
                    Qh[idx] = bf16_rne(val * 0.125f);
                } else if (sec == 1) {
                    size_t idx = ((size_t)bh_i * SEQ + t) * DH + d;
                    Kh[idx] = bf16_rne(val);
                } else {
                    size_t idx = ((size_t)bh_i * DH + d) * SEQ + t;   // V transposed
                    Vh[idx] = bf16_rne(val);
                }
            }
        }
}

// ---------------------------------------------------------------------------
// Attention: Q/K/V all hi-only. QK^T 1-combo; PV 1-combo. 2 staged arrays
// {Kh,Vh} dbuf in 32 KB LDS, 16-segment staging (4/wave). Defer-max THR=8.
// (unchanged from r19)
// ---------------------------------------------------------------------------
__global__ __launch_bounds__(256)
void attn_kernel(const unsigned short* __restrict__ Qh_g,
                 const unsigned short* __restrict__ Kh_g,
                 const unsigned short* __restrict__ Vh_g,
                 unsigned short* __restrict__ Yh)
{
    __shared__ __align__(16) short SM[2][8192];   // 32 KB: 2 bufs x {Kh,Vh}

    const int tid = threadIdx.x, lane = tid & 63, wid = tid >> 6;
    const int l31 = lane & 31, l5 = lane >> 5;
    const int bid = blockIdx.x;
    const int qb = 15 - (bid >> 5), bh = bid & 31;   // heavy q-tiles first
    const int Q0 = qb * 128;
    const int qg = Q0 + wid * 32 + l31;              // this lane's q row

    // Q fragments from global (once per block)
    s16x8 qfh[4];
    {
        const size_t qo = ((size_t)bh * SEQ + qg) * DH;
#pragma unroll
        for (int t = 0; t < 4; ++t) {
            const int ch = t * 2 + l5;
            qfh[t] = *(const s16x8*)&Qh_g[qo + ch * 8];
        }
    }

    float m_i = -INFINITY, l_i = 0.f;
    f32x16 yacc[2];
#pragma unroll
    for (int e = 0; e < 16; ++e) { yacc[0][e] = 0.f; yacc[1][e] = 0.f; }

    const int srow = lane >> 3, ss = lane & 7;
    const int KT = 2 * qb + 2;

    // staging: 16 segments = 2 arrays {Kh,Vh} x 8; 4 per wave.
    {
#pragma unroll
        for (int i = 0; i < 4; ++i) {
            const int s = wid * 4 + i;
            const int t = s >> 3, j = s & 7;
            const int row = j * 8 + srow;
            const int kc = ss ^ (row & 7);
            const unsigned short* src = (t == 0)
                ? Kh_g + ((size_t)bh * SEQ + row) * DH + kc * 8
                : Vh_g + ((size_t)bh * DH + row) * SEQ + kc * 8;
            gload16(src, &SM[0][t * 4096 + j * 512]);
        }
    }

    for (int kt = 0; kt < KT; ++kt) {
        const int cur = kt & 1;
        __syncthreads();   // stage(kt) landed; reads of buf[cur] (kt-2) done
        if (kt + 1 < KT) {
            const int kn = (kt + 1) * 64;
#pragma unroll
            for (int i = 0; i < 4; ++i) {
                const int s = wid * 4 + i;
                const int t = s >> 3, j = s & 7;
                const int row = j * 8 + srow;
                const int kc = ss ^ (row & 7);
                const unsigned short* src = (t == 0)
                    ? Kh_g + ((size_t)bh * SEQ + kn + row) * DH + kc * 8
                    : Vh_g + ((size_t)bh * DH + row) * SEQ + kn + kc * 8;
                gload16(src, &SM[cur ^ 1][t * 4096 + j * 512]);
            }
        }

        if (kt * 64 > Q0 + wid * 32 + 31) continue;   // fully masked for this wave

        const short* Ksh = &SM[cur][0];
        const short* Vsh = &SM[cur][4096];

        // ---- S^T = K . Q  (1-combo; interleaved kb -> distance-2 chains)
        f32x16 s[2];
#pragma unroll
        for (int e = 0; e < 16; ++e) { s[0][e] = 0.f; s[1][e] = 0.f; }
#pragma unroll
        for (int t = 0; t < 4; ++t) {
            s16x8 kh[2];
#pragma unroll
            for (int kb = 0; kb < 2; ++kb) {
                const int row = kb * 32 + l31;
                const int sl = ((t * 2 + l5) ^ (row & 7)) * 8;
                kh[kb] = *(const s16x8*)&Ksh[row * 64 + sl];
            }
#pragma unroll
            for (int kb = 0; kb < 2; ++kb) s[kb] = MFMA32(kh[kb], qfh[t], s[kb]);
        }

        // ---- causal mask (only near the diagonal)
        if (kt * 64 + 63 > Q0 + wid * 32) {
#pragma unroll
            for (int kb = 0; kb < 2; ++kb)
#pragma unroll
                for (int r = 0; r < 16; ++r) {
                    const int key = kt * 64 + kb * 32 + (r & 3) + 8 * (r >> 2) + 4 * l5;
                    if (key > qg) s[kb][r] = -INFINITY;
                }
        }

        // ---- online softmax, in-register (q = lane&31), defer-max THR=8
        float mx = s[0][0];
#pragma unroll
        for (int r = 1; r < 16; ++r) mx = fmaxf(mx, s[0][r]);
#pragma unroll
        for (int r = 0; r < 16; ++r) mx = fmaxf(mx, s[1][r]);
        mx = fmaxf(mx, __shfl_xor(mx, 32));
        const bool defer = (__all(mx - m_i <= 8.f) != 0);
        float mref;
        if (defer) {
            mref = m_i;
        } else {
            mref = fmaxf(m_i, mx);
            const float al = __expf(m_i - mref);
            m_i = mref;
            l_i *= al;
#pragma unroll
            for (int e = 0; e < 16; ++e) { yacc[0][e] *= al; yacc[1][e] *= al; }
        }
        float ls = 0.f;
#pragma unroll
        for (int kb = 0; kb < 2; ++kb)
#pragma unroll
            for (int r = 0; r < 16; ++r) {
                s[kb][r] = __expf(s[kb][r] - mref);
                ls += s[kb][r];
            }
        ls += __shfl_xor(ls, 32);
        l_i += ls;

        // ---- P (bf16) fragments in-register: cvt_pk + permlane32_swap
        unsigned pk[2][8];
#pragma unroll
        for (int kb = 0; kb < 2; ++kb)
#pragma unroll
            for (int j = 0; j < 8; ++j)
                pk[kb][j] = cvt_pk_bf16(s[kb][2 * j], s[kb][2 * j + 1]);
        s16x8 pf[2][2];
#pragma unroll
        for (int kb = 0; kb < 2; ++kb) {
            u32x2 sA = __builtin_amdgcn_permlane32_swap(pk[kb][0], pk[kb][2], false, false);
            u32x2 sB = __builtin_amdgcn_permlane32_swap(pk[kb][1], pk[kb][3], false, false);
            u32x4 w0 = {sA[0], sB[0], sA[1], sB[1]};
            pf[kb][0] = __builtin_bit_cast(s16x8, w0);
            u32x2 sC = __builtin_amdgcn_permlane32_swap(pk[kb][4], pk[kb][6], false, false);
            u32x2 sD = __builtin_amdgcn_permlane32_swap(pk[kb][5], pk[kb][7], false, false);
            u32x4 w1 = {sC[0], sD[0], sC[1], sD[1]};
            pf[kb][1] = __builtin_bit_cast(s16x8, w1);
        }

        // ---- Y^T += V^T . P  (1-combo; interleaved dt -> distance-2 chains)
#pragma unroll
        for (int t = 0; t < 4; ++t) {
            s16x8 vh[2];
#pragma unroll
            for (int dt = 0; dt < 2; ++dt) {
                const int row = dt * 32 + l31;
                const int sl = ((t * 2 + l5) ^ (row & 7)) * 8;
                vh[dt] = *(const s16x8*)&Vsh[row * 64 + sl];
            }
            const s16x8 pfr = pf[t >> 1][t & 1];
#pragma unroll
            for (int dt = 0; dt < 2; ++dt) yacc[dt] = MFMA32(vh[dt], pfr, yacc[dt]);
        }
    }

    // ---- epilogue: normalize, hi-only bf16, LDS transpose bounce, write Yh
    __syncthreads();   // everyone done with K/V LDS
    short* SMf = &SM[0][0];
    const float inv = 1.f / l_i;
    const int qlcl = wid * 32 + l31;
#pragma unroll
    for (int dt = 0; dt < 2; ++dt)
#pragma unroll
        for (int rq = 0; rq < 4; ++rq) {
            const int d0 = dt * 32 + rq * 8 + 4 * l5;
            s16x4 h4;
#pragma unroll
            for (int c = 0; c < 4; ++c)
                h4[c] = (short)bf16_rne(yacc[dt][rq * 4 + c] * inv);
            const int base = qlcl * 64 + (((d0 >> 3) ^ (qlcl & 7)) * 8) + (d0 & 7);
            *(s16x4*)&SMf[base] = h4;
        }
    __syncthreads();
    const int b = bh >> 4, h = bh & 15;
#pragma unroll
    for (int i = 0; i < 4; ++i) {
        const int idx = tid + i * 256;
        const int row = idx >> 3, ch = idx & 7;
        const int sl = (ch ^ (row & 7)) * 8;
        s16x8 vh8 = *(const s16x8*)&SMf[row * 64 + sl];
        const size_t o = ((size_t)(b * SEQ + Q0 + row)) * EMBED + h * DH + ch * 8;
        *(s16x8*)&Yh[o] = vh8;
    }
}

// ---------------------------------------------------------------------------
// Out GEMM: 2-combo (Yh.Wh + Yh.Wl), 3 staged arrays, dbuf 48 KB,
// 24-segment issue-early staging, XCD swizzle, combo-outer MFMA16.
// (unchanged from r19)
// ---------------------------------------------------------------------------
__global__ __launch_bounds__(256)
void out_gemm_kernel(const unsigned short* __restrict__ Yh_g,
                     const unsigned short* __restrict__ WhT, const unsigned short* __restrict__ WlT,
                     const float* __restrict__ bias, float* __restrict__ out)
{
    constexpr int KD = 1024, ND = 1024;
    __shared__ __align__(16) short SB[2][12288];   // 48 KB

    const int tid = threadIdx.x, lane = tid & 63, wid = tid >> 6;
    const int g = lane >> 4, ln = lane & 15;
    const int wm = wid >> 1, wn = wid & 1;

    const int bid = blockIdx.x;
    const int u = bid >> 3, xcd = bid & 7;
    const int by = xcd * 4 + (u & 3);   // m-tile 0..31
    const int bx = u >> 2;              // n-tile 0..7
    const int m0 = by * 128, n0 = bx * 128;

    f32x4 acc[4][4];
#pragma unroll
    for (int i = 0; i < 4; ++i)
#pragma unroll
        for (int j = 0; j < 4; ++j) acc[i][j] = (f32x4){0.f, 0.f, 0.f, 0.f};

    const int srow = lane >> 2, ss = lane & 3;

    {
#pragma unroll
        for (int i = 0; i < 6; ++i) {
            const int s = wid * 6 + i;
            const int t = s >> 3, j = s & 7;
            const unsigned short* gsrc = (t == 0) ? Yh_g : (t == 1) ? WhT : WlT;
            const int roff = (t == 0) ? m0 : n0;
            const int row_loc = j * 16 + srow;
            const int kc = ss ^ ((row_loc >> 1) & 3);
            gload16(gsrc + (size_t)(roff + row_loc) * KD + kc * 8,
                    &SB[0][t * 4096 + j * 512]);
        }
    }

    for (int it = 0; it < 32; ++it) {
        const int cur = it & 1;
        __syncthreads();
        if (it + 1 < 32) {
            const int k0n = (it + 1) * 32;
#pragma unroll
            for (int i = 0; i < 6; ++i) {
                const int s = wid * 6 + i;
                const int t = s >> 3, j = s & 7;
                const unsigned short* gsrc = (t == 0) ? Yh_g : (t == 1) ? WhT : WlT;
                const int roff = (t == 0) ? m0 : n0;
                const int row_loc = j * 16 + srow;
                const int kc = ss ^ ((row_loc >> 1) & 3);
                gload16(gsrc + (size_t)(roff + row_loc) * KD + k0n + kc * 8,
                        &SB[cur ^ 1][t * 4096 + j * 512]);
            }
        }
        const short* Ah = &SB[cur][0];
        const short* Bh = &SB[cur][4096];
        const short* Bl = &SB[cur][8192];

        s16x8 fah[4], fbh[4], fbl[4];
#pragma unroll
        for (int am = 0; am < 4; ++am) {
            int m_loc = wm * 64 + am * 16 + ln;
            int sl = (g ^ ((m_loc >> 1) & 3)) * 8;
            fah[am] = *(const s16x8*)&Ah[m_loc * 32 + sl];
        }
#pragma unroll
        for (int bn = 0; bn < 4; ++bn) {
            int n_loc = wn * 64 + bn * 16 + ln;
            int sl = (g ^ ((n_loc >> 1) & 3)) * 8;
            fbh[bn] = *(const s16x8*)&Bh[n_loc * 32 + sl];
            fbl[bn] = *(const s16x8*)&Bl[n_loc * 32 + sl];
        }
#pragma unroll
        for (int am = 0; am < 4; ++am)
#pragma unroll
            for (int bn = 0; bn < 4; ++bn)
                acc[am][bn] = MFMA16(fah[am], fbh[bn], acc[am][bn]);
#pragma unroll
        for (int am = 0; am < 4; ++am)
#pragma unroll
            for (int bn = 0; bn < 4; ++bn)
                acc[am][bn] = MFMA16(fah[am], fbl[bn], acc[am][bn]);
    }

#pragma unroll
    for (int am = 0; am < 4; ++am)
#pragma unroll
        for (int bn = 0; bn < 4; ++bn) {
            int n = n0 + wn * 64 + bn * 16 + ln;
            float bv = bias[n];
#pragma unroll
            for (int r = 0; r < 4; ++r) {
                int m = m0 + wm * 64 + am * 16 + g * 4 + r;
                out[(size_t)m * ND + n] = acc[am][bn][r] + bv;
            }
        }
}

// ---------------------------------------------------------------------------
extern "C" void kernel_launch(void* const* d_in, const int* in_sizes, int n_in,
                              void* d_out, int out_size, void* d_ws, size_t ws_size,
                              hipStream_t stream)
{
    const float* x     = (const float*)d_in[0];
    const float* W_kqv = (const float*)d_in[1];
    const float* b_kqv = (const float*)d_in[2];
    const float* W_out = (const float*)d_in[3];
    const float* b_out = (const float*)d_in[4];
    float* out = (float*)d_out;

    char* ws = (char*)d_ws;
    const size_t MB = 1024 * 1024;
    unsigned short* Qh = (unsigned short*)(ws);
    unsigned short* Kh = Qh + 8388608;    // ws+16MB
    unsigned short* Vh = Kh + 8388608;    // ws+32MB
    unsigned short* WhT = (unsigned short*)(ws + 48 * MB);
    unsigned short* Yh  = (unsigned short*)(ws + 48 * MB);   // overwrites WhT post-qkv
    // Xh lives in d_out (8 MB of 16): dead until out_gemm rewrites all of it.
    unsigned short* Xh = (unsigned short*)d_out;

    const bool big = (ws_size >= 68 * MB);
    unsigned short* WoTh = big ? (unsigned short*)(ws + 64 * MB)
                               : (unsigned short*)(ws);
    unsigned short* WoTl = WoTh + 1048576;

    const int prep_blocks = 2048 + 3072 + (big ? 1024 : 0);
    prep_kernel<<<dim3(prep_blocks), 256, 0, stream>>>(
        x, W_kqv, W_out, Xh, WhT, WoTh, WoTl);
    qkv_gemm_kernel<<<dim3(768), 256, 0, stream>>>(
        Xh, WhT, b_kqv, Qh, Kh, Vh);
    attn_kernel<<<dim3(BHTOT * (SEQ / 128)), 256, 0, stream>>>(
        Qh, Kh, Vh, Yh);
    if (!big)
        splitT_kernel<<<dim3(EMBED / 32, EMBED / 32), 256, 0, stream>>>(
            W_out, WoTh, WoTl, EMBED, EMBED);
    out_gemm_kernel<<<dim3(256), 256, 0, stream>>>(
        Yh, WoTh, WoTl, b_out, out);
}